// Round 1
// baseline (482.679 us; speedup 1.0000x reference)
//
#include <hip/hip_runtime.h>
#include <math.h>
#include <stdint.h>

#define N_NODES 20000
#define N_EDGES 320000
#define EN_TOT  340000   // E + N (with self loops)
#define HID 128
#define C1  512          // HEADS*HID

// ---------------------------------------------------------------- degree + loop-attr sums
__global__ void k_deg(const int* __restrict__ dst, const float* __restrict__ eattr,
                      float* __restrict__ degf, float* __restrict__ loopsum) {
    int e = blockIdx.x * 256 + threadIdx.x;
    if (e >= N_EDGES) return;
    int d = dst[e];
    atomicAdd(&degf[d], 1.0f);
#pragma unroll
    for (int f = 0; f < 4; f++) atomicAdd(&loopsum[d * 4 + f], eattr[e * 4 + f]);
}

// ---------------------------------------------------------------- scan (offsets), loop_attr normalize, M1/m2 fold
__global__ __launch_bounds__(1024) void k_scan(const float* __restrict__ degf,
                                               float* __restrict__ loopattr, int* __restrict__ offsets,
                                               const float* __restrict__ We1, const float* __restrict__ ae1,
                                               const float* __restrict__ We2, const float* __restrict__ ae2,
                                               float* __restrict__ M1, float* __restrict__ m2) {
    __shared__ int s[1024];
    int t = threadIdx.x;
    int n0 = t * 20;
    int tot = 0;
    for (int i = 0; i < 20; i++) {
        int n = n0 + i;
        if (n < N_NODES) tot += (int)(degf[n] + 0.5f) + 1;
    }
    s[t] = tot;
    __syncthreads();
    for (int off = 1; off < 1024; off <<= 1) {
        int v = (t >= off) ? s[t - off] : 0;
        __syncthreads();
        s[t] += v;
        __syncthreads();
    }
    int run = s[t] - tot;
    for (int i = 0; i < 20; i++) {
        int n = n0 + i;
        if (n < N_NODES) {
            offsets[n] = run;
            run += (int)(degf[n] + 0.5f) + 1;
        }
    }
    if (t == 1023) offsets[N_NODES] = s[1023];
    // normalize loop_attr = loopsum / max(deg,1)
    for (int n = t; n < N_NODES; n += 1024) {
        float inv = 1.0f / fmaxf(degf[n], 1.0f);
#pragma unroll
        for (int f = 0; f < 4; f++) loopattr[n * 4 + f] *= inv;
    }
    // fold edge-attr projections: M1[f][h] = sum_c We1[f, h*128+c] * ae1[h,c];  m2[f] = sum_c We2[f,c]*ae2[c]
    if (t < 16) {
        int f = t >> 2, h = t & 3;
        float acc = 0.f;
        for (int c = 0; c < 128; c++) acc += We1[f * 512 + h * 128 + c] * ae1[h * 128 + c];
        M1[f * 4 + h] = acc;
    } else if (t < 20) {
        int f = t - 16;
        float acc = 0.f;
        for (int c = 0; c < 128; c++) acc += We2[f * 128 + c] * ae2[c];
        m2[f] = acc;
    }
}

// ---------------------------------------------------------------- CSR fill (edges + self loops)
__global__ void k_fill(const int* __restrict__ src, const int* __restrict__ dst,
                       const int* __restrict__ offsets, int* __restrict__ cursor,
                       int* __restrict__ csr_src, int* __restrict__ csr_eid, int* __restrict__ csr_dst) {
    int i = blockIdx.x * 256 + threadIdx.x;
    if (i >= EN_TOT) return;
    int d, sidx, eid;
    if (i < N_EDGES) { d = dst[i]; sidx = src[i]; eid = i; }
    else { int n = i - N_EDGES; d = n; sidx = n; eid = N_EDGES + n; }
    int pos = offsets[d] + atomicAdd(&cursor[d], 1);
    csr_src[pos] = sidx;
    csr_eid[pos] = eid;
    csr_dst[pos] = d;
}

// ---------------------------------------------------------------- input proj: h0 = x @ Wp + bp   [N,4]x[4,128]
__global__ __launch_bounds__(256) void k_proj(const float* __restrict__ x, const float* __restrict__ Wp,
                                              const float* __restrict__ bp, float* __restrict__ h0) {
    int tid = threadIdx.x;
    int n = blockIdx.x * 2 + (tid >> 7);
    int c = tid & 127;
    float acc = bp[c];
#pragma unroll
    for (int f = 0; f < 4; f++) acc += x[n * 4 + f] * Wp[f * 128 + c];
    h0[(size_t)n * 128 + c] = acc;
}

// ---------------------------------------------------------------- generic fp32 GEMM  C[M,Nn] = A[M,K] @ B[K,Nn] (+bias)
__global__ __launch_bounds__(256) void k_gemm(const float* __restrict__ A, const float* __restrict__ B,
                                              float* __restrict__ C, int M, int Nn, int K,
                                              const float* __restrict__ bias) {
    __shared__ float AsT[32][72];   // transposed A tile, padded: row stride 288B (16B-aligned)
    __shared__ float Bs[32][128];
    int m0 = blockIdx.x * 64, n0 = blockIdx.y * 128;
    int tid = threadIdx.x;
    int tx = tid & 31, ty = tid >> 5;      // tx: 32 col groups of 4, ty: 8 row groups of 8
    float acc[8][4];
#pragma unroll
    for (int r = 0; r < 8; r++)
#pragma unroll
        for (int c = 0; c < 4; c++) acc[r][c] = 0.f;

    for (int k0 = 0; k0 < K; k0 += 32) {
        // A tile: 64 rows x 32 cols -> 512 float4, 2 per thread, store transposed
#pragma unroll
        for (int l = 0; l < 2; l++) {
            int idx = tid + l * 256;
            int r = idx >> 3, c4 = (idx & 7) * 4;
            float4 v = make_float4(0.f, 0.f, 0.f, 0.f);
            if (m0 + r < M) v = *(const float4*)&A[(size_t)(m0 + r) * K + k0 + c4];
            AsT[c4 + 0][r] = v.x; AsT[c4 + 1][r] = v.y; AsT[c4 + 2][r] = v.z; AsT[c4 + 3][r] = v.w;
        }
        // B tile: 32 x 128 -> 1024 float4, 4 per thread
#pragma unroll
        for (int l = 0; l < 4; l++) {
            int idx = tid + l * 256;
            int r = idx >> 5, c4 = (idx & 31) * 4;
            *(float4*)&Bs[r][c4] = *(const float4*)&B[(size_t)(k0 + r) * Nn + n0 + c4];
        }
        __syncthreads();
#pragma unroll
        for (int kk = 0; kk < 32; kk++) {
            float4 b = *(float4*)&Bs[kk][tx * 4];
            float4 a0 = *(float4*)&AsT[kk][ty * 8];
            float4 a1 = *(float4*)&AsT[kk][ty * 8 + 4];
            float ar[8] = {a0.x, a0.y, a0.z, a0.w, a1.x, a1.y, a1.z, a1.w};
#pragma unroll
            for (int r = 0; r < 8; r++) {
                acc[r][0] += ar[r] * b.x;
                acc[r][1] += ar[r] * b.y;
                acc[r][2] += ar[r] * b.z;
                acc[r][3] += ar[r] * b.w;
            }
        }
        __syncthreads();
    }
    float4 bb = make_float4(0.f, 0.f, 0.f, 0.f);
    if (bias) bb = *(const float4*)&bias[n0 + tx * 4];
#pragma unroll
    for (int r = 0; r < 8; r++) {
        int m = m0 + ty * 8 + r;
        if (m < M) {
            float4 v;
            v.x = acc[r][0] + bb.x; v.y = acc[r][1] + bb.y;
            v.z = acc[r][2] + bb.z; v.w = acc[r][3] + bb.w;
            *(float4*)&C[(size_t)m * Nn + n0 + tx * 4] = v;
        }
    }
}

// ---------------------------------------------------------------- attention source/dst logit terms, layer 1 (4 heads)
__global__ __launch_bounds__(256) void k_ald1(const float* __restrict__ xh, const float* __restrict__ as1,
                                              const float* __restrict__ ad1, float* __restrict__ als,
                                              float* __restrict__ ald) {
    int n = blockIdx.x;
    int w = threadIdx.x >> 6, l = threadIdx.x & 63;
    const float* xp = &xh[(size_t)n * 512 + w * 128];
    float2 v = *(const float2*)&xp[l * 2];
    float2 a = *(const float2*)&as1[w * 128 + l * 2];
    float2 b = *(const float2*)&ad1[w * 128 + l * 2];
    float ps = v.x * a.x + v.y * a.y, pd = v.x * b.x + v.y * b.y;
    for (int off = 32; off; off >>= 1) { ps += __shfl_down(ps, off); pd += __shfl_down(pd, off); }
    if (l == 0) { als[n * 4 + w] = ps; ald[n * 4 + w] = pd; }
}

// ---------------------------------------------------------------- same for layer 2 (1 head), 4 nodes / block
__global__ __launch_bounds__(256) void k_ald2(const float* __restrict__ xh2, const float* __restrict__ as2,
                                              const float* __restrict__ ad2, float* __restrict__ als,
                                              float* __restrict__ ald) {
    int w = threadIdx.x >> 6, l = threadIdx.x & 63;
    int n = blockIdx.x * 4 + w;
    if (n >= N_NODES) return;
    const float* xp = &xh2[(size_t)n * 128];
    float2 v = *(const float2*)&xp[l * 2];
    float2 a = *(const float2*)&as2[l * 2];
    float2 b = *(const float2*)&ad2[l * 2];
    float ps = v.x * a.x + v.y * a.y, pd = v.x * b.x + v.y * b.y;
    for (int off = 32; off; off >>= 1) { ps += __shfl_down(ps, off); pd += __shfl_down(pd, off); }
    if (l == 0) { als[n] = ps; ald[n] = pd; }
}

// ---------------------------------------------------------------- logits (CSR order), layer 1
__global__ void k_logits1(const int* __restrict__ csr_src, const int* __restrict__ csr_dst,
                          const int* __restrict__ csr_eid, const float* __restrict__ eattr,
                          const float* __restrict__ loopattr, const float* __restrict__ als,
                          const float* __restrict__ ald, const float* __restrict__ M1,
                          float* __restrict__ L1) {
    int p = blockIdx.x * 256 + threadIdx.x;
    if (p >= EN_TOT) return;
    int s = csr_src[p], d = csr_dst[p], eid = csr_eid[p];
    const float* eap = (eid < N_EDGES) ? &eattr[(size_t)eid * 4] : &loopattr[(size_t)(eid - N_EDGES) * 4];
    float4 e4 = *(const float4*)eap;
    float4 out;
    float* op = &out.x;
#pragma unroll
    for (int h = 0; h < 4; h++) {
        float ale = e4.x * M1[0 * 4 + h] + e4.y * M1[1 * 4 + h] + e4.z * M1[2 * 4 + h] + e4.w * M1[3 * 4 + h];
        float l = als[s * 4 + h] + ald[d * 4 + h] + ale;
        op[h] = (l >= 0.f) ? l : 0.2f * l;
    }
    *(float4*)&L1[(size_t)p * 4] = out;
}

// ---------------------------------------------------------------- logits (CSR order), layer 2
__global__ void k_logits2(const int* __restrict__ csr_src, const int* __restrict__ csr_dst,
                          const int* __restrict__ csr_eid, const float* __restrict__ eattr,
                          const float* __restrict__ loopattr, const float* __restrict__ als,
                          const float* __restrict__ ald, const float* __restrict__ m2,
                          float* __restrict__ L2) {
    int p = blockIdx.x * 256 + threadIdx.x;
    if (p >= EN_TOT) return;
    int s = csr_src[p], d = csr_dst[p], eid = csr_eid[p];
    const float* eap = (eid < N_EDGES) ? &eattr[(size_t)eid * 4] : &loopattr[(size_t)(eid - N_EDGES) * 4];
    float4 e4 = *(const float4*)eap;
    float l = als[s] + ald[d] + e4.x * m2[0] + e4.y * m2[1] + e4.z * m2[2] + e4.w * m2[3];
    L2[p] = (l >= 0.f) ? l : 0.2f * l;
}

// ---------------------------------------------------------------- layer-1 aggregation + bias + LN + ELU  (per node)
__global__ __launch_bounds__(256) void k_agg1(const int* __restrict__ offsets, const int* __restrict__ csr_src,
                                              const float* __restrict__ L1, const float* __restrict__ xh,
                                              const float* __restrict__ b1, const float* __restrict__ g1,
                                              const float* __restrict__ be1, float* __restrict__ h1out) {
    int n = blockIdx.x;
    int start = offsets[n];
    int cnt = offsets[n + 1] - start;
    int tid = threadIdx.x;
    __shared__ float red[256];
    __shared__ float mh[4], sh[4];
    __shared__ float sal[64][4];
    __shared__ int ssrc[64];
    __shared__ float sbc[2];
    int hh = tid & 3;
    // segment max per head
    float m = -1e30f;
    for (int j = tid >> 2; j < cnt; j += 64) m = fmaxf(m, L1[(size_t)(start + j) * 4 + hh]);
    red[tid] = m; __syncthreads();
    for (int s2 = 128; s2 >= 4; s2 >>= 1) { if (tid < s2) red[tid] = fmaxf(red[tid], red[tid + s2]); __syncthreads(); }
    if (tid < 4) mh[tid] = red[tid];
    __syncthreads();
    float mm = mh[hh];
    float ss = 0.f;
    for (int j = tid >> 2; j < cnt; j += 64) ss += expf(L1[(size_t)(start + j) * 4 + hh] - mm);
    red[tid] = ss; __syncthreads();
    for (int s2 = 128; s2 >= 4; s2 >>= 1) { if (tid < s2) red[tid] += red[tid + s2]; __syncthreads(); }
    if (tid < 4) sh[tid] = 1.0f / red[tid];
    __syncthreads();
    // weighted gather-accumulate; thread owns channels tid and tid+256
    float acc0 = 0.f, acc1 = 0.f;
    int ha = tid >> 7, hb = ha + 2;
    for (int base = 0; base < cnt; base += 64) {
        int mj = min(64, cnt - base);
        if (tid < mj) {
            int p = start + base + tid;
            ssrc[tid] = csr_src[p];
            float4 l4 = *(const float4*)&L1[(size_t)p * 4];
            sal[tid][0] = expf(l4.x - mh[0]) * sh[0];
            sal[tid][1] = expf(l4.y - mh[1]) * sh[1];
            sal[tid][2] = expf(l4.z - mh[2]) * sh[2];
            sal[tid][3] = expf(l4.w - mh[3]) * sh[3];
        }
        __syncthreads();
        for (int j = 0; j < mj; j++) {
            const float* xp = &xh[(size_t)ssrc[j] * 512];
            acc0 += sal[j][ha] * xp[tid];
            acc1 += sal[j][hb] * xp[tid + 256];
        }
        __syncthreads();
    }
    // + bias, LayerNorm(512), ELU
    float v0 = acc0 + b1[tid], v1 = acc1 + b1[tid + 256];
    red[tid] = v0 + v1; __syncthreads();
    for (int s2 = 128; s2 >= 1; s2 >>= 1) { if (tid < s2) red[tid] += red[tid + s2]; __syncthreads(); }
    if (tid == 0) sbc[0] = red[0] * (1.0f / 512.0f);
    __syncthreads();
    float mu = sbc[0];
    float d0 = v0 - mu, d1 = v1 - mu;
    red[tid] = d0 * d0 + d1 * d1; __syncthreads();
    for (int s2 = 128; s2 >= 1; s2 >>= 1) { if (tid < s2) red[tid] += red[tid + s2]; __syncthreads(); }
    if (tid == 0) sbc[1] = rsqrtf(red[0] * (1.0f / 512.0f) + 1e-5f);
    __syncthreads();
    float rstd = sbc[1];
    float y0 = d0 * rstd * g1[tid] + be1[tid];
    float y1 = d1 * rstd * g1[tid + 256] + be1[tid + 256];
    y0 = (y0 > 0.f) ? y0 : expm1f(y0);
    y1 = (y1 > 0.f) ? y1 : expm1f(y1);
    h1out[(size_t)n * 512 + tid] = y0;
    h1out[(size_t)n * 512 + tid + 256] = y1;
}

// ---------------------------------------------------------------- layer-2 aggregation + alpha out + bias + LN
__global__ __launch_bounds__(128) void k_agg2(const int* __restrict__ offsets, const int* __restrict__ csr_src,
                                              const int* __restrict__ csr_eid, const float* __restrict__ L2,
                                              const float* __restrict__ xh2, const float* __restrict__ b2,
                                              const float* __restrict__ g2, const float* __restrict__ be2,
                                              float* __restrict__ eaout, float* __restrict__ h2out) {
    int n = blockIdx.x;
    int start = offsets[n];
    int cnt = offsets[n + 1] - start;
    int tid = threadIdx.x;
    __shared__ float red[128];
    __shared__ float sal[128];
    __shared__ int ssrc[128];
    __shared__ float sbc[2];
    float m = -1e30f;
    for (int j = tid; j < cnt; j += 128) m = fmaxf(m, L2[start + j]);
    red[tid] = m; __syncthreads();
    for (int s2 = 64; s2 >= 1; s2 >>= 1) { if (tid < s2) red[tid] = fmaxf(red[tid], red[tid + s2]); __syncthreads(); }
    if (tid == 0) sbc[0] = red[0];
    __syncthreads();
    float mm = sbc[0];
    float ss = 0.f;
    for (int j = tid; j < cnt; j += 128) ss += expf(L2[start + j] - mm);
    red[tid] = ss; __syncthreads();
    for (int s2 = 64; s2 >= 1; s2 >>= 1) { if (tid < s2) red[tid] += red[tid + s2]; __syncthreads(); }
    if (tid == 0) sbc[1] = 1.0f / red[0];
    __syncthreads();
    float inv = sbc[1];
    float acc = 0.f;
    for (int base = 0; base < cnt; base += 128) {
        int mj = min(128, cnt - base);
        if (tid < mj) {
            int p = start + base + tid;
            float a = expf(L2[p] - mm) * inv;
            sal[tid] = a;
            ssrc[tid] = csr_src[p];
            eaout[csr_eid[p]] = a;   // edge_attention in original edge order
        }
        __syncthreads();
        for (int j = 0; j < mj; j++) acc += sal[j] * xh2[(size_t)ssrc[j] * 128 + tid];
        __syncthreads();
    }
    float v = acc + b2[tid];
    red[tid] = v; __syncthreads();
    for (int s2 = 64; s2 >= 1; s2 >>= 1) { if (tid < s2) red[tid] += red[tid + s2]; __syncthreads(); }
    if (tid == 0) sbc[0] = red[0] * (1.0f / 128.0f);
    __syncthreads();
    float mu = sbc[0];
    float d = v - mu;
    red[tid] = d * d; __syncthreads();
    for (int s2 = 64; s2 >= 1; s2 >>= 1) { if (tid < s2) red[tid] += red[tid + s2]; __syncthreads(); }
    if (tid == 0) sbc[1] = rsqrtf(red[0] * (1.0f / 128.0f) + 1e-5f);
    __syncthreads();
    h2out[(size_t)n * 128 + tid] = d * sbc[1] * g2[tid] + be2[tid];
}

// ---------------------------------------------------------------- importance = sigmoid(emb @ Wi + bi)
__global__ __launch_bounds__(256) void k_imp(const float* __restrict__ emb, const float* __restrict__ Wi,
                                             const float* __restrict__ bi, float* __restrict__ impout) {
    int w = threadIdx.x >> 6, l = threadIdx.x & 63;
    int n = blockIdx.x * 4 + w;
    if (n >= N_NODES) return;
    const float* ep = &emb[(size_t)n * 128];
    float p = ep[l] * Wi[l] + ep[l + 64] * Wi[l + 64];
    for (int off = 32; off; off >>= 1) p += __shfl_down(p, off);
    if (l == 0) impout[n] = 1.0f / (1.0f + expf(-(p + bi[0])));
}

// ================================================================ launch
extern "C" void kernel_launch(void* const* d_in, const int* in_sizes, int n_in,
                              void* d_out, int out_size, void* d_ws, size_t ws_size,
                              hipStream_t stream) {
    const float* x    = (const float*)d_in[0];
    const int*   eidx = (const int*)d_in[1];
    const float* eattr= (const float*)d_in[2];
    const float* Wp   = (const float*)d_in[3];
    const float* bp   = (const float*)d_in[4];
    const float* W1   = (const float*)d_in[5];
    const float* We1  = (const float*)d_in[6];
    const float* as1  = (const float*)d_in[7];
    const float* ad1  = (const float*)d_in[8];
    const float* ae1  = (const float*)d_in[9];
    const float* b1   = (const float*)d_in[10];
    const float* g1   = (const float*)d_in[11];
    const float* be1  = (const float*)d_in[12];
    const float* W2   = (const float*)d_in[13];
    const float* We2  = (const float*)d_in[14];
    const float* as2  = (const float*)d_in[15];
    const float* ad2  = (const float*)d_in[16];
    const float* ae2  = (const float*)d_in[17];
    const float* b2   = (const float*)d_in[18];
    const float* g2   = (const float*)d_in[19];
    const float* be2  = (const float*)d_in[20];
    const float* Wo   = (const float*)d_in[21];
    const float* bo   = (const float*)d_in[22];
    const float* Wi   = (const float*)d_in[23];
    const float* bi   = (const float*)d_in[24];

    const int* src = eidx;
    const int* dst = eidx + N_EDGES;

    float* emb_out = (float*)d_out;                       // [N,128]
    float* ea_out  = emb_out + (size_t)N_NODES * 128;     // [E+N]
    float* imp_out = ea_out + EN_TOT;                     // [N]

    // ---- workspace carve (all 256B aligned) ----
    char* w = (char*)d_ws;
    auto alloc = [&](size_t bytes) -> void* { void* p = (void*)w; w += (bytes + 255) & ~(size_t)255; return p; };
    float* xh      = (float*)alloc((size_t)N_NODES * 512 * 4);   // [N,512]
    float* h1      = (float*)alloc((size_t)N_NODES * 512 * 4);   // [N,512]
    float* h0      = (float*)alloc((size_t)N_NODES * 128 * 4);   // [N,128]  (reused as xh2)
    float* h2      = (float*)alloc((size_t)N_NODES * 128 * 4);   // [N,128]
    float* L1      = (float*)alloc((size_t)EN_TOT * 4 * 4);      // [E+N,4]
    float* L2      = (float*)alloc((size_t)EN_TOT * 4);          // [E+N]
    int*   csr_src = (int*)alloc((size_t)EN_TOT * 4);
    int*   csr_eid = (int*)alloc((size_t)EN_TOT * 4);
    int*   csr_dst = (int*)alloc((size_t)EN_TOT * 4);
    int*   offsets = (int*)alloc((size_t)(N_NODES + 1) * 4);
    int*   cursor  = (int*)alloc((size_t)N_NODES * 4);
    float* degf    = (float*)alloc((size_t)N_NODES * 4);
    float* loopat  = (float*)alloc((size_t)N_NODES * 4 * 4);
    float* als1v   = (float*)alloc((size_t)N_NODES * 4 * 4);
    float* ald1v   = (float*)alloc((size_t)N_NODES * 4 * 4);
    float* als2v   = (float*)alloc((size_t)N_NODES * 4);
    float* ald2v   = (float*)alloc((size_t)N_NODES * 4);
    float* M1      = (float*)alloc(32 * 4);                      // 16 + 4 used
    float* m2      = M1 + 16;
    float* xh2     = h0;                                          // alias: h0 dead after GEMM1

    hipMemsetAsync(degf,   0, (size_t)N_NODES * 4, stream);
    hipMemsetAsync(loopat, 0, (size_t)N_NODES * 16, stream);
    hipMemsetAsync(cursor, 0, (size_t)N_NODES * 4, stream);

    k_deg<<<(N_EDGES + 255) / 256, 256, 0, stream>>>(dst, eattr, degf, loopat);
    k_scan<<<1, 1024, 0, stream>>>(degf, loopat, offsets, We1, ae1, We2, ae2, M1, m2);
    k_fill<<<(EN_TOT + 255) / 256, 256, 0, stream>>>(src, dst, offsets, cursor, csr_src, csr_eid, csr_dst);
    k_proj<<<N_NODES / 2, 256, 0, stream>>>(x, Wp, bp, h0);

    // xh = h0 @ W1  [20000,128]x[128,512]
    k_gemm<<<dim3((N_NODES + 63) / 64, 4), 256, 0, stream>>>(h0, W1, xh, N_NODES, 512, 128, nullptr);
    k_ald1<<<N_NODES, 256, 0, stream>>>(xh, as1, ad1, als1v, ald1v);
    k_logits1<<<(EN_TOT + 255) / 256, 256, 0, stream>>>(csr_src, csr_dst, csr_eid, eattr, loopat,
                                                        als1v, ald1v, M1, L1);
    k_agg1<<<N_NODES, 256, 0, stream>>>(offsets, csr_src, L1, xh, b1, g1, be1, h1);

    // xh2 = h1 @ W2  [20000,512]x[512,128]
    k_gemm<<<dim3((N_NODES + 63) / 64, 1), 256, 0, stream>>>(h1, W2, xh2, N_NODES, 128, 512, nullptr);
    k_ald2<<<(N_NODES + 3) / 4, 256, 0, stream>>>(xh2, as2, ad2, als2v, ald2v);
    k_logits2<<<(EN_TOT + 255) / 256, 256, 0, stream>>>(csr_src, csr_dst, csr_eid, eattr, loopat,
                                                        als2v, ald2v, m2, L2);
    k_agg2<<<N_NODES, 128, 0, stream>>>(offsets, csr_src, csr_eid, L2, xh2, b2, g2, be2, ea_out, h2);

    // emb = h2 @ Wo + bo  -> d_out
    k_gemm<<<dim3((N_NODES + 63) / 64, 1), 256, 0, stream>>>(h2, Wo, emb_out, N_NODES, 128, 128, bo);
    k_imp<<<(N_NODES + 3) / 4, 256, 0, stream>>>(emb_out, Wi, bi, imp_out);
}

// Round 3
// 385.655 us; speedup vs baseline: 1.2516x; 1.2516x over previous
//
#include <hip/hip_runtime.h>
#include <math.h>
#include <stdint.h>

#define N_NODES 20000
#define N_EDGES 320000
#define EN_TOT  340000   // E + N (with self loops)

typedef __attribute__((ext_vector_type(8))) _Float16 half8v;  // 8 fp16 (4 VGPRs)
typedef __attribute__((ext_vector_type(4))) float float4v;    // MFMA accumulator

__device__ __forceinline__ ushort f2h(float f) {              // fp32 -> fp16 RNE
    _Float16 h = (_Float16)f;
    return __builtin_bit_cast(ushort, h);
}
__device__ __forceinline__ float h2f(ushort s) {
    return (float)__builtin_bit_cast(_Float16, s);
}

// ---------------------------------------------------------------- degree + loop-attr sums
__global__ void k_deg(const int* __restrict__ dst, const float* __restrict__ eattr,
                      float* __restrict__ degf, float* __restrict__ loopsum) {
    int e = blockIdx.x * 256 + threadIdx.x;
    if (e >= N_EDGES) return;
    int d = dst[e];
    atomicAdd(&degf[d], 1.0f);
#pragma unroll
    for (int f = 0; f < 4; f++) atomicAdd(&loopsum[d * 4 + f], eattr[e * 4 + f]);
}

// ---------------------------------------------------------------- scan (offsets), loop_attr normalize, M1/m2 fold
__global__ __launch_bounds__(1024) void k_scan(const float* __restrict__ degf,
                                               float* __restrict__ loopattr, int* __restrict__ offsets,
                                               const float* __restrict__ We1, const float* __restrict__ ae1,
                                               const float* __restrict__ We2, const float* __restrict__ ae2,
                                               float* __restrict__ M1, float* __restrict__ m2) {
    __shared__ int s[1024];
    int t = threadIdx.x;
    int n0 = t * 20;
    int tot = 0;
    for (int i = 0; i < 20; i++) {
        int n = n0 + i;
        if (n < N_NODES) tot += (int)(degf[n] + 0.5f) + 1;
    }
    s[t] = tot;
    __syncthreads();
    for (int off = 1; off < 1024; off <<= 1) {
        int v = (t >= off) ? s[t - off] : 0;
        __syncthreads();
        s[t] += v;
        __syncthreads();
    }
    int run = s[t] - tot;
    for (int i = 0; i < 20; i++) {
        int n = n0 + i;
        if (n < N_NODES) {
            offsets[n] = run;
            run += (int)(degf[n] + 0.5f) + 1;
        }
    }
    if (t == 1023) offsets[N_NODES] = s[1023];
    for (int n = t; n < N_NODES; n += 1024) {
        float inv = 1.0f / fmaxf(degf[n], 1.0f);
#pragma unroll
        for (int f = 0; f < 4; f++) loopattr[n * 4 + f] *= inv;
    }
    if (t < 16) {
        int f = t >> 2, h = t & 3;
        float acc = 0.f;
        for (int c = 0; c < 128; c++) acc += We1[f * 512 + h * 128 + c] * ae1[h * 128 + c];
        M1[f * 4 + h] = acc;
    } else if (t < 20) {
        int f = t - 16;
        float acc = 0.f;
        for (int c = 0; c < 128; c++) acc += We2[f * 128 + c] * ae2[c];
        m2[f] = acc;
    }
}

// ---------------------------------------------------------------- CSR fill (edges + self loops)
__global__ void k_fill(const int* __restrict__ src, const int* __restrict__ dst,
                       const int* __restrict__ offsets, int* __restrict__ cursor,
                       int* __restrict__ csr_src, int* __restrict__ csr_eid, int* __restrict__ csr_dst) {
    int i = blockIdx.x * 256 + threadIdx.x;
    if (i >= EN_TOT) return;
    int d, sidx, eid;
    if (i < N_EDGES) { d = dst[i]; sidx = src[i]; eid = i; }
    else { int n = i - N_EDGES; d = n; sidx = n; eid = N_EDGES + n; }
    int pos = offsets[d] + atomicAdd(&cursor[d], 1);
    csr_src[pos] = sidx;
    csr_eid[pos] = eid;
    csr_dst[pos] = d;
}

// ---------------------------------------------------------------- weight transpose + fp16 convert
__global__ void k_prep(const float* __restrict__ W1, const float* __restrict__ W2,
                       const float* __restrict__ Wo, ushort* __restrict__ W1T,
                       ushort* __restrict__ W2T, ushort* __restrict__ WoT) {
    int i = blockIdx.x * 256 + threadIdx.x;
    if (i < 512 * 128) {                       // W1T[n][k] = W1[k][n], n<512 k<128
        int nn = i >> 7, kk = i & 127;
        W1T[i] = f2h(W1[kk * 512 + nn]);
    } else if (i < 2 * 512 * 128) {            // W2T[n][k] = W2[k][n], n<128 k<512
        int j = i - 512 * 128;
        int nn = j >> 9, kk = j & 511;
        W2T[j] = f2h(W2[kk * 128 + nn]);
    } else if (i < 2 * 512 * 128 + 128 * 128) {// WoT[n][k] = Wo[k][n], n<128 k<128
        int j = i - 2 * 512 * 128;
        int nn = j >> 7, kk = j & 127;
        WoT[j] = f2h(Wo[kk * 128 + nn]);
    }
}

// ---------------------------------------------------------------- input proj: h0 = x @ Wp + bp (fp16 out)
__global__ __launch_bounds__(256) void k_proj(const float* __restrict__ x, const float* __restrict__ Wp,
                                              const float* __restrict__ bp, ushort* __restrict__ h0h) {
    int tid = threadIdx.x;
    int n = blockIdx.x * 2 + (tid >> 7);
    int c = tid & 127;
    float acc = bp[c];
#pragma unroll
    for (int f = 0; f < 4; f++) acc += x[n * 4 + f] * Wp[f * 128 + c];
    h0h[(size_t)n * 128 + c] = f2h(acc);
}

// ---------------------------------------------------------------- MFMA fp16 GEMM: C[M,Nn] = A[M,K] @ BT[Nn,K]^T
// 128x128 tile, BK=64, 4 waves (each 64x64), XOR-swizzled LDS, fp32 and/or fp16 out.
__global__ __launch_bounds__(256) void k_gemm_hf(const ushort* __restrict__ A, const ushort* __restrict__ BT,
                                                 float* __restrict__ Cf, ushort* __restrict__ Ch,
                                                 int M, int Nn, int K, const float* __restrict__ bias) {
    __shared__ ushort As[128 * 64];
    __shared__ ushort Bs[128 * 64];
    const int tid = threadIdx.x;
    const int lane = tid & 63, wid = tid >> 6;
    const int wr = wid >> 1, wc = wid & 1;
    const int m0 = blockIdx.x * 128, n0 = blockIdx.y * 128;
    float4v acc[4][4];
#pragma unroll
    for (int i = 0; i < 4; i++)
#pragma unroll
        for (int j = 0; j < 4; j++) acc[i][j] = (float4v){0.f, 0.f, 0.f, 0.f};

    for (int k0 = 0; k0 < K; k0 += 64) {
        __syncthreads();
#pragma unroll
        for (int i = 0; i < 4; i++) {
            int c = tid + i * 256;             // 0..1023
            int row = c >> 3, sl = c & 7;      // 8 x 16B chunks per 64-elem row
            int off = row * 128 + ((sl ^ (row & 7)) << 4);
            uint4 va = make_uint4(0u, 0u, 0u, 0u);
            if (m0 + row < M) va = *(const uint4*)&A[(size_t)(m0 + row) * K + k0 + sl * 8];
            *(uint4*)((char*)As + off) = va;
            uint4 vb = *(const uint4*)&BT[(size_t)(n0 + row) * K + k0 + sl * 8];
            *(uint4*)((char*)Bs + off) = vb;
        }
        __syncthreads();
#pragma unroll
        for (int kk = 0; kk < 2; kk++) {
            half8v af[4], bq[4];
            int sl = kk * 4 + (lane >> 4);     // 16B slot: k = kk*32 + (lane>>4)*8
            int ra = wr * 64 + (lane & 15);
            int rb = wc * 64 + (lane & 15);
#pragma unroll
            for (int mi = 0; mi < 4; mi++) {
                int row = ra + mi * 16;
                af[mi] = *(const half8v*)((const char*)As + row * 128 + ((sl ^ (row & 7)) << 4));
            }
#pragma unroll
            for (int ni = 0; ni < 4; ni++) {
                int row = rb + ni * 16;
                bq[ni] = *(const half8v*)((const char*)Bs + row * 128 + ((sl ^ (row & 7)) << 4));
            }
#pragma unroll
            for (int mi = 0; mi < 4; mi++)
#pragma unroll
                for (int ni = 0; ni < 4; ni++)
                    acc[mi][ni] = __builtin_amdgcn_mfma_f32_16x16x32_f16(af[mi], bq[ni], acc[mi][ni], 0, 0, 0);
        }
    }
#pragma unroll
    for (int mi = 0; mi < 4; mi++) {
#pragma unroll
        for (int j = 0; j < 4; j++) {
            int row = m0 + wr * 64 + mi * 16 + ((lane >> 4) << 2) + j;
            if (row < M) {
#pragma unroll
                for (int ni = 0; ni < 4; ni++) {
                    int col = n0 + wc * 64 + ni * 16 + (lane & 15);
                    float v = acc[mi][ni][j];
                    if (bias) v += bias[col];
                    if (Cf) Cf[(size_t)row * Nn + col] = v;
                    if (Ch) Ch[(size_t)row * Nn + col] = f2h(v);
                }
            }
        }
    }
}

// ---------------------------------------------------------------- attention src/dst logit terms, layer 1 (fp16 xh)
__global__ __launch_bounds__(256) void k_ald1(const ushort* __restrict__ xhh, const float* __restrict__ as1,
                                              const float* __restrict__ ad1, float* __restrict__ als,
                                              float* __restrict__ ald) {
    int n = blockIdx.x;
    int w = threadIdx.x >> 6, l = threadIdx.x & 63;
    uint v = *(const uint*)&xhh[(size_t)n * 512 + w * 128 + l * 2];
    float f0 = h2f((ushort)(v & 0xffffu));
    float f1 = h2f((ushort)(v >> 16));
    float2 a = *(const float2*)&as1[w * 128 + l * 2];
    float2 b = *(const float2*)&ad1[w * 128 + l * 2];
    float ps = f0 * a.x + f1 * a.y, pd = f0 * b.x + f1 * b.y;
    for (int off = 32; off; off >>= 1) { ps += __shfl_down(ps, off); pd += __shfl_down(pd, off); }
    if (l == 0) { als[n * 4 + w] = ps; ald[n * 4 + w] = pd; }
}

// ---------------------------------------------------------------- same for layer 2 (1 head)
__global__ __launch_bounds__(256) void k_ald2(const ushort* __restrict__ xh2h, const float* __restrict__ as2,
                                              const float* __restrict__ ad2, float* __restrict__ als,
                                              float* __restrict__ ald) {
    int w = threadIdx.x >> 6, l = threadIdx.x & 63;
    int n = blockIdx.x * 4 + w;
    if (n >= N_NODES) return;
    uint v = *(const uint*)&xh2h[(size_t)n * 128 + l * 2];
    float f0 = h2f((ushort)(v & 0xffffu));
    float f1 = h2f((ushort)(v >> 16));
    float2 a = *(const float2*)&as2[l * 2];
    float2 b = *(const float2*)&ad2[l * 2];
    float ps = f0 * a.x + f1 * a.y, pd = f0 * b.x + f1 * b.y;
    for (int off = 32; off; off >>= 1) { ps += __shfl_down(ps, off); pd += __shfl_down(pd, off); }
    if (l == 0) { als[n] = ps; ald[n] = pd; }
}

// ---------------------------------------------------------------- logits (CSR order), layer 1
__global__ void k_logits1(const int* __restrict__ csr_src, const int* __restrict__ csr_dst,
                          const int* __restrict__ csr_eid, const float* __restrict__ eattr,
                          const float* __restrict__ loopattr, const float* __restrict__ als,
                          const float* __restrict__ ald, const float* __restrict__ M1,
                          float* __restrict__ L1) {
    int p = blockIdx.x * 256 + threadIdx.x;
    if (p >= EN_TOT) return;
    int s = csr_src[p], d = csr_dst[p], eid = csr_eid[p];
    const float* eap = (eid < N_EDGES) ? &eattr[(size_t)eid * 4] : &loopattr[(size_t)(eid - N_EDGES) * 4];
    float4 e4 = *(const float4*)eap;
    float4 out;
    float* op = &out.x;
#pragma unroll
    for (int h = 0; h < 4; h++) {
        float ale = e4.x * M1[0 * 4 + h] + e4.y * M1[1 * 4 + h] + e4.z * M1[2 * 4 + h] + e4.w * M1[3 * 4 + h];
        float l = als[s * 4 + h] + ald[d * 4 + h] + ale;
        op[h] = (l >= 0.f) ? l : 0.2f * l;
    }
    *(float4*)&L1[(size_t)p * 4] = out;
}

// ---------------------------------------------------------------- logits (CSR order), layer 2
__global__ void k_logits2(const int* __restrict__ csr_src, const int* __restrict__ csr_dst,
                          const int* __restrict__ csr_eid, const float* __restrict__ eattr,
                          const float* __restrict__ loopattr, const float* __restrict__ als,
                          const float* __restrict__ ald, const float* __restrict__ m2,
                          float* __restrict__ L2) {
    int p = blockIdx.x * 256 + threadIdx.x;
    if (p >= EN_TOT) return;
    int s = csr_src[p], d = csr_dst[p], eid = csr_eid[p];
    const float* eap = (eid < N_EDGES) ? &eattr[(size_t)eid * 4] : &loopattr[(size_t)(eid - N_EDGES) * 4];
    float4 e4 = *(const float4*)eap;
    float l = als[s] + ald[d] + e4.x * m2[0] + e4.y * m2[1] + e4.z * m2[2] + e4.w * m2[3];
    L2[p] = (l >= 0.f) ? l : 0.2f * l;
}

// ---------------------------------------------------------------- layer-1 aggregation + bias + LN + ELU (fp16 in/out)
__global__ __launch_bounds__(256) void k_agg1(const int* __restrict__ offsets, const int* __restrict__ csr_src,
                                              const float* __restrict__ L1, const ushort* __restrict__ xhh,
                                              const float* __restrict__ b1, const float* __restrict__ g1,
                                              const float* __restrict__ be1, ushort* __restrict__ h1h) {
    int n = blockIdx.x;
    int start = offsets[n];
    int cnt = offsets[n + 1] - start;
    int tid = threadIdx.x;
    __shared__ float red[256];
    __shared__ float mh[4], sh[4];
    __shared__ float sal[64][4];
    __shared__ int ssrc[64];
    __shared__ float sbc[2];
    int hh = tid & 3;
    float m = -1e30f;
    for (int j = tid >> 2; j < cnt; j += 64) m = fmaxf(m, L1[(size_t)(start + j) * 4 + hh]);
    red[tid] = m; __syncthreads();
    for (int s2 = 128; s2 >= 4; s2 >>= 1) { if (tid < s2) red[tid] = fmaxf(red[tid], red[tid + s2]); __syncthreads(); }
    if (tid < 4) mh[tid] = red[tid];
    __syncthreads();
    float mm = mh[hh];
    float ss = 0.f;
    for (int j = tid >> 2; j < cnt; j += 64) ss += expf(L1[(size_t)(start + j) * 4 + hh] - mm);
    red[tid] = ss; __syncthreads();
    for (int s2 = 128; s2 >= 4; s2 >>= 1) { if (tid < s2) red[tid] += red[tid + s2]; __syncthreads(); }
    if (tid < 4) sh[tid] = 1.0f / red[tid];
    __syncthreads();
    // gather: thread owns channels 2t, 2t+1 (one uint = 2 fp16 per edge)
    float acc0 = 0.f, acc1 = 0.f;
    int hg = tid >> 6;   // head of channels 2t,2t+1
    for (int base = 0; base < cnt; base += 64) {
        int mj = min(64, cnt - base);
        if (tid < mj) {
            int p = start + base + tid;
            ssrc[tid] = csr_src[p];
            float4 l4 = *(const float4*)&L1[(size_t)p * 4];
            sal[tid][0] = expf(l4.x - mh[0]) * sh[0];
            sal[tid][1] = expf(l4.y - mh[1]) * sh[1];
            sal[tid][2] = expf(l4.z - mh[2]) * sh[2];
            sal[tid][3] = expf(l4.w - mh[3]) * sh[3];
        }
        __syncthreads();
        for (int j = 0; j < mj; j++) {
            float a = sal[j][hg];
            uint v = *(const uint*)&xhh[(size_t)ssrc[j] * 512 + tid * 2];
            acc0 += a * h2f((ushort)(v & 0xffffu));
            acc1 += a * h2f((ushort)(v >> 16));
        }
        __syncthreads();
    }
    // + bias, LayerNorm(512), ELU
    float2 bb = *(const float2*)&b1[tid * 2];
    float v0 = acc0 + bb.x, v1 = acc1 + bb.y;
    red[tid] = v0 + v1; __syncthreads();
    for (int s2 = 128; s2 >= 1; s2 >>= 1) { if (tid < s2) red[tid] += red[tid + s2]; __syncthreads(); }
    if (tid == 0) sbc[0] = red[0] * (1.0f / 512.0f);
    __syncthreads();
    float mu = sbc[0];
    float d0 = v0 - mu, d1 = v1 - mu;
    red[tid] = d0 * d0 + d1 * d1; __syncthreads();
    for (int s2 = 128; s2 >= 1; s2 >>= 1) { if (tid < s2) red[tid] += red[tid + s2]; __syncthreads(); }
    if (tid == 0) sbc[1] = rsqrtf(red[0] * (1.0f / 512.0f) + 1e-5f);
    __syncthreads();
    float rstd = sbc[1];
    float2 gg = *(const float2*)&g1[tid * 2];
    float2 ee = *(const float2*)&be1[tid * 2];
    float y0 = d0 * rstd * gg.x + ee.x;
    float y1 = d1 * rstd * gg.y + ee.y;
    y0 = (y0 > 0.f) ? y0 : expm1f(y0);
    y1 = (y1 > 0.f) ? y1 : expm1f(y1);
    uint o = (uint)f2h(y0) | ((uint)f2h(y1) << 16);
    *(uint*)&h1h[(size_t)n * 512 + tid * 2] = o;
}

// ---------------------------------------------------------------- layer-2 aggregation + alpha out + bias + LN (fp16)
__global__ __launch_bounds__(128) void k_agg2(const int* __restrict__ offsets, const int* __restrict__ csr_src,
                                              const int* __restrict__ csr_eid, const float* __restrict__ L2,
                                              const ushort* __restrict__ xh2h, const float* __restrict__ b2,
                                              const float* __restrict__ g2, const float* __restrict__ be2,
                                              float* __restrict__ eaout, ushort* __restrict__ h2h) {
    int n = blockIdx.x;
    int start = offsets[n];
    int cnt = offsets[n + 1] - start;
    int tid = threadIdx.x;
    __shared__ float red[128];
    __shared__ float sal[128];
    __shared__ int ssrc[128];
    __shared__ float sbc[2];
    float m = -1e30f;
    for (int j = tid; j < cnt; j += 128) m = fmaxf(m, L2[start + j]);
    red[tid] = m; __syncthreads();
    for (int s2 = 64; s2 >= 1; s2 >>= 1) { if (tid < s2) red[tid] = fmaxf(red[tid], red[tid + s2]); __syncthreads(); }
    if (tid == 0) sbc[0] = red[0];
    __syncthreads();
    float mm = sbc[0];
    float ss = 0.f;
    for (int j = tid; j < cnt; j += 128) ss += expf(L2[start + j] - mm);
    red[tid] = ss; __syncthreads();
    for (int s2 = 64; s2 >= 1; s2 >>= 1) { if (tid < s2) red[tid] += red[tid + s2]; __syncthreads(); }
    if (tid == 0) sbc[1] = 1.0f / red[0];
    __syncthreads();
    float inv = sbc[1];
    float acc = 0.f;
    for (int base = 0; base < cnt; base += 128) {
        int mj = min(128, cnt - base);
        if (tid < mj) {
            int p = start + base + tid;
            float a = expf(L2[p] - mm) * inv;
            sal[tid] = a;
            ssrc[tid] = csr_src[p];
            eaout[csr_eid[p]] = a;
        }
        __syncthreads();
        for (int j = 0; j < mj; j++) acc += sal[j] * h2f(xh2h[(size_t)ssrc[j] * 128 + tid]);
        __syncthreads();
    }
    float v = acc + b2[tid];
    red[tid] = v; __syncthreads();
    for (int s2 = 64; s2 >= 1; s2 >>= 1) { if (tid < s2) red[tid] += red[tid + s2]; __syncthreads(); }
    if (tid == 0) sbc[0] = red[0] * (1.0f / 128.0f);
    __syncthreads();
    float mu = sbc[0];
    float d = v - mu;
    red[tid] = d * d; __syncthreads();
    for (int s2 = 64; s2 >= 1; s2 >>= 1) { if (tid < s2) red[tid] += red[tid + s2]; __syncthreads(); }
    if (tid == 0) sbc[1] = rsqrtf(red[0] * (1.0f / 128.0f) + 1e-5f);
    __syncthreads();
    h2h[(size_t)n * 128 + tid] = f2h(d * sbc[1] * g2[tid] + be2[tid]);
}

// ---------------------------------------------------------------- importance = sigmoid(emb @ Wi + bi)
__global__ __launch_bounds__(256) void k_imp(const float* __restrict__ emb, const float* __restrict__ Wi,
                                             const float* __restrict__ bi, float* __restrict__ impout) {
    int w = threadIdx.x >> 6, l = threadIdx.x & 63;
    int n = blockIdx.x * 4 + w;
    if (n >= N_NODES) return;
    const float* ep = &emb[(size_t)n * 128];
    float p = ep[l] * Wi[l] + ep[l + 64] * Wi[l + 64];
    for (int off = 32; off; off >>= 1) p += __shfl_down(p, off);
    if (l == 0) impout[n] = 1.0f / (1.0f + expf(-(p + bi[0])));
}

// ================================================================ launch
extern "C" void kernel_launch(void* const* d_in, const int* in_sizes, int n_in,
                              void* d_out, int out_size, void* d_ws, size_t ws_size,
                              hipStream_t stream) {
    const float* x    = (const float*)d_in[0];
    const int*   eidx = (const int*)d_in[1];
    const float* eattr= (const float*)d_in[2];
    const float* Wp   = (const float*)d_in[3];
    const float* bp   = (const float*)d_in[4];
    const float* W1   = (const float*)d_in[5];
    const float* We1  = (const float*)d_in[6];
    const float* as1  = (const float*)d_in[7];
    const float* ad1  = (const float*)d_in[8];
    const float* ae1  = (const float*)d_in[9];
    const float* b1   = (const float*)d_in[10];
    const float* g1   = (const float*)d_in[11];
    const float* be1  = (const float*)d_in[12];
    const float* W2   = (const float*)d_in[13];
    const float* We2  = (const float*)d_in[14];
    const float* as2  = (const float*)d_in[15];
    const float* ad2  = (const float*)d_in[16];
    const float* ae2  = (const float*)d_in[17];
    const float* b2   = (const float*)d_in[18];
    const float* g2   = (const float*)d_in[19];
    const float* be2  = (const float*)d_in[20];
    const float* Wo   = (const float*)d_in[21];
    const float* bo   = (const float*)d_in[22];
    const float* Wi   = (const float*)d_in[23];
    const float* bi   = (const float*)d_in[24];

    const int* src = eidx;
    const int* dst = eidx + N_EDGES;

    float* emb_out = (float*)d_out;                       // [N,128]
    float* ea_out  = emb_out + (size_t)N_NODES * 128;     // [E+N]
    float* imp_out = ea_out + EN_TOT;                     // [N]

    // ---- workspace carve (256B aligned) ----
    char* w = (char*)d_ws;
    auto alloc = [&](size_t bytes) -> void* { void* p = (void*)w; w += (bytes + 255) & ~(size_t)255; return p; };
    ushort* xhh    = (ushort*)alloc((size_t)N_NODES * 512 * 2);  // [N,512] fp16
    ushort* h1h    = (ushort*)alloc((size_t)N_NODES * 512 * 2);  // [N,512] fp16
    ushort* h0h    = (ushort*)alloc((size_t)N_NODES * 128 * 2);  // [N,128] fp16
    ushort* xh2h   = (ushort*)alloc((size_t)N_NODES * 128 * 2);  // [N,128] fp16
    ushort* h2h    = (ushort*)alloc((size_t)N_NODES * 128 * 2);  // [N,128] fp16
    ushort* W1T    = (ushort*)alloc((size_t)512 * 128 * 2);
    ushort* W2T    = (ushort*)alloc((size_t)128 * 512 * 2);
    ushort* WoT    = (ushort*)alloc((size_t)128 * 128 * 2);
    float* L1      = (float*)alloc((size_t)EN_TOT * 4 * 4);      // [E+N,4]
    float* L2      = (float*)alloc((size_t)EN_TOT * 4);          // [E+N]
    int*   csr_src = (int*)alloc((size_t)EN_TOT * 4);
    int*   csr_eid = (int*)alloc((size_t)EN_TOT * 4);
    int*   csr_dst = (int*)alloc((size_t)EN_TOT * 4);
    int*   offsets = (int*)alloc((size_t)(N_NODES + 1) * 4);
    int*   cursor  = (int*)alloc((size_t)N_NODES * 4);
    float* degf    = (float*)alloc((size_t)N_NODES * 4);
    float* loopat  = (float*)alloc((size_t)N_NODES * 4 * 4);
    float* als1v   = (float*)alloc((size_t)N_NODES * 4 * 4);
    float* ald1v   = (float*)alloc((size_t)N_NODES * 4 * 4);
    float* als2v   = (float*)alloc((size_t)N_NODES * 4);
    float* ald2v   = (float*)alloc((size_t)N_NODES * 4);
    float* M1      = (float*)alloc(32 * 4);
    float* m2      = M1 + 16;

    hipMemsetAsync(degf,   0, (size_t)N_NODES * 4, stream);
    hipMemsetAsync(loopat, 0, (size_t)N_NODES * 16, stream);
    hipMemsetAsync(cursor, 0, (size_t)N_NODES * 4, stream);

    k_deg<<<(N_EDGES + 255) / 256, 256, 0, stream>>>(dst, eattr, degf, loopat);
    k_scan<<<1, 1024, 0, stream>>>(degf, loopat, offsets, We1, ae1, We2, ae2, M1, m2);
    k_fill<<<(EN_TOT + 255) / 256, 256, 0, stream>>>(src, dst, offsets, cursor, csr_src, csr_eid, csr_dst);
    k_prep<<<576, 256, 0, stream>>>(W1, W2, Wo, W1T, W2T, WoT);
    k_proj<<<N_NODES / 2, 256, 0, stream>>>(x, Wp, bp, h0h);

    // xh = h0 @ W1   [20000,128] x [128,512] -> fp16
    k_gemm_hf<<<dim3((N_NODES + 127) / 128, 4), 256, 0, stream>>>(h0h, W1T, nullptr, xhh,
                                                                  N_NODES, 512, 128, nullptr);
    k_ald1<<<N_NODES, 256, 0, stream>>>(xhh, as1, ad1, als1v, ald1v);
    k_logits1<<<(EN_TOT + 255) / 256, 256, 0, stream>>>(csr_src, csr_dst, csr_eid, eattr, loopat,
                                                        als1v, ald1v, M1, L1);
    k_agg1<<<N_NODES, 256, 0, stream>>>(offsets, csr_src, L1, xhh, b1, g1, be1, h1h);

    // xh2 = h1 @ W2  [20000,512] x [512,128] -> fp16
    k_gemm_hf<<<dim3((N_NODES + 127) / 128, 1), 256, 0, stream>>>(h1h, W2T, nullptr, xh2h,
                                                                  N_NODES, 128, 512, nullptr);
    k_ald2<<<(N_NODES + 3) / 4, 256, 0, stream>>>(xh2h, as2, ad2, als2v, ald2v);
    k_logits2<<<(EN_TOT + 255) / 256, 256, 0, stream>>>(csr_src, csr_dst, csr_eid, eattr, loopat,
                                                        als2v, ald2v, m2, L2);
    k_agg2<<<N_NODES, 128, 0, stream>>>(offsets, csr_src, csr_eid, L2, xh2h, b2, g2, be2, ea_out, h2h);

    // emb = h2 @ Wo + bo -> d_out (fp32)
    k_gemm_hf<<<dim3((N_NODES + 127) / 128, 1), 256, 0, stream>>>(h2h, WoT, emb_out, nullptr,
                                                                  N_NODES, 128, 128, bo);
    k_imp<<<(N_NODES + 3) / 4, 256, 0, stream>>>(emb_out, Wi, bi, imp_out);
}

// Round 4
// 308.835 us; speedup vs baseline: 1.5629x; 1.2487x over previous
//
#include <hip/hip_runtime.h>
#include <math.h>
#include <stdint.h>

#define N_NODES 20000
#define N_EDGES 320000
#define EN_TOT  340000   // E + N (with self loops)

typedef __attribute__((ext_vector_type(8))) _Float16 half8v;  // 8 fp16 (4 VGPRs)
typedef __attribute__((ext_vector_type(4))) float float4v;    // MFMA accumulator

__device__ __forceinline__ ushort f2h(float f) {              // fp32 -> fp16 RNE
    _Float16 h = (_Float16)f;
    return __builtin_bit_cast(ushort, h);
}
__device__ __forceinline__ float h2f(ushort s) {
    return (float)__builtin_bit_cast(_Float16, s);
}

// ---------------------------------------------------------------- degree count (1 int atomic / edge)
__global__ void k_deg(const int* __restrict__ dst, int* __restrict__ degi) {
    int e = blockIdx.x * 256 + threadIdx.x;
    if (e >= N_EDGES) return;
    atomicAdd(&degi[dst[e]], 1);
}

// ---------------------------------------------------------------- scan (offsets) + M1/m2 fold
__global__ __launch_bounds__(1024) void k_scan(const int* __restrict__ degi, int* __restrict__ offsets,
                                               const float* __restrict__ We1, const float* __restrict__ ae1,
                                               const float* __restrict__ We2, const float* __restrict__ ae2,
                                               float* __restrict__ M1, float* __restrict__ m2) {
    __shared__ int s[1024];
    int t = threadIdx.x;
    int n0 = t * 20;
    int tot = 0;
    for (int i = 0; i < 20; i++) {
        int n = n0 + i;
        if (n < N_NODES) tot += degi[n] + 1;
    }
    s[t] = tot;
    __syncthreads();
    for (int off = 1; off < 1024; off <<= 1) {
        int v = (t >= off) ? s[t - off] : 0;
        __syncthreads();
        s[t] += v;
        __syncthreads();
    }
    int run = s[t] - tot;
    for (int i = 0; i < 20; i++) {
        int n = n0 + i;
        if (n < N_NODES) {
            offsets[n] = run;
            run += degi[n] + 1;
        }
    }
    if (t == 1023) offsets[N_NODES] = s[1023];
    // fold edge-attr projections: M1[f][h] = sum_c We1[f, h*128+c] * ae1[h,c];  m2[f] = sum_c We2[f,c]*ae2[c]
    if (t < 16) {
        int f = t >> 2, h = t & 3;
        float acc = 0.f;
        for (int c = 0; c < 128; c++) acc += We1[f * 512 + h * 128 + c] * ae1[h * 128 + c];
        M1[f * 4 + h] = acc;
    } else if (t < 20) {
        int f = t - 16;
        float acc = 0.f;
        for (int c = 0; c < 128; c++) acc += We2[f * 128 + c] * ae2[c];
        m2[f] = acc;
    }
}

// ---------------------------------------------------------------- CSR fill (edges + self loops)
__global__ void k_fill(const int* __restrict__ src, const int* __restrict__ dst,
                       const int* __restrict__ offsets, int* __restrict__ cursor,
                       int* __restrict__ csr_src, int* __restrict__ csr_eid, int* __restrict__ csr_dst) {
    int i = blockIdx.x * 256 + threadIdx.x;
    if (i >= EN_TOT) return;
    int d, sidx, eid;
    if (i < N_EDGES) { d = dst[i]; sidx = src[i]; eid = i; }
    else { int n = i - N_EDGES; d = n; sidx = n; eid = N_EDGES + n; }
    int pos = offsets[d] + atomicAdd(&cursor[d], 1);
    csr_src[pos] = sidx;
    csr_eid[pos] = eid;
    csr_dst[pos] = d;
}

// ---------------------------------------------------------------- loop_attr = mean of incoming eattr (no atomics)
__global__ __launch_bounds__(256) void k_loopattr(const int* __restrict__ offsets,
                                                  const int* __restrict__ csr_eid,
                                                  const float* __restrict__ eattr,
                                                  float* __restrict__ loopattr) {
    int wv = threadIdx.x >> 6, l = threadIdx.x & 63;
    int n = blockIdx.x * 4 + wv;
    if (n >= N_NODES) return;
    int start = offsets[n], end = offsets[n + 1];
    float sx = 0.f, sy = 0.f, sz = 0.f, sw = 0.f;
    for (int p = start + l; p < end; p += 64) {
        int eid = csr_eid[p];
        if (eid < N_EDGES) {
            float4 e = *(const float4*)&eattr[(size_t)eid * 4];
            sx += e.x; sy += e.y; sz += e.z; sw += e.w;
        }
    }
    for (int off = 32; off; off >>= 1) {
        sx += __shfl_down(sx, off);
        sy += __shfl_down(sy, off);
        sz += __shfl_down(sz, off);
        sw += __shfl_down(sw, off);
    }
    if (l == 0) {
        float inv = 1.0f / fmaxf((float)(end - start - 1), 1.0f);
        float4 o;
        o.x = sx * inv; o.y = sy * inv; o.z = sz * inv; o.w = sw * inv;
        *(float4*)&loopattr[(size_t)n * 4] = o;
    }
}

// ---------------------------------------------------------------- weight transpose + fp16 convert
__global__ void k_prep(const float* __restrict__ W1, const float* __restrict__ W2,
                       const float* __restrict__ Wo, ushort* __restrict__ W1T,
                       ushort* __restrict__ W2T, ushort* __restrict__ WoT) {
    int i = blockIdx.x * 256 + threadIdx.x;
    if (i < 512 * 128) {                       // W1T[n][k] = W1[k][n], n<512 k<128
        int nn = i >> 7, kk = i & 127;
        W1T[i] = f2h(W1[kk * 512 + nn]);
    } else if (i < 2 * 512 * 128) {            // W2T[n][k] = W2[k][n], n<128 k<512
        int j = i - 512 * 128;
        int nn = j >> 9, kk = j & 511;
        W2T[j] = f2h(W2[kk * 128 + nn]);
    } else if (i < 2 * 512 * 128 + 128 * 128) {// WoT[n][k] = Wo[k][n], n<128 k<128
        int j = i - 2 * 512 * 128;
        int nn = j >> 7, kk = j & 127;
        WoT[j] = f2h(Wo[kk * 128 + nn]);
    }
}

// ---------------------------------------------------------------- input proj: h0 = x @ Wp + bp (fp16 out)
__global__ __launch_bounds__(256) void k_proj(const float* __restrict__ x, const float* __restrict__ Wp,
                                              const float* __restrict__ bp, ushort* __restrict__ h0h) {
    int tid = threadIdx.x;
    int n = blockIdx.x * 2 + (tid >> 7);
    int c = tid & 127;
    float acc = bp[c];
#pragma unroll
    for (int f = 0; f < 4; f++) acc += x[n * 4 + f] * Wp[f * 128 + c];
    h0h[(size_t)n * 128 + c] = f2h(acc);
}

// ---------------------------------------------------------------- MFMA fp16 GEMM: C[M,Nn] = A[M,K] @ BT[Nn,K]^T
// 128x128 tile, BK=64, 4 waves (each 64x64), XOR-swizzled LDS, fp32 and/or fp16 out.
__global__ __launch_bounds__(256) void k_gemm_hf(const ushort* __restrict__ A, const ushort* __restrict__ BT,
                                                 float* __restrict__ Cf, ushort* __restrict__ Ch,
                                                 int M, int Nn, int K, const float* __restrict__ bias) {
    __shared__ ushort As[128 * 64];
    __shared__ ushort Bs[128 * 64];
    const int tid = threadIdx.x;
    const int lane = tid & 63, wid = tid >> 6;
    const int wr = wid >> 1, wc = wid & 1;
    const int m0 = blockIdx.x * 128, n0 = blockIdx.y * 128;
    float4v acc[4][4];
#pragma unroll
    for (int i = 0; i < 4; i++)
#pragma unroll
        for (int j = 0; j < 4; j++) acc[i][j] = (float4v){0.f, 0.f, 0.f, 0.f};

    for (int k0 = 0; k0 < K; k0 += 64) {
        __syncthreads();
#pragma unroll
        for (int i = 0; i < 4; i++) {
            int c = tid + i * 256;             // 0..1023
            int row = c >> 3, sl = c & 7;      // 8 x 16B chunks per 64-elem row
            int off = row * 128 + ((sl ^ (row & 7)) << 4);
            uint4 va = make_uint4(0u, 0u, 0u, 0u);
            if (m0 + row < M) va = *(const uint4*)&A[(size_t)(m0 + row) * K + k0 + sl * 8];
            *(uint4*)((char*)As + off) = va;
            uint4 vb = *(const uint4*)&BT[(size_t)(n0 + row) * K + k0 + sl * 8];
            *(uint4*)((char*)Bs + off) = vb;
        }
        __syncthreads();
#pragma unroll
        for (int kk = 0; kk < 2; kk++) {
            half8v af[4], bq[4];
            int sl = kk * 4 + (lane >> 4);     // 16B slot: k = kk*32 + (lane>>4)*8
            int ra = wr * 64 + (lane & 15);
            int rb = wc * 64 + (lane & 15);
#pragma unroll
            for (int mi = 0; mi < 4; mi++) {
                int row = ra + mi * 16;
                af[mi] = *(const half8v*)((const char*)As + row * 128 + ((sl ^ (row & 7)) << 4));
            }
#pragma unroll
            for (int ni = 0; ni < 4; ni++) {
                int row = rb + ni * 16;
                bq[ni] = *(const half8v*)((const char*)Bs + row * 128 + ((sl ^ (row & 7)) << 4));
            }
#pragma unroll
            for (int mi = 0; mi < 4; mi++)
#pragma unroll
                for (int ni = 0; ni < 4; ni++)
                    acc[mi][ni] = __builtin_amdgcn_mfma_f32_16x16x32_f16(af[mi], bq[ni], acc[mi][ni], 0, 0, 0);
        }
    }
#pragma unroll
    for (int mi = 0; mi < 4; mi++) {
#pragma unroll
        for (int j = 0; j < 4; j++) {
            int row = m0 + wr * 64 + mi * 16 + ((lane >> 4) << 2) + j;
            if (row < M) {
#pragma unroll
                for (int ni = 0; ni < 4; ni++) {
                    int col = n0 + wc * 64 + ni * 16 + (lane & 15);
                    float v = acc[mi][ni][j];
                    if (bias) v += bias[col];
                    if (Cf) Cf[(size_t)row * Nn + col] = v;
                    if (Ch) Ch[(size_t)row * Nn + col] = f2h(v);
                }
            }
        }
    }
}

// ---------------------------------------------------------------- attention src/dst logit terms, layer 1 (fp16 xh)
__global__ __launch_bounds__(256) void k_ald1(const ushort* __restrict__ xhh, const float* __restrict__ as1,
                                              const float* __restrict__ ad1, float* __restrict__ als,
                                              float* __restrict__ ald) {
    int n = blockIdx.x;
    int w = threadIdx.x >> 6, l = threadIdx.x & 63;
    uint v = *(const uint*)&xhh[(size_t)n * 512 + w * 128 + l * 2];
    float f0 = h2f((ushort)(v & 0xffffu));
    float f1 = h2f((ushort)(v >> 16));
    float2 a = *(const float2*)&as1[w * 128 + l * 2];
    float2 b = *(const float2*)&ad1[w * 128 + l * 2];
    float ps = f0 * a.x + f1 * a.y, pd = f0 * b.x + f1 * b.y;
    for (int off = 32; off; off >>= 1) { ps += __shfl_down(ps, off); pd += __shfl_down(pd, off); }
    if (l == 0) { als[n * 4 + w] = ps; ald[n * 4 + w] = pd; }
}

// ---------------------------------------------------------------- same for layer 2 (1 head)
__global__ __launch_bounds__(256) void k_ald2(const ushort* __restrict__ xh2h, const float* __restrict__ as2,
                                              const float* __restrict__ ad2, float* __restrict__ als,
                                              float* __restrict__ ald) {
    int w = threadIdx.x >> 6, l = threadIdx.x & 63;
    int n = blockIdx.x * 4 + w;
    if (n >= N_NODES) return;
    uint v = *(const uint*)&xh2h[(size_t)n * 128 + l * 2];
    float f0 = h2f((ushort)(v & 0xffffu));
    float f1 = h2f((ushort)(v >> 16));
    float2 a = *(const float2*)&as2[l * 2];
    float2 b = *(const float2*)&ad2[l * 2];
    float ps = f0 * a.x + f1 * a.y, pd = f0 * b.x + f1 * b.y;
    for (int off = 32; off; off >>= 1) { ps += __shfl_down(ps, off); pd += __shfl_down(pd, off); }
    if (l == 0) { als[n] = ps; ald[n] = pd; }
}

// ---------------------------------------------------------------- logits (CSR order), layer 1
__global__ void k_logits1(const int* __restrict__ csr_src, const int* __restrict__ csr_dst,
                          const int* __restrict__ csr_eid, const float* __restrict__ eattr,
                          const float* __restrict__ loopattr, const float* __restrict__ als,
                          const float* __restrict__ ald, const float* __restrict__ M1,
                          float* __restrict__ L1) {
    int p = blockIdx.x * 256 + threadIdx.x;
    if (p >= EN_TOT) return;
    int s = csr_src[p], d = csr_dst[p], eid = csr_eid[p];
    const float* eap = (eid < N_EDGES) ? &eattr[(size_t)eid * 4] : &loopattr[(size_t)(eid - N_EDGES) * 4];
    float4 e4 = *(const float4*)eap;
    float4 out;
    float* op = &out.x;
#pragma unroll
    for (int h = 0; h < 4; h++) {
        float ale = e4.x * M1[0 * 4 + h] + e4.y * M1[1 * 4 + h] + e4.z * M1[2 * 4 + h] + e4.w * M1[3 * 4 + h];
        float l = als[s * 4 + h] + ald[d * 4 + h] + ale;
        op[h] = (l >= 0.f) ? l : 0.2f * l;
    }
    *(float4*)&L1[(size_t)p * 4] = out;
}

// ---------------------------------------------------------------- logits (CSR order), layer 2
__global__ void k_logits2(const int* __restrict__ csr_src, const int* __restrict__ csr_dst,
                          const int* __restrict__ csr_eid, const float* __restrict__ eattr,
                          const float* __restrict__ loopattr, const float* __restrict__ als,
                          const float* __restrict__ ald, const float* __restrict__ m2,
                          float* __restrict__ L2) {
    int p = blockIdx.x * 256 + threadIdx.x;
    if (p >= EN_TOT) return;
    int s = csr_src[p], d = csr_dst[p], eid = csr_eid[p];
    const float* eap = (eid < N_EDGES) ? &eattr[(size_t)eid * 4] : &loopattr[(size_t)(eid - N_EDGES) * 4];
    float4 e4 = *(const float4*)eap;
    float l = als[s] + ald[d] + e4.x * m2[0] + e4.y * m2[1] + e4.z * m2[2] + e4.w * m2[3];
    L2[p] = (l >= 0.f) ? l : 0.2f * l;
}

// ---------------------------------------------------------------- layer-1 aggregation + bias + LN + ELU (fp16 in/out)
__global__ __launch_bounds__(256) void k_agg1(const int* __restrict__ offsets, const int* __restrict__ csr_src,
                                              const float* __restrict__ L1, const ushort* __restrict__ xhh,
                                              const float* __restrict__ b1, const float* __restrict__ g1,
                                              const float* __restrict__ be1, ushort* __restrict__ h1h) {
    int n = blockIdx.x;
    int start = offsets[n];
    int cnt = offsets[n + 1] - start;
    int tid = threadIdx.x;
    __shared__ float red[256];
    __shared__ float mh[4], sh[4];
    __shared__ float sal[64][4];
    __shared__ int ssrc[64];
    __shared__ float sbc[2];
    int hh = tid & 3;
    float m = -1e30f;
    for (int j = tid >> 2; j < cnt; j += 64) m = fmaxf(m, L1[(size_t)(start + j) * 4 + hh]);
    red[tid] = m; __syncthreads();
    for (int s2 = 128; s2 >= 4; s2 >>= 1) { if (tid < s2) red[tid] = fmaxf(red[tid], red[tid + s2]); __syncthreads(); }
    if (tid < 4) mh[tid] = red[tid];
    __syncthreads();
    float mm = mh[hh];
    float ss = 0.f;
    for (int j = tid >> 2; j < cnt; j += 64) ss += expf(L1[(size_t)(start + j) * 4 + hh] - mm);
    red[tid] = ss; __syncthreads();
    for (int s2 = 128; s2 >= 4; s2 >>= 1) { if (tid < s2) red[tid] += red[tid + s2]; __syncthreads(); }
    if (tid < 4) sh[tid] = 1.0f / red[tid];
    __syncthreads();
    // gather: thread owns channels 2t, 2t+1 (one uint = 2 fp16 per edge)
    float acc0 = 0.f, acc1 = 0.f;
    int hg = tid >> 6;   // head of channels 2t,2t+1
    for (int base = 0; base < cnt; base += 64) {
        int mj = min(64, cnt - base);
        if (tid < mj) {
            int p = start + base + tid;
            ssrc[tid] = csr_src[p];
            float4 l4 = *(const float4*)&L1[(size_t)p * 4];
            sal[tid][0] = expf(l4.x - mh[0]) * sh[0];
            sal[tid][1] = expf(l4.y - mh[1]) * sh[1];
            sal[tid][2] = expf(l4.z - mh[2]) * sh[2];
            sal[tid][3] = expf(l4.w - mh[3]) * sh[3];
        }
        __syncthreads();
        int j = 0;
        for (; j + 2 <= mj; j += 2) {   // 2 independent row loads in flight
            float a0 = sal[j][hg], a1 = sal[j + 1][hg];
            uint v0 = *(const uint*)&xhh[(size_t)ssrc[j] * 512 + tid * 2];
            uint v1 = *(const uint*)&xhh[(size_t)ssrc[j + 1] * 512 + tid * 2];
            acc0 += a0 * h2f((ushort)(v0 & 0xffffu)) + a1 * h2f((ushort)(v1 & 0xffffu));
            acc1 += a0 * h2f((ushort)(v0 >> 16)) + a1 * h2f((ushort)(v1 >> 16));
        }
        if (j < mj) {
            float a = sal[j][hg];
            uint v = *(const uint*)&xhh[(size_t)ssrc[j] * 512 + tid * 2];
            acc0 += a * h2f((ushort)(v & 0xffffu));
            acc1 += a * h2f((ushort)(v >> 16));
        }
        __syncthreads();
    }
    // + bias, LayerNorm(512), ELU
    float2 bb = *(const float2*)&b1[tid * 2];
    float v0 = acc0 + bb.x, v1 = acc1 + bb.y;
    red[tid] = v0 + v1; __syncthreads();
    for (int s2 = 128; s2 >= 1; s2 >>= 1) { if (tid < s2) red[tid] += red[tid + s2]; __syncthreads(); }
    if (tid == 0) sbc[0] = red[0] * (1.0f / 512.0f);
    __syncthreads();
    float mu = sbc[0];
    float d0 = v0 - mu, d1 = v1 - mu;
    red[tid] = d0 * d0 + d1 * d1; __syncthreads();
    for (int s2 = 128; s2 >= 1; s2 >>= 1) { if (tid < s2) red[tid] += red[tid + s2]; __syncthreads(); }
    if (tid == 0) sbc[1] = rsqrtf(red[0] * (1.0f / 512.0f) + 1e-5f);
    __syncthreads();
    float rstd = sbc[1];
    float2 gg = *(const float2*)&g1[tid * 2];
    float2 ee = *(const float2*)&be1[tid * 2];
    float y0 = d0 * rstd * gg.x + ee.x;
    float y1 = d1 * rstd * gg.y + ee.y;
    y0 = (y0 > 0.f) ? y0 : expm1f(y0);
    y1 = (y1 > 0.f) ? y1 : expm1f(y1);
    uint o = (uint)f2h(y0) | ((uint)f2h(y1) << 16);
    *(uint*)&h1h[(size_t)n * 512 + tid * 2] = o;
}

// ---------------------------------------------------------------- layer-2 aggregation + alpha out + bias + LN (fp16)
__global__ __launch_bounds__(128) void k_agg2(const int* __restrict__ offsets, const int* __restrict__ csr_src,
                                              const int* __restrict__ csr_eid, const float* __restrict__ L2,
                                              const ushort* __restrict__ xh2h, const float* __restrict__ b2,
                                              const float* __restrict__ g2, const float* __restrict__ be2,
                                              float* __restrict__ eaout, ushort* __restrict__ h2h) {
    int n = blockIdx.x;
    int start = offsets[n];
    int cnt = offsets[n + 1] - start;
    int tid = threadIdx.x;
    __shared__ float red[128];
    __shared__ float sal[128];
    __shared__ int ssrc[128];
    __shared__ float sbc[2];
    float m = -1e30f;
    for (int j = tid; j < cnt; j += 128) m = fmaxf(m, L2[start + j]);
    red[tid] = m; __syncthreads();
    for (int s2 = 64; s2 >= 1; s2 >>= 1) { if (tid < s2) red[tid] = fmaxf(red[tid], red[tid + s2]); __syncthreads(); }
    if (tid == 0) sbc[0] = red[0];
    __syncthreads();
    float mm = sbc[0];
    float ss = 0.f;
    for (int j = tid; j < cnt; j += 128) ss += expf(L2[start + j] - mm);
    red[tid] = ss; __syncthreads();
    for (int s2 = 64; s2 >= 1; s2 >>= 1) { if (tid < s2) red[tid] += red[tid + s2]; __syncthreads(); }
    if (tid == 0) sbc[1] = 1.0f / red[0];
    __syncthreads();
    float inv = sbc[1];
    float acc = 0.f;
    for (int base = 0; base < cnt; base += 128) {
        int mj = min(128, cnt - base);
        if (tid < mj) {
            int p = start + base + tid;
            float a = expf(L2[p] - mm) * inv;
            sal[tid] = a;
            ssrc[tid] = csr_src[p];
            eaout[csr_eid[p]] = a;
        }
        __syncthreads();
        int j = 0;
        for (; j + 2 <= mj; j += 2) {
            float a0 = sal[j], a1 = sal[j + 1];
            float x0 = h2f(xh2h[(size_t)ssrc[j] * 128 + tid]);
            float x1 = h2f(xh2h[(size_t)ssrc[j + 1] * 128 + tid]);
            acc += a0 * x0 + a1 * x1;
        }
        if (j < mj) acc += sal[j] * h2f(xh2h[(size_t)ssrc[j] * 128 + tid]);
        __syncthreads();
    }
    float v = acc + b2[tid];
    red[tid] = v; __syncthreads();
    for (int s2 = 64; s2 >= 1; s2 >>= 1) { if (tid < s2) red[tid] += red[tid + s2]; __syncthreads(); }
    if (tid == 0) sbc[0] = red[0] * (1.0f / 128.0f);
    __syncthreads();
    float mu = sbc[0];
    float d = v - mu;
    red[tid] = d * d; __syncthreads();
    for (int s2 = 64; s2 >= 1; s2 >>= 1) { if (tid < s2) red[tid] += red[tid + s2]; __syncthreads(); }
    if (tid == 0) sbc[1] = rsqrtf(red[0] * (1.0f / 128.0f) + 1e-5f);
    __syncthreads();
    h2h[(size_t)n * 128 + tid] = f2h(d * sbc[1] * g2[tid] + be2[tid]);
}

// ---------------------------------------------------------------- importance = sigmoid(emb @ Wi + bi)
__global__ __launch_bounds__(256) void k_imp(const float* __restrict__ emb, const float* __restrict__ Wi,
                                             const float* __restrict__ bi, float* __restrict__ impout) {
    int w = threadIdx.x >> 6, l = threadIdx.x & 63;
    int n = blockIdx.x * 4 + w;
    if (n >= N_NODES) return;
    const float* ep = &emb[(size_t)n * 128];
    float p = ep[l] * Wi[l] + ep[l + 64] * Wi[l + 64];
    for (int off = 32; off; off >>= 1) p += __shfl_down(p, off);
    if (l == 0) impout[n] = 1.0f / (1.0f + expf(-(p + bi[0])));
}

// ================================================================ launch
extern "C" void kernel_launch(void* const* d_in, const int* in_sizes, int n_in,
                              void* d_out, int out_size, void* d_ws, size_t ws_size,
                              hipStream_t stream) {
    const float* x    = (const float*)d_in[0];
    const int*   eidx = (const int*)d_in[1];
    const float* eattr= (const float*)d_in[2];
    const float* Wp   = (const float*)d_in[3];
    const float* bp   = (const float*)d_in[4];
    const float* W1   = (const float*)d_in[5];
    const float* We1  = (const float*)d_in[6];
    const float* as1  = (const float*)d_in[7];
    const float* ad1  = (const float*)d_in[8];
    const float* ae1  = (const float*)d_in[9];
    const float* b1   = (const float*)d_in[10];
    const float* g1   = (const float*)d_in[11];
    const float* be1  = (const float*)d_in[12];
    const float* W2   = (const float*)d_in[13];
    const float* We2  = (const float*)d_in[14];
    const float* as2  = (const float*)d_in[15];
    const float* ad2  = (const float*)d_in[16];
    const float* ae2  = (const float*)d_in[17];
    const float* b2   = (const float*)d_in[18];
    const float* g2   = (const float*)d_in[19];
    const float* be2  = (const float*)d_in[20];
    const float* Wo   = (const float*)d_in[21];
    const float* bo   = (const float*)d_in[22];
    const float* Wi   = (const float*)d_in[23];
    const float* bi   = (const float*)d_in[24];

    const int* src = eidx;
    const int* dst = eidx + N_EDGES;

    float* emb_out = (float*)d_out;                       // [N,128]
    float* ea_out  = emb_out + (size_t)N_NODES * 128;     // [E+N]
    float* imp_out = ea_out + EN_TOT;                     // [N]

    // ---- workspace carve (256B aligned) ----
    char* w = (char*)d_ws;
    auto alloc = [&](size_t bytes) -> void* { void* p = (void*)w; w += (bytes + 255) & ~(size_t)255; return p; };
    ushort* xhh    = (ushort*)alloc((size_t)N_NODES * 512 * 2);  // [N,512] fp16
    ushort* h1h    = (ushort*)alloc((size_t)N_NODES * 512 * 2);  // [N,512] fp16
    ushort* h0h    = (ushort*)alloc((size_t)N_NODES * 128 * 2);  // [N,128] fp16
    ushort* xh2h   = (ushort*)alloc((size_t)N_NODES * 128 * 2);  // [N,128] fp16
    ushort* h2h    = (ushort*)alloc((size_t)N_NODES * 128 * 2);  // [N,128] fp16
    ushort* W1T    = (ushort*)alloc((size_t)512 * 128 * 2);
    ushort* W2T    = (ushort*)alloc((size_t)128 * 512 * 2);
    ushort* WoT    = (ushort*)alloc((size_t)128 * 128 * 2);
    float* L1      = (float*)alloc((size_t)EN_TOT * 4 * 4);      // [E+N,4]
    float* L2      = (float*)alloc((size_t)EN_TOT * 4);          // [E+N]
    int*   csr_src = (int*)alloc((size_t)EN_TOT * 4);
    int*   csr_eid = (int*)alloc((size_t)EN_TOT * 4);
    int*   csr_dst = (int*)alloc((size_t)EN_TOT * 4);
    int*   offsets = (int*)alloc((size_t)(N_NODES + 1) * 4);
    int*   cursor  = (int*)alloc((size_t)N_NODES * 4);
    int*   degi    = (int*)alloc((size_t)N_NODES * 4);
    float* loopat  = (float*)alloc((size_t)N_NODES * 4 * 4);
    float* als1v   = (float*)alloc((size_t)N_NODES * 4 * 4);
    float* ald1v   = (float*)alloc((size_t)N_NODES * 4 * 4);
    float* als2v   = (float*)alloc((size_t)N_NODES * 4);
    float* ald2v   = (float*)alloc((size_t)N_NODES * 4);
    float* M1      = (float*)alloc(32 * 4);
    float* m2      = M1 + 16;

    hipMemsetAsync(degi,   0, (size_t)N_NODES * 4, stream);
    hipMemsetAsync(cursor, 0, (size_t)N_NODES * 4, stream);

    k_deg<<<(N_EDGES + 255) / 256, 256, 0, stream>>>(dst, degi);
    k_scan<<<1, 1024, 0, stream>>>(degi, offsets, We1, ae1, We2, ae2, M1, m2);
    k_fill<<<(EN_TOT + 255) / 256, 256, 0, stream>>>(src, dst, offsets, cursor, csr_src, csr_eid, csr_dst);
    k_loopattr<<<(N_NODES + 3) / 4, 256, 0, stream>>>(offsets, csr_eid, eattr, loopat);
    k_prep<<<576, 256, 0, stream>>>(W1, W2, Wo, W1T, W2T, WoT);
    k_proj<<<N_NODES / 2, 256, 0, stream>>>(x, Wp, bp, h0h);

    // xh = h0 @ W1   [20000,128] x [128,512] -> fp16
    k_gemm_hf<<<dim3((N_NODES + 127) / 128, 4), 256, 0, stream>>>(h0h, W1T, nullptr, xhh,
                                                                  N_NODES, 512, 128, nullptr);
    k_ald1<<<N_NODES, 256, 0, stream>>>(xhh, as1, ad1, als1v, ald1v);
    k_logits1<<<(EN_TOT + 255) / 256, 256, 0, stream>>>(csr_src, csr_dst, csr_eid, eattr, loopat,
                                                        als1v, ald1v, M1, L1);
    k_agg1<<<N_NODES, 256, 0, stream>>>(offsets, csr_src, L1, xhh, b1, g1, be1, h1h);

    // xh2 = h1 @ W2  [20000,512] x [512,128] -> fp16
    k_gemm_hf<<<dim3((N_NODES + 127) / 128, 1), 256, 0, stream>>>(h1h, W2T, nullptr, xh2h,
                                                                  N_NODES, 128, 512, nullptr);
    k_ald2<<<(N_NODES + 3) / 4, 256, 0, stream>>>(xh2h, as2, ad2, als2v, ald2v);
    k_logits2<<<(EN_TOT + 255) / 256, 256, 0, stream>>>(csr_src, csr_dst, csr_eid, eattr, loopat,
                                                        als2v, ald2v, m2, L2);
    k_agg2<<<N_NODES, 128, 0, stream>>>(offsets, csr_src, csr_eid, L2, xh2h, b2, g2, be2, ea_out, h2h);

    // emb = h2 @ Wo + bo -> d_out (fp32)
    k_gemm_hf<<<dim3((N_NODES + 127) / 128, 1), 256, 0, stream>>>(h2h, WoT, emb_out, nullptr,
                                                                  N_NODES, 128, 128, bo);
    k_imp<<<(N_NODES + 3) / 4, 256, 0, stream>>>(emb_out, Wi, bi, imp_out);
}

// Round 5
// 266.301 us; speedup vs baseline: 1.8125x; 1.1597x over previous
//
#include <hip/hip_runtime.h>
#include <math.h>
#include <stdint.h>

#define N_NODES 20000
#define N_EDGES 320000
#define EN_TOT  340000   // E + N (with self loops)

typedef __attribute__((ext_vector_type(8))) _Float16 half8v;  // 8 fp16 (4 VGPRs)
typedef __attribute__((ext_vector_type(4))) float float4v;    // MFMA accumulator

__device__ __forceinline__ ushort f2h(float f) {              // fp32 -> fp16 RNE
    _Float16 h = (_Float16)f;
    return __builtin_bit_cast(ushort, h);
}
__device__ __forceinline__ float h2f(ushort s) {
    return (float)__builtin_bit_cast(_Float16, s);
}

// ---------------------------------------------------------------- degree count (1 int atomic / edge)
__global__ void k_deg(const int* __restrict__ dst, int* __restrict__ degi) {
    int e = blockIdx.x * 256 + threadIdx.x;
    if (e >= N_EDGES) return;
    atomicAdd(&degi[dst[e]], 1);
}

// ---------------------------------------------------------------- scan (offsets) + M1/m2 fold
__global__ __launch_bounds__(1024) void k_scan(const int* __restrict__ degi, int* __restrict__ offsets,
                                               const float* __restrict__ We1, const float* __restrict__ ae1,
                                               const float* __restrict__ We2, const float* __restrict__ ae2,
                                               float* __restrict__ M1, float* __restrict__ m2) {
    __shared__ int s[1024];
    int t = threadIdx.x;
    int n0 = t * 20;
    int tot = 0;
    for (int i = 0; i < 20; i++) {
        int n = n0 + i;
        if (n < N_NODES) tot += degi[n] + 1;
    }
    s[t] = tot;
    __syncthreads();
    for (int off = 1; off < 1024; off <<= 1) {
        int v = (t >= off) ? s[t - off] : 0;
        __syncthreads();
        s[t] += v;
        __syncthreads();
    }
    int run = s[t] - tot;
    for (int i = 0; i < 20; i++) {
        int n = n0 + i;
        if (n < N_NODES) {
            offsets[n] = run;
            run += degi[n] + 1;
        }
    }
    if (t == 1023) offsets[N_NODES] = s[1023];
    // fold edge-attr projections: M1[f][h] = sum_c We1[f, h*128+c] * ae1[h,c];  m2[f] = sum_c We2[f,c]*ae2[c]
    if (t < 16) {
        int f = t >> 2, h = t & 3;
        float acc = 0.f;
        for (int c = 0; c < 128; c++) acc += We1[f * 512 + h * 128 + c] * ae1[h * 128 + c];
        M1[f * 4 + h] = acc;
    } else if (t < 20) {
        int f = t - 16;
        float acc = 0.f;
        for (int c = 0; c < 128; c++) acc += We2[f * 128 + c] * ae2[c];
        m2[f] = acc;
    }
}

// ---------------------------------------------------------------- CSR fill (edges + self loops)
__global__ void k_fill(const int* __restrict__ src, const int* __restrict__ dst,
                       const int* __restrict__ offsets, int* __restrict__ cursor,
                       int* __restrict__ csr_src, int* __restrict__ csr_eid, int* __restrict__ csr_dst) {
    int i = blockIdx.x * 256 + threadIdx.x;
    if (i >= EN_TOT) return;
    int d, sidx, eid;
    if (i < N_EDGES) { d = dst[i]; sidx = src[i]; eid = i; }
    else { int n = i - N_EDGES; d = n; sidx = n; eid = N_EDGES + n; }
    int pos = offsets[d] + atomicAdd(&cursor[d], 1);
    csr_src[pos] = sidx;
    csr_eid[pos] = eid;
    csr_dst[pos] = d;
}

// ---------------------------------------------------------------- loop_attr = mean of incoming eattr (no atomics)
__global__ __launch_bounds__(256) void k_loopattr(const int* __restrict__ offsets,
                                                  const int* __restrict__ csr_eid,
                                                  const float* __restrict__ eattr,
                                                  float* __restrict__ loopattr) {
    int wv = threadIdx.x >> 6, l = threadIdx.x & 63;
    int n = blockIdx.x * 4 + wv;
    if (n >= N_NODES) return;
    int start = offsets[n], end = offsets[n + 1];
    float sx = 0.f, sy = 0.f, sz = 0.f, sw = 0.f;
    for (int p = start + l; p < end; p += 64) {
        int eid = csr_eid[p];
        if (eid < N_EDGES) {
            float4 e = *(const float4*)&eattr[(size_t)eid * 4];
            sx += e.x; sy += e.y; sz += e.z; sw += e.w;
        }
    }
    for (int off = 32; off; off >>= 1) {
        sx += __shfl_down(sx, off);
        sy += __shfl_down(sy, off);
        sz += __shfl_down(sz, off);
        sw += __shfl_down(sw, off);
    }
    if (l == 0) {
        float inv = 1.0f / fmaxf((float)(end - start - 1), 1.0f);
        float4 o;
        o.x = sx * inv; o.y = sy * inv; o.z = sz * inv; o.w = sw * inv;
        *(float4*)&loopattr[(size_t)n * 4] = o;
    }
}

// ---------------------------------------------------------------- weight transpose + fp16 convert
__global__ void k_prep(const float* __restrict__ W1, const float* __restrict__ W2,
                       const float* __restrict__ Wo, ushort* __restrict__ W1T,
                       ushort* __restrict__ W2T, ushort* __restrict__ WoT) {
    int i = blockIdx.x * 256 + threadIdx.x;
    if (i < 512 * 128) {                       // W1T[n][k] = W1[k][n], n<512 k<128
        int nn = i >> 7, kk = i & 127;
        W1T[i] = f2h(W1[kk * 512 + nn]);
    } else if (i < 2 * 512 * 128) {            // W2T[n][k] = W2[k][n], n<128 k<512
        int j = i - 512 * 128;
        int nn = j >> 9, kk = j & 511;
        W2T[j] = f2h(W2[kk * 128 + nn]);
    } else if (i < 2 * 512 * 128 + 128 * 128) {// WoT[n][k] = Wo[k][n], n<128 k<128
        int j = i - 2 * 512 * 128;
        int nn = j >> 7, kk = j & 127;
        WoT[j] = f2h(Wo[kk * 128 + nn]);
    }
}

// ---------------------------------------------------------------- input proj: h0 = x @ Wp + bp (fp16 out)
__global__ __launch_bounds__(256) void k_proj(const float* __restrict__ x, const float* __restrict__ Wp,
                                              const float* __restrict__ bp, ushort* __restrict__ h0h) {
    int tid = threadIdx.x;
    int n = blockIdx.x * 2 + (tid >> 7);
    int c = tid & 127;
    float acc = bp[c];
#pragma unroll
    for (int f = 0; f < 4; f++) acc += x[n * 4 + f] * Wp[f * 128 + c];
    h0h[(size_t)n * 128 + c] = f2h(acc);
}

// ---------------------------------------------------------------- MFMA fp16 GEMM: C[M,Nn] = A[M,K] @ BT[Nn,K]^T
// 128x128 tile, BK=64, 4 waves (each 64x64), XOR-swizzled LDS, fp32 and/or fp16 out.
__global__ __launch_bounds__(256) void k_gemm_hf(const ushort* __restrict__ A, const ushort* __restrict__ BT,
                                                 float* __restrict__ Cf, ushort* __restrict__ Ch,
                                                 int M, int Nn, int K, const float* __restrict__ bias) {
    __shared__ ushort As[128 * 64];
    __shared__ ushort Bs[128 * 64];
    const int tid = threadIdx.x;
    const int lane = tid & 63, wid = tid >> 6;
    const int wr = wid >> 1, wc = wid & 1;
    const int m0 = blockIdx.x * 128, n0 = blockIdx.y * 128;
    float4v acc[4][4];
#pragma unroll
    for (int i = 0; i < 4; i++)
#pragma unroll
        for (int j = 0; j < 4; j++) acc[i][j] = (float4v){0.f, 0.f, 0.f, 0.f};

    for (int k0 = 0; k0 < K; k0 += 64) {
        __syncthreads();
#pragma unroll
        for (int i = 0; i < 4; i++) {
            int c = tid + i * 256;             // 0..1023
            int row = c >> 3, sl = c & 7;      // 8 x 16B chunks per 64-elem row
            int off = row * 128 + ((sl ^ (row & 7)) << 4);
            uint4 va = make_uint4(0u, 0u, 0u, 0u);
            if (m0 + row < M) va = *(const uint4*)&A[(size_t)(m0 + row) * K + k0 + sl * 8];
            *(uint4*)((char*)As + off) = va;
            uint4 vb = *(const uint4*)&BT[(size_t)(n0 + row) * K + k0 + sl * 8];
            *(uint4*)((char*)Bs + off) = vb;
        }
        __syncthreads();
#pragma unroll
        for (int kk = 0; kk < 2; kk++) {
            half8v af[4], bq[4];
            int sl = kk * 4 + (lane >> 4);     // 16B slot: k = kk*32 + (lane>>4)*8
            int ra = wr * 64 + (lane & 15);
            int rb = wc * 64 + (lane & 15);
#pragma unroll
            for (int mi = 0; mi < 4; mi++) {
                int row = ra + mi * 16;
                af[mi] = *(const half8v*)((const char*)As + row * 128 + ((sl ^ (row & 7)) << 4));
            }
#pragma unroll
            for (int ni = 0; ni < 4; ni++) {
                int row = rb + ni * 16;
                bq[ni] = *(const half8v*)((const char*)Bs + row * 128 + ((sl ^ (row & 7)) << 4));
            }
#pragma unroll
            for (int mi = 0; mi < 4; mi++)
#pragma unroll
                for (int ni = 0; ni < 4; ni++)
                    acc[mi][ni] = __builtin_amdgcn_mfma_f32_16x16x32_f16(af[mi], bq[ni], acc[mi][ni], 0, 0, 0);
        }
    }
#pragma unroll
    for (int mi = 0; mi < 4; mi++) {
#pragma unroll
        for (int j = 0; j < 4; j++) {
            int row = m0 + wr * 64 + mi * 16 + ((lane >> 4) << 2) + j;
            if (row < M) {
#pragma unroll
                for (int ni = 0; ni < 4; ni++) {
                    int col = n0 + wc * 64 + ni * 16 + (lane & 15);
                    float v = acc[mi][ni][j];
                    if (bias) v += bias[col];
                    if (Cf) Cf[(size_t)row * Nn + col] = v;
                    if (Ch) Ch[(size_t)row * Nn + col] = f2h(v);
                }
            }
        }
    }
}

// ---------------------------------------------------------------- attention src/dst logit terms, layer 1 (fp16 xh)
__global__ __launch_bounds__(256) void k_ald1(const ushort* __restrict__ xhh, const float* __restrict__ as1,
                                              const float* __restrict__ ad1, float* __restrict__ als,
                                              float* __restrict__ ald) {
    int n = blockIdx.x;
    int w = threadIdx.x >> 6, l = threadIdx.x & 63;
    uint v = *(const uint*)&xhh[(size_t)n * 512 + w * 128 + l * 2];
    float f0 = h2f((ushort)(v & 0xffffu));
    float f1 = h2f((ushort)(v >> 16));
    float2 a = *(const float2*)&as1[w * 128 + l * 2];
    float2 b = *(const float2*)&ad1[w * 128 + l * 2];
    float ps = f0 * a.x + f1 * a.y, pd = f0 * b.x + f1 * b.y;
    for (int off = 32; off; off >>= 1) { ps += __shfl_down(ps, off); pd += __shfl_down(pd, off); }
    if (l == 0) { als[n * 4 + w] = ps; ald[n * 4 + w] = pd; }
}

// ---------------------------------------------------------------- same for layer 2 (1 head)
__global__ __launch_bounds__(256) void k_ald2(const ushort* __restrict__ xh2h, const float* __restrict__ as2,
                                              const float* __restrict__ ad2, float* __restrict__ als,
                                              float* __restrict__ ald) {
    int w = threadIdx.x >> 6, l = threadIdx.x & 63;
    int n = blockIdx.x * 4 + w;
    if (n >= N_NODES) return;
    uint v = *(const uint*)&xh2h[(size_t)n * 128 + l * 2];
    float f0 = h2f((ushort)(v & 0xffffu));
    float f1 = h2f((ushort)(v >> 16));
    float2 a = *(const float2*)&as2[l * 2];
    float2 b = *(const float2*)&ad2[l * 2];
    float ps = f0 * a.x + f1 * a.y, pd = f0 * b.x + f1 * b.y;
    for (int off = 32; off; off >>= 1) { ps += __shfl_down(ps, off); pd += __shfl_down(pd, off); }
    if (l == 0) { als[n] = ps; ald[n] = pd; }
}

// ---------------------------------------------------------------- logits (CSR order), layer 1
__global__ void k_logits1(const int* __restrict__ csr_src, const int* __restrict__ csr_dst,
                          const int* __restrict__ csr_eid, const float* __restrict__ eattr,
                          const float* __restrict__ loopattr, const float* __restrict__ als,
                          const float* __restrict__ ald, const float* __restrict__ M1,
                          float* __restrict__ L1) {
    int p = blockIdx.x * 256 + threadIdx.x;
    if (p >= EN_TOT) return;
    int s = csr_src[p], d = csr_dst[p], eid = csr_eid[p];
    const float* eap = (eid < N_EDGES) ? &eattr[(size_t)eid * 4] : &loopattr[(size_t)(eid - N_EDGES) * 4];
    float4 e4 = *(const float4*)eap;
    float4 out;
    float* op = &out.x;
#pragma unroll
    for (int h = 0; h < 4; h++) {
        float ale = e4.x * M1[0 * 4 + h] + e4.y * M1[1 * 4 + h] + e4.z * M1[2 * 4 + h] + e4.w * M1[3 * 4 + h];
        float l = als[s * 4 + h] + ald[d * 4 + h] + ale;
        op[h] = (l >= 0.f) ? l : 0.2f * l;
    }
    *(float4*)&L1[(size_t)p * 4] = out;
}

// ---------------------------------------------------------------- logits (CSR order), layer 2
__global__ void k_logits2(const int* __restrict__ csr_src, const int* __restrict__ csr_dst,
                          const int* __restrict__ csr_eid, const float* __restrict__ eattr,
                          const float* __restrict__ loopattr, const float* __restrict__ als,
                          const float* __restrict__ ald, const float* __restrict__ m2,
                          float* __restrict__ L2) {
    int p = blockIdx.x * 256 + threadIdx.x;
    if (p >= EN_TOT) return;
    int s = csr_src[p], d = csr_dst[p], eid = csr_eid[p];
    const float* eap = (eid < N_EDGES) ? &eattr[(size_t)eid * 4] : &loopattr[(size_t)(eid - N_EDGES) * 4];
    float4 e4 = *(const float4*)eap;
    float l = als[s] + ald[d] + e4.x * m2[0] + e4.y * m2[1] + e4.z * m2[2] + e4.w * m2[3];
    L2[p] = (l >= 0.f) ? l : 0.2f * l;
}

// ---------------------------------------------------------------- layer-1 aggregation + bias + LN + ELU (fp16 in/out)
// 256 thr: ct=tid&127 owns channels 4ct..4ct+3 (uint2 8B loads), half=tid>>7 -> 2 edges concurrent.
// Online-softmax stats via shuffles; ~8 barriers/block total.
__global__ __launch_bounds__(256) void k_agg1(const int* __restrict__ offsets, const int* __restrict__ csr_src,
                                              const float* __restrict__ L1, const ushort* __restrict__ xhh,
                                              const float* __restrict__ b1, const float* __restrict__ g1,
                                              const float* __restrict__ be1, ushort* __restrict__ h1h) {
    int n = blockIdx.x;
    int start = offsets[n];
    int cnt = offsets[n + 1] - start;
    int tid = threadIdx.x;
    int lane = tid & 63, wv = tid >> 6;
    __shared__ float mws[4][4], sws[4][4];
    __shared__ float mh[4], sh[4];
    __shared__ float sal[64][4];
    __shared__ int ssrc[64];
    __shared__ float part[128][4];
    __shared__ float wred[2], wred2[2];

    // ---- online softmax stats: thread covers head hh, edges (tid>>2)+64k
    int hh = tid & 3;
    float m = -1e30f, s = 0.f;
    for (int j = tid >> 2; j < cnt; j += 64) {
        float l = L1[(size_t)(start + j) * 4 + hh];
        float mn = fmaxf(m, l);
        s = s * __expf(m - mn) + __expf(l - mn);
        m = mn;
    }
#pragma unroll
    for (int off = 4; off < 64; off <<= 1) {
        float mo = __shfl_xor(m, off);
        float so = __shfl_xor(s, off);
        float mn = fmaxf(m, mo);
        s = s * __expf(m - mn) + so * __expf(mo - mn);
        m = mn;
    }
    if (lane < 4) { mws[wv][lane] = m; sws[wv][lane] = s; }
    __syncthreads();
    if (tid < 4) {
        float M = mws[0][tid], S = sws[0][tid];
#pragma unroll
        for (int w2 = 1; w2 < 4; w2++) {
            float mo = mws[w2][tid], so = sws[w2][tid];
            float mn = fmaxf(M, mo);
            S = S * __expf(M - mn) + so * __expf(mo - mn);
            M = mn;
        }
        mh[tid] = M; sh[tid] = 1.0f / S;
    }
    __syncthreads();

    // ---- gather: 2 edges in flight (half split), uint2 per thread
    float acc0 = 0.f, acc1 = 0.f, acc2 = 0.f, acc3 = 0.f;
    int ct = tid & 127, half = tid >> 7;
    int hg = ct >> 5;    // head of channels 4ct..4ct+3
    for (int base = 0; base < cnt; base += 64) {
        int mj = min(64, cnt - base);
        if (tid < mj) {
            int p = start + base + tid;
            ssrc[tid] = csr_src[p];
            float4 l4 = *(const float4*)&L1[(size_t)p * 4];
            sal[tid][0] = __expf(l4.x - mh[0]) * sh[0];
            sal[tid][1] = __expf(l4.y - mh[1]) * sh[1];
            sal[tid][2] = __expf(l4.z - mh[2]) * sh[2];
            sal[tid][3] = __expf(l4.w - mh[3]) * sh[3];
        }
        __syncthreads();
        int j = half;
        for (; j + 2 < mj; j += 4) {
            float a0 = sal[j][hg], a1 = sal[j + 2][hg];
            int s0 = ssrc[j], s1 = ssrc[j + 2];
            uint2 v0 = *(const uint2*)&xhh[(size_t)s0 * 512 + ct * 4];
            uint2 v1 = *(const uint2*)&xhh[(size_t)s1 * 512 + ct * 4];
            acc0 += a0 * h2f((ushort)(v0.x & 0xffffu)) + a1 * h2f((ushort)(v1.x & 0xffffu));
            acc1 += a0 * h2f((ushort)(v0.x >> 16))     + a1 * h2f((ushort)(v1.x >> 16));
            acc2 += a0 * h2f((ushort)(v0.y & 0xffffu)) + a1 * h2f((ushort)(v1.y & 0xffffu));
            acc3 += a0 * h2f((ushort)(v0.y >> 16))     + a1 * h2f((ushort)(v1.y >> 16));
        }
        if (j < mj) {
            float a = sal[j][hg];
            int s0 = ssrc[j];
            uint2 v = *(const uint2*)&xhh[(size_t)s0 * 512 + ct * 4];
            acc0 += a * h2f((ushort)(v.x & 0xffffu));
            acc1 += a * h2f((ushort)(v.x >> 16));
            acc2 += a * h2f((ushort)(v.y & 0xffffu));
            acc3 += a * h2f((ushort)(v.y >> 16));
        }
        __syncthreads();
    }

    // ---- combine halves
    if (half == 1) { part[ct][0] = acc0; part[ct][1] = acc1; part[ct][2] = acc2; part[ct][3] = acc3; }
    __syncthreads();
    float v0 = 0.f, v1 = 0.f, v2 = 0.f, v3 = 0.f, s4 = 0.f;
    if (half == 0) {
        float4 bb = *(const float4*)&b1[ct * 4];
        v0 = acc0 + part[ct][0] + bb.x;
        v1 = acc1 + part[ct][1] + bb.y;
        v2 = acc2 + part[ct][2] + bb.z;
        v3 = acc3 + part[ct][3] + bb.w;
        s4 = v0 + v1 + v2 + v3;
    }
#pragma unroll
    for (int off = 1; off < 64; off <<= 1) s4 += __shfl_xor(s4, off);
    if (half == 0 && lane == 0) wred[wv] = s4;
    __syncthreads();
    float mu = (wred[0] + wred[1]) * (1.0f / 512.0f);
    float d0 = 0.f, d1 = 0.f, d2 = 0.f, d3 = 0.f, sq = 0.f;
    if (half == 0) {
        d0 = v0 - mu; d1 = v1 - mu; d2 = v2 - mu; d3 = v3 - mu;
        sq = d0 * d0 + d1 * d1 + d2 * d2 + d3 * d3;
    }
#pragma unroll
    for (int off = 1; off < 64; off <<= 1) sq += __shfl_xor(sq, off);
    if (half == 0 && lane == 0) wred2[wv] = sq;
    __syncthreads();
    if (half == 0) {
        float rstd = rsqrtf((wred2[0] + wred2[1]) * (1.0f / 512.0f) + 1e-5f);
        float4 gg = *(const float4*)&g1[ct * 4];
        float4 ee = *(const float4*)&be1[ct * 4];
        float y0 = d0 * rstd * gg.x + ee.x;
        float y1 = d1 * rstd * gg.y + ee.y;
        float y2 = d2 * rstd * gg.z + ee.z;
        float y3 = d3 * rstd * gg.w + ee.w;
        y0 = (y0 > 0.f) ? y0 : (__expf(y0) - 1.0f);
        y1 = (y1 > 0.f) ? y1 : (__expf(y1) - 1.0f);
        y2 = (y2 > 0.f) ? y2 : (__expf(y2) - 1.0f);
        y3 = (y3 > 0.f) ? y3 : (__expf(y3) - 1.0f);
        uint2 o;
        o.x = (uint)f2h(y0) | ((uint)f2h(y1) << 16);
        o.y = (uint)f2h(y2) | ((uint)f2h(y3) << 16);
        *(uint2*)&h1h[(size_t)n * 512 + ct * 4] = o;
    }
}

// ---------------------------------------------------------------- layer-2 aggregation + alpha out + bias + LN (fp16)
// 128 thr: ct=tid&63 owns channels 2ct,2ct+1 (uint 4B), half=tid>>6 -> 2 edges concurrent.
__global__ __launch_bounds__(128) void k_agg2(const int* __restrict__ offsets, const int* __restrict__ csr_src,
                                              const int* __restrict__ csr_eid, const float* __restrict__ L2,
                                              const ushort* __restrict__ xh2h, const float* __restrict__ b2,
                                              const float* __restrict__ g2, const float* __restrict__ be2,
                                              float* __restrict__ eaout, ushort* __restrict__ h2h) {
    int n = blockIdx.x;
    int start = offsets[n];
    int cnt = offsets[n + 1] - start;
    int tid = threadIdx.x;
    int lane = tid & 63, wv = tid >> 6;
    __shared__ float mws[2], sws[2];
    __shared__ float sal[128];
    __shared__ int ssrc[128];
    __shared__ float part[64][2];

    // online softmax stats
    float m = -1e30f, s = 0.f;
    for (int j = tid; j < cnt; j += 128) {
        float l = L2[start + j];
        float mn = fmaxf(m, l);
        s = s * __expf(m - mn) + __expf(l - mn);
        m = mn;
    }
#pragma unroll
    for (int off = 1; off < 64; off <<= 1) {
        float mo = __shfl_xor(m, off);
        float so = __shfl_xor(s, off);
        float mn = fmaxf(m, mo);
        s = s * __expf(m - mn) + so * __expf(mo - mn);
        m = mn;
    }
    if (lane == 0) { mws[wv] = m; sws[wv] = s; }
    __syncthreads();
    float m0 = mws[0], m1 = mws[1];
    float mm = fmaxf(m0, m1);
    float inv = 1.0f / (sws[0] * __expf(m0 - mm) + sws[1] * __expf(m1 - mm));

    // gather
    float acc0 = 0.f, acc1 = 0.f;
    int ct = tid & 63, half = tid >> 6;
    for (int base = 0; base < cnt; base += 128) {
        int mj = min(128, cnt - base);
        if (tid < mj) {
            int p = start + base + tid;
            float a = __expf(L2[p] - mm) * inv;
            sal[tid] = a;
            ssrc[tid] = csr_src[p];
            eaout[csr_eid[p]] = a;
        }
        __syncthreads();
        int j = half;
        for (; j + 2 < mj; j += 4) {
            float a0 = sal[j], a1 = sal[j + 2];
            uint v0 = *(const uint*)&xh2h[(size_t)ssrc[j] * 128 + ct * 2];
            uint v1 = *(const uint*)&xh2h[(size_t)ssrc[j + 2] * 128 + ct * 2];
            acc0 += a0 * h2f((ushort)(v0 & 0xffffu)) + a1 * h2f((ushort)(v1 & 0xffffu));
            acc1 += a0 * h2f((ushort)(v0 >> 16))     + a1 * h2f((ushort)(v1 >> 16));
        }
        if (j < mj) {
            float a = sal[j];
            uint v = *(const uint*)&xh2h[(size_t)ssrc[j] * 128 + ct * 2];
            acc0 += a * h2f((ushort)(v & 0xffffu));
            acc1 += a * h2f((ushort)(v >> 16));
        }
        __syncthreads();
    }
    if (half == 1) { part[ct][0] = acc0; part[ct][1] = acc1; }
    __syncthreads();
    if (half == 0) {
        float2 bb = *(const float2*)&b2[ct * 2];
        float v0 = acc0 + part[ct][0] + bb.x;
        float v1 = acc1 + part[ct][1] + bb.y;
        float s2 = v0 + v1;
#pragma unroll
        for (int off = 1; off < 64; off <<= 1) s2 += __shfl_xor(s2, off);
        float mu = s2 * (1.0f / 128.0f);
        float d0 = v0 - mu, d1 = v1 - mu;
        float q = d0 * d0 + d1 * d1;
#pragma unroll
        for (int off = 1; off < 64; off <<= 1) q += __shfl_xor(q, off);
        float rstd = rsqrtf(q * (1.0f / 128.0f) + 1e-5f);
        float2 gg = *(const float2*)&g2[ct * 2];
        float2 ee = *(const float2*)&be2[ct * 2];
        float y0 = d0 * rstd * gg.x + ee.x;
        float y1 = d1 * rstd * gg.y + ee.y;
        uint o = (uint)f2h(y0) | ((uint)f2h(y1) << 16);
        *(uint*)&h2h[(size_t)n * 128 + ct * 2] = o;
    }
}

// ---------------------------------------------------------------- importance = sigmoid(emb @ Wi + bi)
__global__ __launch_bounds__(256) void k_imp(const float* __restrict__ emb, const float* __restrict__ Wi,
                                             const float* __restrict__ bi, float* __restrict__ impout) {
    int w = threadIdx.x >> 6, l = threadIdx.x & 63;
    int n = blockIdx.x * 4 + w;
    if (n >= N_NODES) return;
    const float* ep = &emb[(size_t)n * 128];
    float p = ep[l] * Wi[l] + ep[l + 64] * Wi[l + 64];
    for (int off = 32; off; off >>= 1) p += __shfl_down(p, off);
    if (l == 0) impout[n] = 1.0f / (1.0f + expf(-(p + bi[0])));
}

// ================================================================ launch
extern "C" void kernel_launch(void* const* d_in, const int* in_sizes, int n_in,
                              void* d_out, int out_size, void* d_ws, size_t ws_size,
                              hipStream_t stream) {
    const float* x    = (const float*)d_in[0];
    const int*   eidx = (const int*)d_in[1];
    const float* eattr= (const float*)d_in[2];
    const float* Wp   = (const float*)d_in[3];
    const float* bp   = (const float*)d_in[4];
    const float* W1   = (const float*)d_in[5];
    const float* We1  = (const float*)d_in[6];
    const float* as1  = (const float*)d_in[7];
    const float* ad1  = (const float*)d_in[8];
    const float* ae1  = (const float*)d_in[9];
    const float* b1   = (const float*)d_in[10];
    const float* g1   = (const float*)d_in[11];
    const float* be1  = (const float*)d_in[12];
    const float* W2   = (const float*)d_in[13];
    const float* We2  = (const float*)d_in[14];
    const float* as2  = (const float*)d_in[15];
    const float* ad2  = (const float*)d_in[16];
    const float* ae2  = (const float*)d_in[17];
    const float* b2   = (const float*)d_in[18];
    const float* g2   = (const float*)d_in[19];
    const float* be2  = (const float*)d_in[20];
    const float* Wo   = (const float*)d_in[21];
    const float* bo   = (const float*)d_in[22];
    const float* Wi   = (const float*)d_in[23];
    const float* bi   = (const float*)d_in[24];

    const int* src = eidx;
    const int* dst = eidx + N_EDGES;

    float* emb_out = (float*)d_out;                       // [N,128]
    float* ea_out  = emb_out + (size_t)N_NODES * 128;     // [E+N]
    float* imp_out = ea_out + EN_TOT;                     // [N]

    // ---- workspace carve (256B aligned) ----
    char* w = (char*)d_ws;
    auto alloc = [&](size_t bytes) -> void* { void* p = (void*)w; w += (bytes + 255) & ~(size_t)255; return p; };
    ushort* xhh    = (ushort*)alloc((size_t)N_NODES * 512 * 2);  // [N,512] fp16
    ushort* h1h    = (ushort*)alloc((size_t)N_NODES * 512 * 2);  // [N,512] fp16
    ushort* h0h    = (ushort*)alloc((size_t)N_NODES * 128 * 2);  // [N,128] fp16
    ushort* xh2h   = (ushort*)alloc((size_t)N_NODES * 128 * 2);  // [N,128] fp16
    ushort* h2h    = (ushort*)alloc((size_t)N_NODES * 128 * 2);  // [N,128] fp16
    ushort* W1T    = (ushort*)alloc((size_t)512 * 128 * 2);
    ushort* W2T    = (ushort*)alloc((size_t)128 * 512 * 2);
    ushort* WoT    = (ushort*)alloc((size_t)128 * 128 * 2);
    float* L1      = (float*)alloc((size_t)EN_TOT * 4 * 4);      // [E+N,4]
    float* L2      = (float*)alloc((size_t)EN_TOT * 4);          // [E+N]
    int*   csr_src = (int*)alloc((size_t)EN_TOT * 4);
    int*   csr_eid = (int*)alloc((size_t)EN_TOT * 4);
    int*   csr_dst = (int*)alloc((size_t)EN_TOT * 4);
    int*   offsets = (int*)alloc((size_t)(N_NODES + 1) * 4);
    int*   cursor  = (int*)alloc((size_t)N_NODES * 4);
    int*   degi    = (int*)alloc((size_t)N_NODES * 4);
    float* loopat  = (float*)alloc((size_t)N_NODES * 4 * 4);
    float* als1v   = (float*)alloc((size_t)N_NODES * 4 * 4);
    float* ald1v   = (float*)alloc((size_t)N_NODES * 4 * 4);
    float* als2v   = (float*)alloc((size_t)N_NODES * 4);
    float* ald2v   = (float*)alloc((size_t)N_NODES * 4);
    float* M1      = (float*)alloc(32 * 4);
    float* m2      = M1 + 16;

    hipMemsetAsync(degi,   0, (size_t)N_NODES * 4, stream);
    hipMemsetAsync(cursor, 0, (size_t)N_NODES * 4, stream);

    k_deg<<<(N_EDGES + 255) / 256, 256, 0, stream>>>(dst, degi);
    k_scan<<<1, 1024, 0, stream>>>(degi, offsets, We1, ae1, We2, ae2, M1, m2);
    k_fill<<<(EN_TOT + 255) / 256, 256, 0, stream>>>(src, dst, offsets, cursor, csr_src, csr_eid, csr_dst);
    k_loopattr<<<(N_NODES + 3) / 4, 256, 0, stream>>>(offsets, csr_eid, eattr, loopat);
    k_prep<<<576, 256, 0, stream>>>(W1, W2, Wo, W1T, W2T, WoT);
    k_proj<<<N_NODES / 2, 256, 0, stream>>>(x, Wp, bp, h0h);

    // xh = h0 @ W1   [20000,128] x [128,512] -> fp16
    k_gemm_hf<<<dim3((N_NODES + 127) / 128, 4), 256, 0, stream>>>(h0h, W1T, nullptr, xhh,
                                                                  N_NODES, 512, 128, nullptr);
    k_ald1<<<N_NODES, 256, 0, stream>>>(xhh, as1, ad1, als1v, ald1v);
    k_logits1<<<(EN_TOT + 255) / 256, 256, 0, stream>>>(csr_src, csr_dst, csr_eid, eattr, loopat,
                                                        als1v, ald1v, M1, L1);
    k_agg1<<<N_NODES, 256, 0, stream>>>(offsets, csr_src, L1, xhh, b1, g1, be1, h1h);

    // xh2 = h1 @ W2  [20000,512] x [512,128] -> fp16
    k_gemm_hf<<<dim3((N_NODES + 127) / 128, 1), 256, 0, stream>>>(h1h, W2T, nullptr, xh2h,
                                                                  N_NODES, 128, 512, nullptr);
    k_ald2<<<(N_NODES + 3) / 4, 256, 0, stream>>>(xh2h, as2, ad2, als2v, ald2v);
    k_logits2<<<(EN_TOT + 255) / 256, 256, 0, stream>>>(csr_src, csr_dst, csr_eid, eattr, loopat,
                                                        als2v, ald2v, m2, L2);
    k_agg2<<<N_NODES, 128, 0, stream>>>(offsets, csr_src, csr_eid, L2, xh2h, b2, g2, be2, ea_out, h2h);

    // emb = h2 @ Wo + bo -> d_out (fp32)
    k_gemm_hf<<<dim3((N_NODES + 127) / 128, 1), 256, 0, stream>>>(h2h, WoT, emb_out, nullptr,
                                                                  N_NODES, 128, 128, bo);
    k_imp<<<(N_NODES + 3) / 4, 256, 0, stream>>>(emb_out, Wi, bi, imp_out);
}

// Round 6
// 238.760 us; speedup vs baseline: 2.0216x; 1.1154x over previous
//
#include <hip/hip_runtime.h>
#include <math.h>
#include <stdint.h>

#define N_NODES 20000
#define N_EDGES 320000
#define EN_TOT  340000   // E + N (with self loops)
#define CAP     768      // max per-node CSR segment cached in LDS (deg ~ Poisson(16))

typedef __attribute__((ext_vector_type(8))) _Float16 half8v;  // 8 fp16 (4 VGPRs)
typedef __attribute__((ext_vector_type(4))) float float4v;    // MFMA accumulator

__device__ __forceinline__ ushort f2h(float f) {              // fp32 -> fp16 RNE
    _Float16 h = (_Float16)f;
    return __builtin_bit_cast(ushort, h);
}
__device__ __forceinline__ float h2f(ushort s) {
    return (float)__builtin_bit_cast(_Float16, s);
}

// ---------------------------------------------------------------- degree count (1 int atomic / edge)
__global__ void k_deg(const int* __restrict__ dst, int* __restrict__ degi) {
    int e = blockIdx.x * 256 + threadIdx.x;
    if (e >= N_EDGES) return;
    atomicAdd(&degi[dst[e]], 1);
}

// ---------------------------------------------------------------- scan (offsets) + M1/m2 fold
__global__ __launch_bounds__(1024) void k_scan(const int* __restrict__ degi, int* __restrict__ offsets,
                                               const float* __restrict__ We1, const float* __restrict__ ae1,
                                               const float* __restrict__ We2, const float* __restrict__ ae2,
                                               float* __restrict__ M1, float* __restrict__ m2) {
    __shared__ int s[1024];
    int t = threadIdx.x;
    int n0 = t * 20;
    int tot = 0;
    for (int i = 0; i < 20; i++) {
        int n = n0 + i;
        if (n < N_NODES) tot += degi[n] + 1;
    }
    s[t] = tot;
    __syncthreads();
    for (int off = 1; off < 1024; off <<= 1) {
        int v = (t >= off) ? s[t - off] : 0;
        __syncthreads();
        s[t] += v;
        __syncthreads();
    }
    int run = s[t] - tot;
    for (int i = 0; i < 20; i++) {
        int n = n0 + i;
        if (n < N_NODES) {
            offsets[n] = run;
            run += degi[n] + 1;
        }
    }
    if (t == 1023) offsets[N_NODES] = s[1023];
    if (t < 16) {
        int f = t >> 2, h = t & 3;
        float acc = 0.f;
        for (int c = 0; c < 128; c++) acc += We1[f * 512 + h * 128 + c] * ae1[h * 128 + c];
        M1[f * 4 + h] = acc;
    } else if (t < 20) {
        int f = t - 16;
        float acc = 0.f;
        for (int c = 0; c < 128; c++) acc += We2[f * 128 + c] * ae2[c];
        m2[f] = acc;
    }
}

// ---------------------------------------------------------------- CSR fill: packed (src, eid) int2
__global__ void k_fill(const int* __restrict__ src, const int* __restrict__ dst,
                       const int* __restrict__ offsets, int* __restrict__ cursor,
                       int2* __restrict__ csr_se) {
    int i = blockIdx.x * 256 + threadIdx.x;
    if (i >= EN_TOT) return;
    int d, sidx, eid;
    if (i < N_EDGES) { d = dst[i]; sidx = src[i]; eid = i; }
    else { int n = i - N_EDGES; d = n; sidx = n; eid = N_EDGES + n; }
    int pos = offsets[d] + atomicAdd(&cursor[d], 1);
    csr_se[pos] = make_int2(sidx, eid);
}

// ---------------------------------------------------------------- loop_attr = mean of incoming eattr (no atomics)
__global__ __launch_bounds__(256) void k_loopattr(const int* __restrict__ offsets,
                                                  const int2* __restrict__ csr_se,
                                                  const float* __restrict__ eattr,
                                                  float* __restrict__ loopattr) {
    int wv = threadIdx.x >> 6, l = threadIdx.x & 63;
    int n = blockIdx.x * 4 + wv;
    if (n >= N_NODES) return;
    int start = offsets[n], end = offsets[n + 1];
    float sx = 0.f, sy = 0.f, sz = 0.f, sw = 0.f;
    for (int p = start + l; p < end; p += 64) {
        int eid = csr_se[p].y;
        if (eid < N_EDGES) {
            float4 e = *(const float4*)&eattr[(size_t)eid * 4];
            sx += e.x; sy += e.y; sz += e.z; sw += e.w;
        }
    }
    for (int off = 32; off; off >>= 1) {
        sx += __shfl_down(sx, off);
        sy += __shfl_down(sy, off);
        sz += __shfl_down(sz, off);
        sw += __shfl_down(sw, off);
    }
    if (l == 0) {
        float inv = 1.0f / fmaxf((float)(end - start - 1), 1.0f);
        float4 o;
        o.x = sx * inv; o.y = sy * inv; o.z = sz * inv; o.w = sw * inv;
        *(float4*)&loopattr[(size_t)n * 4] = o;
    }
}

// ---------------------------------------------------------------- weight transpose + fp16 convert
__global__ void k_prep(const float* __restrict__ W1, const float* __restrict__ W2,
                       const float* __restrict__ Wo, ushort* __restrict__ W1T,
                       ushort* __restrict__ W2T, ushort* __restrict__ WoT) {
    int i = blockIdx.x * 256 + threadIdx.x;
    if (i < 512 * 128) {
        int nn = i >> 7, kk = i & 127;
        W1T[i] = f2h(W1[kk * 512 + nn]);
    } else if (i < 2 * 512 * 128) {
        int j = i - 512 * 128;
        int nn = j >> 9, kk = j & 511;
        W2T[j] = f2h(W2[kk * 128 + nn]);
    } else if (i < 2 * 512 * 128 + 128 * 128) {
        int j = i - 2 * 512 * 128;
        int nn = j >> 7, kk = j & 127;
        WoT[j] = f2h(Wo[kk * 128 + nn]);
    }
}

// ---------------------------------------------------------------- input proj: h0 = x @ Wp + bp (fp16 out)
__global__ __launch_bounds__(256) void k_proj(const float* __restrict__ x, const float* __restrict__ Wp,
                                              const float* __restrict__ bp, ushort* __restrict__ h0h) {
    int tid = threadIdx.x;
    int n = blockIdx.x * 2 + (tid >> 7);
    int c = tid & 127;
    float acc = bp[c];
#pragma unroll
    for (int f = 0; f < 4; f++) acc += x[n * 4 + f] * Wp[f * 128 + c];
    h0h[(size_t)n * 128 + c] = f2h(acc);
}

// ---------------------------------------------------------------- MFMA fp16 GEMM: C[M,Nn] = A[M,K] @ BT[Nn,K]^T
// BM=64 x BN=128 tile, BK=64; 4 waves each cover 64x32; XOR-swizzled LDS.
__global__ __launch_bounds__(256) void k_gemm_hf(const ushort* __restrict__ A, const ushort* __restrict__ BT,
                                                 float* __restrict__ Cf, ushort* __restrict__ Ch,
                                                 int M, int Nn, int K, const float* __restrict__ bias) {
    __shared__ ushort As[64 * 64];    // 8 KB
    __shared__ ushort Bs[128 * 64];   // 16 KB
    const int tid = threadIdx.x;
    const int lane = tid & 63, wid = tid >> 6;
    const int m0 = blockIdx.x * 64, n0 = blockIdx.y * 128;
    float4v acc[4][2];
#pragma unroll
    for (int i = 0; i < 4; i++)
#pragma unroll
        for (int j = 0; j < 2; j++) acc[i][j] = (float4v){0.f, 0.f, 0.f, 0.f};

    for (int k0 = 0; k0 < K; k0 += 64) {
        __syncthreads();
#pragma unroll
        for (int i = 0; i < 2; i++) {           // A: 64 rows x 8 chunks
            int c = tid + i * 256;
            int row = c >> 3, sl = c & 7;
            int off = row * 128 + ((sl ^ (row & 7)) << 4);
            uint4 va = make_uint4(0u, 0u, 0u, 0u);
            if (m0 + row < M) va = *(const uint4*)&A[(size_t)(m0 + row) * K + k0 + sl * 8];
            *(uint4*)((char*)As + off) = va;
        }
#pragma unroll
        for (int i = 0; i < 4; i++) {           // B: 128 rows x 8 chunks
            int c = tid + i * 256;
            int row = c >> 3, sl = c & 7;
            int off = row * 128 + ((sl ^ (row & 7)) << 4);
            uint4 vb = *(const uint4*)&BT[(size_t)(n0 + row) * K + k0 + sl * 8];
            *(uint4*)((char*)Bs + off) = vb;
        }
        __syncthreads();
#pragma unroll
        for (int kk = 0; kk < 2; kk++) {
            half8v af[4], bq[2];
            int sl = kk * 4 + (lane >> 4);
#pragma unroll
            for (int mi = 0; mi < 4; mi++) {
                int row = (lane & 15) + mi * 16;
                af[mi] = *(const half8v*)((const char*)As + row * 128 + ((sl ^ (row & 7)) << 4));
            }
#pragma unroll
            for (int ni = 0; ni < 2; ni++) {
                int row = wid * 32 + ni * 16 + (lane & 15);
                bq[ni] = *(const half8v*)((const char*)Bs + row * 128 + ((sl ^ (row & 7)) << 4));
            }
#pragma unroll
            for (int mi = 0; mi < 4; mi++)
#pragma unroll
                for (int ni = 0; ni < 2; ni++)
                    acc[mi][ni] = __builtin_amdgcn_mfma_f32_16x16x32_f16(af[mi], bq[ni], acc[mi][ni], 0, 0, 0);
        }
    }
#pragma unroll
    for (int mi = 0; mi < 4; mi++) {
#pragma unroll
        for (int j = 0; j < 4; j++) {
            int row = m0 + mi * 16 + ((lane >> 4) << 2) + j;
            if (row < M) {
#pragma unroll
                for (int ni = 0; ni < 2; ni++) {
                    int col = n0 + wid * 32 + ni * 16 + (lane & 15);
                    float v = acc[mi][ni][j];
                    if (bias) v += bias[col];
                    if (Cf) Cf[(size_t)row * Nn + col] = v;
                    if (Ch) Ch[(size_t)row * Nn + col] = f2h(v);
                }
            }
        }
    }
}

// ---------------------------------------------------------------- attention src/dst logit terms, layer 1 (fp16 xh)
__global__ __launch_bounds__(256) void k_ald1(const ushort* __restrict__ xhh, const float* __restrict__ as1,
                                              const float* __restrict__ ad1, float* __restrict__ als,
                                              float* __restrict__ ald) {
    int n = blockIdx.x;
    int w = threadIdx.x >> 6, l = threadIdx.x & 63;
    uint v = *(const uint*)&xhh[(size_t)n * 512 + w * 128 + l * 2];
    float f0 = h2f((ushort)(v & 0xffffu));
    float f1 = h2f((ushort)(v >> 16));
    float2 a = *(const float2*)&as1[w * 128 + l * 2];
    float2 b = *(const float2*)&ad1[w * 128 + l * 2];
    float ps = f0 * a.x + f1 * a.y, pd = f0 * b.x + f1 * b.y;
    for (int off = 32; off; off >>= 1) { ps += __shfl_down(ps, off); pd += __shfl_down(pd, off); }
    if (l == 0) { als[n * 4 + w] = ps; ald[n * 4 + w] = pd; }
}

// ---------------------------------------------------------------- same for layer 2 (1 head)
__global__ __launch_bounds__(256) void k_ald2(const ushort* __restrict__ xh2h, const float* __restrict__ as2,
                                              const float* __restrict__ ad2, float* __restrict__ als,
                                              float* __restrict__ ald) {
    int w = threadIdx.x >> 6, l = threadIdx.x & 63;
    int n = blockIdx.x * 4 + w;
    if (n >= N_NODES) return;
    uint v = *(const uint*)&xh2h[(size_t)n * 128 + l * 2];
    float f0 = h2f((ushort)(v & 0xffffu));
    float f1 = h2f((ushort)(v >> 16));
    float2 a = *(const float2*)&as2[l * 2];
    float2 b = *(const float2*)&ad2[l * 2];
    float ps = f0 * a.x + f1 * a.y, pd = f0 * b.x + f1 * b.y;
    for (int off = 32; off; off >>= 1) { ps += __shfl_down(ps, off); pd += __shfl_down(pd, off); }
    if (l == 0) { als[n] = ps; ald[n] = pd; }
}

// ---------------------------------------------------------------- layer-1: fused logits + softmax + gather + LN + ELU
// 128 thr (2 waves). Logits cached in LDS; barrier-free unroll-4 gather; thread owns 4 channels.
__global__ __launch_bounds__(128) void k_agg1(const int* __restrict__ offsets, const int2* __restrict__ csr_se,
                                              const float* __restrict__ eattr, const float* __restrict__ loopattr,
                                              const float* __restrict__ als, const float* __restrict__ aldv,
                                              const float* __restrict__ M1, const ushort* __restrict__ xhh,
                                              const float* __restrict__ b1, const float* __restrict__ g1,
                                              const float* __restrict__ be1, ushort* __restrict__ h1h) {
    int n = blockIdx.x;
    int start = offsets[n];
    int cnt = offsets[n + 1] - start;
    int tid = threadIdx.x;
    int lane = tid & 63, wv = tid >> 6;
    __shared__ float Lc[CAP][4];
    __shared__ int   sSrc[CAP];
    __shared__ float mws[2][4], sws[2][4];
    __shared__ float mh[4], shv[4];
    __shared__ float wred[2], wred2[2];

    // ---- phase A: inline logits + online softmax stats (4 lanes per edge)
    int hh = tid & 3;
    float aldn = aldv[n * 4 + hh];
    float c0 = M1[0 * 4 + hh], c1 = M1[1 * 4 + hh], c2 = M1[2 * 4 + hh], c3 = M1[3 * 4 + hh];
    float m = -1e30f, s = 0.f;
    for (int j = tid >> 2; j < cnt; j += 32) {
        int p = start + j;
        int2 se = csr_se[p];
        const float* eap = (se.y < N_EDGES) ? &eattr[(size_t)se.y * 4] : &loopattr[(size_t)(se.y - N_EDGES) * 4];
        float4 e4 = *(const float4*)eap;
        float l = als[se.x * 4 + hh] + aldn + e4.x * c0 + e4.y * c1 + e4.z * c2 + e4.w * c3;
        l = (l >= 0.f) ? l : 0.2f * l;
        Lc[j][hh] = l;
        if (hh == 0) sSrc[j] = se.x;
        float mn = fmaxf(m, l);
        s = s * __expf(m - mn) + __expf(l - mn);
        m = mn;
    }
#pragma unroll
    for (int off = 4; off < 64; off <<= 1) {
        float mo = __shfl_xor(m, off), so = __shfl_xor(s, off);
        float mn = fmaxf(m, mo);
        s = s * __expf(m - mn) + so * __expf(mo - mn);
        m = mn;
    }
    if (lane < 4) { mws[wv][lane] = m; sws[wv][lane] = s; }
    __syncthreads();
    if (tid < 4) {
        float M0 = mws[0][tid], S0 = sws[0][tid];
        float M1b = mws[1][tid], S1 = sws[1][tid];
        float mn = fmaxf(M0, M1b);
        float S = S0 * __expf(M0 - mn) + S1 * __expf(M1b - mn);
        mh[tid] = mn; shv[tid] = 1.0f / S;
    }
    __syncthreads();
    // ---- phase A2: logits -> alpha (in place)
    int tot = cnt * 4;
    for (int idx = tid; idx < tot; idx += 128) {
        int j = idx >> 2, h = idx & 3;
        Lc[j][h] = __expf(Lc[j][h] - mh[h]) * shv[h];
    }
    __syncthreads();

    // ---- gather: barrier-free, 4 edges in flight; thread owns channels 4t..4t+3
    float acc0 = 0.f, acc1 = 0.f, acc2 = 0.f, acc3 = 0.f;
    int hg = tid >> 5;                 // head of channels 4t..4t+3
    uint ch = (uint)tid * 4u;
    int j = 0;
    for (; j + 4 <= cnt; j += 4) {
        float a0 = Lc[j][hg], a1 = Lc[j + 1][hg], a2 = Lc[j + 2][hg], a3 = Lc[j + 3][hg];
        uint o0 = ((uint)sSrc[j] << 9) + ch;
        uint o1 = ((uint)sSrc[j + 1] << 9) + ch;
        uint o2 = ((uint)sSrc[j + 2] << 9) + ch;
        uint o3 = ((uint)sSrc[j + 3] << 9) + ch;
        uint2 v0 = *(const uint2*)&xhh[o0];
        uint2 v1 = *(const uint2*)&xhh[o1];
        uint2 v2 = *(const uint2*)&xhh[o2];
        uint2 v3 = *(const uint2*)&xhh[o3];
        acc0 += a0 * h2f((ushort)(v0.x & 0xffffu)) + a1 * h2f((ushort)(v1.x & 0xffffu))
              + a2 * h2f((ushort)(v2.x & 0xffffu)) + a3 * h2f((ushort)(v3.x & 0xffffu));
        acc1 += a0 * h2f((ushort)(v0.x >> 16)) + a1 * h2f((ushort)(v1.x >> 16))
              + a2 * h2f((ushort)(v2.x >> 16)) + a3 * h2f((ushort)(v3.x >> 16));
        acc2 += a0 * h2f((ushort)(v0.y & 0xffffu)) + a1 * h2f((ushort)(v1.y & 0xffffu))
              + a2 * h2f((ushort)(v2.y & 0xffffu)) + a3 * h2f((ushort)(v3.y & 0xffffu));
        acc3 += a0 * h2f((ushort)(v0.y >> 16)) + a1 * h2f((ushort)(v1.y >> 16))
              + a2 * h2f((ushort)(v2.y >> 16)) + a3 * h2f((ushort)(v3.y >> 16));
    }
    for (; j < cnt; j++) {
        float a = Lc[j][hg];
        uint2 v = *(const uint2*)&xhh[((uint)sSrc[j] << 9) + ch];
        acc0 += a * h2f((ushort)(v.x & 0xffffu));
        acc1 += a * h2f((ushort)(v.x >> 16));
        acc2 += a * h2f((ushort)(v.y & 0xffffu));
        acc3 += a * h2f((ushort)(v.y >> 16));
    }

    // ---- + bias, LayerNorm(512), ELU (2-wave combine)
    float4 bb = *(const float4*)&b1[tid * 4];
    float v0 = acc0 + bb.x, v1 = acc1 + bb.y, v2 = acc2 + bb.z, v3 = acc3 + bb.w;
    float s4 = v0 + v1 + v2 + v3;
#pragma unroll
    for (int off = 1; off < 64; off <<= 1) s4 += __shfl_xor(s4, off);
    if (lane == 0) wred[wv] = s4;
    __syncthreads();
    float mu = (wred[0] + wred[1]) * (1.0f / 512.0f);
    float d0 = v0 - mu, d1 = v1 - mu, d2 = v2 - mu, d3 = v3 - mu;
    float sq = d0 * d0 + d1 * d1 + d2 * d2 + d3 * d3;
#pragma unroll
    for (int off = 1; off < 64; off <<= 1) sq += __shfl_xor(sq, off);
    if (lane == 0) wred2[wv] = sq;
    __syncthreads();
    float rstd = rsqrtf((wred2[0] + wred2[1]) * (1.0f / 512.0f) + 1e-5f);
    float4 gg = *(const float4*)&g1[tid * 4];
    float4 ee = *(const float4*)&be1[tid * 4];
    float y0 = d0 * rstd * gg.x + ee.x;
    float y1 = d1 * rstd * gg.y + ee.y;
    float y2 = d2 * rstd * gg.z + ee.z;
    float y3 = d3 * rstd * gg.w + ee.w;
    y0 = (y0 > 0.f) ? y0 : (__expf(y0) - 1.0f);
    y1 = (y1 > 0.f) ? y1 : (__expf(y1) - 1.0f);
    y2 = (y2 > 0.f) ? y2 : (__expf(y2) - 1.0f);
    y3 = (y3 > 0.f) ? y3 : (__expf(y3) - 1.0f);
    uint2 o;
    o.x = (uint)f2h(y0) | ((uint)f2h(y1) << 16);
    o.y = (uint)f2h(y2) | ((uint)f2h(y3) << 16);
    *(uint2*)&h1h[(size_t)n * 512 + tid * 4] = o;
}

// ---------------------------------------------------------------- layer-2: fused logits + softmax + alpha-out + gather + LN
// 64 thr (1 wave); lane owns 2 channels; single barrier.
__global__ __launch_bounds__(64) void k_agg2(const int* __restrict__ offsets, const int2* __restrict__ csr_se,
                                             const float* __restrict__ eattr, const float* __restrict__ loopattr,
                                             const float* __restrict__ als, const float* __restrict__ aldv,
                                             const float* __restrict__ m2v, const ushort* __restrict__ xh2h,
                                             const float* __restrict__ b2, const float* __restrict__ g2,
                                             const float* __restrict__ be2, float* __restrict__ eaout,
                                             ushort* __restrict__ h2h) {
    int n = blockIdx.x;
    int start = offsets[n];
    int cnt = offsets[n + 1] - start;
    int lane = threadIdx.x;
    __shared__ float Lc[CAP];
    __shared__ int   sSrc[CAP];
    __shared__ int   sEid[CAP];

    float aldn = aldv[n];
    float c0 = m2v[0], c1 = m2v[1], c2 = m2v[2], c3 = m2v[3];
    float m = -1e30f, s = 0.f;
    for (int j = lane; j < cnt; j += 64) {
        int p = start + j;
        int2 se = csr_se[p];
        const float* eap = (se.y < N_EDGES) ? &eattr[(size_t)se.y * 4] : &loopattr[(size_t)(se.y - N_EDGES) * 4];
        float4 e4 = *(const float4*)eap;
        float l = als[se.x] + aldn + e4.x * c0 + e4.y * c1 + e4.z * c2 + e4.w * c3;
        l = (l >= 0.f) ? l : 0.2f * l;
        Lc[j] = l; sSrc[j] = se.x; sEid[j] = se.y;
        float mn = fmaxf(m, l);
        s = s * __expf(m - mn) + __expf(l - mn);
        m = mn;
    }
#pragma unroll
    for (int off = 1; off < 64; off <<= 1) {
        float mo = __shfl_xor(m, off), so = __shfl_xor(s, off);
        float mn = fmaxf(m, mo);
        s = s * __expf(m - mn) + so * __expf(mo - mn);
        m = mn;
    }
    float inv = 1.0f / s;
    // alpha (own entries) + edge_attention output
    for (int j = lane; j < cnt; j += 64) {
        float a = __expf(Lc[j] - m) * inv;
        Lc[j] = a;
        eaout[sEid[j]] = a;
    }
    __syncthreads();
    // gather: lane owns channels 2l, 2l+1; 4 edges in flight
    float acc0 = 0.f, acc1 = 0.f;
    uint ch = (uint)lane * 2u;
    int j = 0;
    for (; j + 4 <= cnt; j += 4) {
        float a0 = Lc[j], a1 = Lc[j + 1], a2 = Lc[j + 2], a3 = Lc[j + 3];
        uint v0 = *(const uint*)&xh2h[((uint)sSrc[j] << 7) + ch];
        uint v1 = *(const uint*)&xh2h[((uint)sSrc[j + 1] << 7) + ch];
        uint v2 = *(const uint*)&xh2h[((uint)sSrc[j + 2] << 7) + ch];
        uint v3 = *(const uint*)&xh2h[((uint)sSrc[j + 3] << 7) + ch];
        acc0 += a0 * h2f((ushort)(v0 & 0xffffu)) + a1 * h2f((ushort)(v1 & 0xffffu))
              + a2 * h2f((ushort)(v2 & 0xffffu)) + a3 * h2f((ushort)(v3 & 0xffffu));
        acc1 += a0 * h2f((ushort)(v0 >> 16)) + a1 * h2f((ushort)(v1 >> 16))
              + a2 * h2f((ushort)(v2 >> 16)) + a3 * h2f((ushort)(v3 >> 16));
    }
    for (; j < cnt; j++) {
        float a = Lc[j];
        uint v = *(const uint*)&xh2h[((uint)sSrc[j] << 7) + ch];
        acc0 += a * h2f((ushort)(v & 0xffffu));
        acc1 += a * h2f((ushort)(v >> 16));
    }
    // bias + LN(128) within the wave
    float2 bb = *(const float2*)&b2[lane * 2];
    float v0 = acc0 + bb.x, v1 = acc1 + bb.y;
    float s2 = v0 + v1;
#pragma unroll
    for (int off = 1; off < 64; off <<= 1) s2 += __shfl_xor(s2, off);
    float mu = s2 * (1.0f / 128.0f);
    float d0 = v0 - mu, d1 = v1 - mu;
    float q = d0 * d0 + d1 * d1;
#pragma unroll
    for (int off = 1; off < 64; off <<= 1) q += __shfl_xor(q, off);
    float rstd = rsqrtf(q * (1.0f / 128.0f) + 1e-5f);
    float2 gg = *(const float2*)&g2[lane * 2];
    float2 ee = *(const float2*)&be2[lane * 2];
    float y0 = d0 * rstd * gg.x + ee.x;
    float y1 = d1 * rstd * gg.y + ee.y;
    uint o = (uint)f2h(y0) | ((uint)f2h(y1) << 16);
    *(uint*)&h2h[(size_t)n * 128 + lane * 2] = o;
}

// ---------------------------------------------------------------- importance = sigmoid(emb @ Wi + bi)
__global__ __launch_bounds__(256) void k_imp(const float* __restrict__ emb, const float* __restrict__ Wi,
                                             const float* __restrict__ bi, float* __restrict__ impout) {
    int w = threadIdx.x >> 6, l = threadIdx.x & 63;
    int n = blockIdx.x * 4 + w;
    if (n >= N_NODES) return;
    const float* ep = &emb[(size_t)n * 128];
    float p = ep[l] * Wi[l] + ep[l + 64] * Wi[l + 64];
    for (int off = 32; off; off >>= 1) p += __shfl_down(p, off);
    if (l == 0) impout[n] = 1.0f / (1.0f + expf(-(p + bi[0])));
}

// ================================================================ launch
extern "C" void kernel_launch(void* const* d_in, const int* in_sizes, int n_in,
                              void* d_out, int out_size, void* d_ws, size_t ws_size,
                              hipStream_t stream) {
    const float* x    = (const float*)d_in[0];
    const int*   eidx = (const int*)d_in[1];
    const float* eattr= (const float*)d_in[2];
    const float* Wp   = (const float*)d_in[3];
    const float* bp   = (const float*)d_in[4];
    const float* W1   = (const float*)d_in[5];
    const float* We1  = (const float*)d_in[6];
    const float* as1  = (const float*)d_in[7];
    const float* ad1  = (const float*)d_in[8];
    const float* ae1  = (const float*)d_in[9];
    const float* b1   = (const float*)d_in[10];
    const float* g1   = (const float*)d_in[11];
    const float* be1  = (const float*)d_in[12];
    const float* W2   = (const float*)d_in[13];
    const float* We2  = (const float*)d_in[14];
    const float* as2  = (const float*)d_in[15];
    const float* ad2  = (const float*)d_in[16];
    const float* ae2  = (const float*)d_in[17];
    const float* b2   = (const float*)d_in[18];
    const float* g2   = (const float*)d_in[19];
    const float* be2  = (const float*)d_in[20];
    const float* Wo   = (const float*)d_in[21];
    const float* bo   = (const float*)d_in[22];
    const float* Wi   = (const float*)d_in[23];
    const float* bi   = (const float*)d_in[24];

    const int* src = eidx;
    const int* dst = eidx + N_EDGES;

    float* emb_out = (float*)d_out;                       // [N,128]
    float* ea_out  = emb_out + (size_t)N_NODES * 128;     // [E+N]
    float* imp_out = ea_out + EN_TOT;                     // [N]

    // ---- workspace carve (256B aligned) ----
    char* w = (char*)d_ws;
    auto alloc = [&](size_t bytes) -> void* { void* p = (void*)w; w += (bytes + 255) & ~(size_t)255; return p; };
    ushort* xhh    = (ushort*)alloc((size_t)N_NODES * 512 * 2);  // [N,512] fp16
    ushort* h1h    = (ushort*)alloc((size_t)N_NODES * 512 * 2);  // [N,512] fp16
    ushort* h0h    = (ushort*)alloc((size_t)N_NODES * 128 * 2);  // [N,128] fp16
    ushort* xh2h   = (ushort*)alloc((size_t)N_NODES * 128 * 2);  // [N,128] fp16
    ushort* h2h    = (ushort*)alloc((size_t)N_NODES * 128 * 2);  // [N,128] fp16
    ushort* W1T    = (ushort*)alloc((size_t)512 * 128 * 2);
    ushort* W2T    = (ushort*)alloc((size_t)128 * 512 * 2);
    ushort* WoT    = (ushort*)alloc((size_t)128 * 128 * 2);
    int2*  csr_se  = (int2*)alloc((size_t)EN_TOT * 8);
    int*   offsets = (int*)alloc((size_t)(N_NODES + 1) * 4);
    int*   cursor  = (int*)alloc((size_t)N_NODES * 4);
    int*   degi    = (int*)alloc((size_t)N_NODES * 4);
    float* loopat  = (float*)alloc((size_t)N_NODES * 4 * 4);
    float* als1v   = (float*)alloc((size_t)N_NODES * 4 * 4);
    float* ald1v   = (float*)alloc((size_t)N_NODES * 4 * 4);
    float* als2v   = (float*)alloc((size_t)N_NODES * 4);
    float* ald2v   = (float*)alloc((size_t)N_NODES * 4);
    float* M1      = (float*)alloc(32 * 4);
    float* m2      = M1 + 16;

    hipMemsetAsync(degi,   0, (size_t)N_NODES * 4, stream);
    hipMemsetAsync(cursor, 0, (size_t)N_NODES * 4, stream);

    k_deg<<<(N_EDGES + 255) / 256, 256, 0, stream>>>(dst, degi);
    k_scan<<<1, 1024, 0, stream>>>(degi, offsets, We1, ae1, We2, ae2, M1, m2);
    k_fill<<<(EN_TOT + 255) / 256, 256, 0, stream>>>(src, dst, offsets, cursor, csr_se);
    k_loopattr<<<(N_NODES + 3) / 4, 256, 0, stream>>>(offsets, csr_se, eattr, loopat);
    k_prep<<<576, 256, 0, stream>>>(W1, W2, Wo, W1T, W2T, WoT);
    k_proj<<<N_NODES / 2, 256, 0, stream>>>(x, Wp, bp, h0h);

    // xh = h0 @ W1   [20000,128] x [128,512] -> fp16
    k_gemm_hf<<<dim3((N_NODES + 63) / 64, 4), 256, 0, stream>>>(h0h, W1T, nullptr, xhh,
                                                                N_NODES, 512, 128, nullptr);
    k_ald1<<<N_NODES, 256, 0, stream>>>(xhh, as1, ad1, als1v, ald1v);
    k_agg1<<<N_NODES, 128, 0, stream>>>(offsets, csr_se, eattr, loopat, als1v, ald1v, M1,
                                        xhh, b1, g1, be1, h1h);

    // xh2 = h1 @ W2  [20000,512] x [512,128] -> fp16
    k_gemm_hf<<<dim3((N_NODES + 63) / 64, 1), 256, 0, stream>>>(h1h, W2T, nullptr, xh2h,
                                                                N_NODES, 128, 512, nullptr);
    k_ald2<<<(N_NODES + 3) / 4, 256, 0, stream>>>(xh2h, as2, ad2, als2v, ald2v);
    k_agg2<<<N_NODES, 64, 0, stream>>>(offsets, csr_se, eattr, loopat, als2v, ald2v, m2,
                                       xh2h, b2, g2, be2, ea_out, h2h);

    // emb = h2 @ Wo + bo -> d_out (fp32)
    k_gemm_hf<<<dim3((N_NODES + 63) / 64, 1), 256, 0, stream>>>(h2h, WoT, emb_out, nullptr,
                                                                N_NODES, 128, 128, bo);
    k_imp<<<(N_NODES + 3) / 4, 256, 0, stream>>>(emb_out, Wi, bi, imp_out);
}

// Round 7
// 220.483 us; speedup vs baseline: 2.1892x; 1.0829x over previous
//
#include <hip/hip_runtime.h>
#include <math.h>
#include <stdint.h>

#define N_NODES 20000
#define N_EDGES 320000
#define EN_TOT  340000   // E + N (with self loops)
#define CAP     160      // max per-node CSR segment (deg ~ Poisson(16); 160 is >30 sigma)

typedef __attribute__((ext_vector_type(8))) _Float16 half8v;  // 8 fp16 (4 VGPRs)
typedef __attribute__((ext_vector_type(4))) float float4v;    // MFMA accumulator

__device__ __forceinline__ ushort f2h(float f) {              // fp32 -> fp16 RNE
    _Float16 h = (_Float16)f;
    return __builtin_bit_cast(ushort, h);
}
__device__ __forceinline__ float h2f(ushort s) {
    return (float)__builtin_bit_cast(_Float16, s);
}

// ---------------------------------------------------------------- degree count (1 int atomic / edge)
__global__ void k_deg(const int* __restrict__ dst, int* __restrict__ degi) {
    int e = blockIdx.x * 256 + threadIdx.x;
    if (e >= N_EDGES) return;
    atomicAdd(&degi[dst[e]], 1);
}

// ---------------------------------------------------------------- scan (offsets) + M1/m2 fold
__global__ __launch_bounds__(1024) void k_scan(const int* __restrict__ degi, int* __restrict__ offsets,
                                               const float* __restrict__ We1, const float* __restrict__ ae1,
                                               const float* __restrict__ We2, const float* __restrict__ ae2,
                                               float* __restrict__ M1, float* __restrict__ m2) {
    __shared__ int s[1024];
    int t = threadIdx.x;
    int n0 = t * 20;
    int tot = 0;
    for (int i = 0; i < 20; i++) {
        int n = n0 + i;
        if (n < N_NODES) tot += degi[n] + 1;
    }
    s[t] = tot;
    __syncthreads();
    for (int off = 1; off < 1024; off <<= 1) {
        int v = (t >= off) ? s[t - off] : 0;
        __syncthreads();
        s[t] += v;
        __syncthreads();
    }
    int run = s[t] - tot;
    for (int i = 0; i < 20; i++) {
        int n = n0 + i;
        if (n < N_NODES) {
            offsets[n] = run;
            run += degi[n] + 1;
        }
    }
    if (t == 1023) offsets[N_NODES] = s[1023];
    if (t < 16) {
        int f = t >> 2, h = t & 3;
        float acc = 0.f;
        for (int c = 0; c < 128; c++) acc += We1[f * 512 + h * 128 + c] * ae1[h * 128 + c];
        M1[f * 4 + h] = acc;
    } else if (t < 20) {
        int f = t - 16;
        float acc = 0.f;
        for (int c = 0; c < 128; c++) acc += We2[f * 128 + c] * ae2[c];
        m2[f] = acc;
    }
}

// ---------------------------------------------------------------- CSR fill: packed (src, eid) int2
__global__ void k_fill(const int* __restrict__ src, const int* __restrict__ dst,
                       const int* __restrict__ offsets, int* __restrict__ cursor,
                       int2* __restrict__ csr_se) {
    int i = blockIdx.x * 256 + threadIdx.x;
    if (i >= EN_TOT) return;
    int d, sidx, eid;
    if (i < N_EDGES) { d = dst[i]; sidx = src[i]; eid = i; }
    else { int n = i - N_EDGES; d = n; sidx = n; eid = N_EDGES + n; }
    int pos = offsets[d] + atomicAdd(&cursor[d], 1);
    csr_se[pos] = make_int2(sidx, eid);
}

// ---------------------------------------------------------------- merged: loop_attr | weight prep | input proj
// blocks [0,5000): loopattr (4 nodes/blk); [5000,5576): prep; [5576,15576): proj (2 nodes/blk)
__global__ __launch_bounds__(256) void k_misc(const int* __restrict__ offsets, const int2* __restrict__ csr_se,
                                              const float* __restrict__ eattr, float* __restrict__ loopattr,
                                              const float* __restrict__ W1, const float* __restrict__ W2,
                                              const float* __restrict__ Wo, ushort* __restrict__ W1T,
                                              ushort* __restrict__ W2T, ushort* __restrict__ WoT,
                                              const float* __restrict__ x, const float* __restrict__ Wp,
                                              const float* __restrict__ bp, ushort* __restrict__ h0h) {
    int b = blockIdx.x;
    int tid = threadIdx.x;
    if (b < 5000) {
        int wv = tid >> 6, l = tid & 63;
        int n = b * 4 + wv;
        if (n >= N_NODES) return;
        int start = offsets[n], end = offsets[n + 1];
        float sx = 0.f, sy = 0.f, sz = 0.f, sw = 0.f;
        for (int p = start + l; p < end; p += 64) {
            int eid = csr_se[p].y;
            if (eid < N_EDGES) {
                float4 e = *(const float4*)&eattr[(size_t)eid * 4];
                sx += e.x; sy += e.y; sz += e.z; sw += e.w;
            }
        }
        for (int off = 32; off; off >>= 1) {
            sx += __shfl_down(sx, off);
            sy += __shfl_down(sy, off);
            sz += __shfl_down(sz, off);
            sw += __shfl_down(sw, off);
        }
        if (l == 0) {
            float inv = 1.0f / fmaxf((float)(end - start - 1), 1.0f);
            float4 o;
            o.x = sx * inv; o.y = sy * inv; o.z = sz * inv; o.w = sw * inv;
            *(float4*)&loopattr[(size_t)n * 4] = o;
        }
    } else if (b < 5576) {
        int i = (b - 5000) * 256 + tid;
        if (i < 512 * 128) {
            int nn = i >> 7, kk = i & 127;
            W1T[i] = f2h(W1[kk * 512 + nn]);
        } else if (i < 2 * 512 * 128) {
            int j = i - 512 * 128;
            int nn = j >> 9, kk = j & 511;
            W2T[j] = f2h(W2[kk * 128 + nn]);
        } else if (i < 2 * 512 * 128 + 128 * 128) {
            int j = i - 2 * 512 * 128;
            int nn = j >> 7, kk = j & 127;
            WoT[j] = f2h(Wo[kk * 128 + nn]);
        }
    } else {
        int n = (b - 5576) * 2 + (tid >> 7);
        int c = tid & 127;
        float acc = bp[c];
#pragma unroll
        for (int f = 0; f < 4; f++) acc += x[n * 4 + f] * Wp[f * 128 + c];
        h0h[(size_t)n * 128 + c] = f2h(acc);
    }
}

// ---------------------------------------------------------------- MFMA fp16 GEMM: C[M,Nn] = A[M,K] @ BT[Nn,K]^T
// BM=64 x BN=128 tile, BK=64; 4 waves each cover 64x32; XOR-swizzled LDS.
__global__ __launch_bounds__(256) void k_gemm_hf(const ushort* __restrict__ A, const ushort* __restrict__ BT,
                                                 float* __restrict__ Cf, ushort* __restrict__ Ch,
                                                 int M, int Nn, int K, const float* __restrict__ bias) {
    __shared__ ushort As[64 * 64];    // 8 KB
    __shared__ ushort Bs[128 * 64];   // 16 KB
    const int tid = threadIdx.x;
    const int lane = tid & 63, wid = tid >> 6;
    const int m0 = blockIdx.x * 64, n0 = blockIdx.y * 128;
    float4v acc[4][2];
#pragma unroll
    for (int i = 0; i < 4; i++)
#pragma unroll
        for (int j = 0; j < 2; j++) acc[i][j] = (float4v){0.f, 0.f, 0.f, 0.f};

    for (int k0 = 0; k0 < K; k0 += 64) {
        __syncthreads();
#pragma unroll
        for (int i = 0; i < 2; i++) {           // A: 64 rows x 8 chunks
            int c = tid + i * 256;
            int row = c >> 3, sl = c & 7;
            int off = row * 128 + ((sl ^ (row & 7)) << 4);
            uint4 va = make_uint4(0u, 0u, 0u, 0u);
            if (m0 + row < M) va = *(const uint4*)&A[(size_t)(m0 + row) * K + k0 + sl * 8];
            *(uint4*)((char*)As + off) = va;
        }
#pragma unroll
        for (int i = 0; i < 4; i++) {           // B: 128 rows x 8 chunks
            int c = tid + i * 256;
            int row = c >> 3, sl = c & 7;
            int off = row * 128 + ((sl ^ (row & 7)) << 4);
            uint4 vb = *(const uint4*)&BT[(size_t)(n0 + row) * K + k0 + sl * 8];
            *(uint4*)((char*)Bs + off) = vb;
        }
        __syncthreads();
#pragma unroll
        for (int kk = 0; kk < 2; kk++) {
            half8v af[4], bq[2];
            int sl = kk * 4 + (lane >> 4);
#pragma unroll
            for (int mi = 0; mi < 4; mi++) {
                int row = (lane & 15) + mi * 16;
                af[mi] = *(const half8v*)((const char*)As + row * 128 + ((sl ^ (row & 7)) << 4));
            }
#pragma unroll
            for (int ni = 0; ni < 2; ni++) {
                int row = wid * 32 + ni * 16 + (lane & 15);
                bq[ni] = *(const half8v*)((const char*)Bs + row * 128 + ((sl ^ (row & 7)) << 4));
            }
#pragma unroll
            for (int mi = 0; mi < 4; mi++)
#pragma unroll
                for (int ni = 0; ni < 2; ni++)
                    acc[mi][ni] = __builtin_amdgcn_mfma_f32_16x16x32_f16(af[mi], bq[ni], acc[mi][ni], 0, 0, 0);
        }
    }
#pragma unroll
    for (int mi = 0; mi < 4; mi++) {
#pragma unroll
        for (int j = 0; j < 4; j++) {
            int row = m0 + mi * 16 + ((lane >> 4) << 2) + j;
            if (row < M) {
#pragma unroll
                for (int ni = 0; ni < 2; ni++) {
                    int col = n0 + wid * 32 + ni * 16 + (lane & 15);
                    float v = acc[mi][ni][j];
                    if (bias) v += bias[col];
                    if (Cf) Cf[(size_t)row * Nn + col] = v;
                    if (Ch) Ch[(size_t)row * Nn + col] = f2h(v);
                }
            }
        }
    }
}

// ---------------------------------------------------------------- attention src/dst logit terms, layer 1 (fp16 xh)
__global__ __launch_bounds__(256) void k_ald1(const ushort* __restrict__ xhh, const float* __restrict__ as1,
                                              const float* __restrict__ ad1, float* __restrict__ als,
                                              float* __restrict__ ald) {
    int n = blockIdx.x;
    int w = threadIdx.x >> 6, l = threadIdx.x & 63;
    uint v = *(const uint*)&xhh[(size_t)n * 512 + w * 128 + l * 2];
    float f0 = h2f((ushort)(v & 0xffffu));
    float f1 = h2f((ushort)(v >> 16));
    float2 a = *(const float2*)&as1[w * 128 + l * 2];
    float2 b = *(const float2*)&ad1[w * 128 + l * 2];
    float ps = f0 * a.x + f1 * a.y, pd = f0 * b.x + f1 * b.y;
    for (int off = 32; off; off >>= 1) { ps += __shfl_down(ps, off); pd += __shfl_down(pd, off); }
    if (l == 0) { als[n * 4 + w] = ps; ald[n * 4 + w] = pd; }
}

// ---------------------------------------------------------------- same for layer 2 (1 head)
__global__ __launch_bounds__(256) void k_ald2(const ushort* __restrict__ xh2h, const float* __restrict__ as2,
                                              const float* __restrict__ ad2, float* __restrict__ als,
                                              float* __restrict__ ald) {
    int w = threadIdx.x >> 6, l = threadIdx.x & 63;
    int n = blockIdx.x * 4 + w;
    if (n >= N_NODES) return;
    uint v = *(const uint*)&xh2h[(size_t)n * 128 + l * 2];
    float f0 = h2f((ushort)(v & 0xffffu));
    float f1 = h2f((ushort)(v >> 16));
    float2 a = *(const float2*)&as2[l * 2];
    float2 b = *(const float2*)&ad2[l * 2];
    float ps = f0 * a.x + f1 * a.y, pd = f0 * b.x + f1 * b.y;
    for (int off = 32; off; off >>= 1) { ps += __shfl_down(ps, off); pd += __shfl_down(pd, off); }
    if (l == 0) { als[n] = ps; ald[n] = pd; }
}

// ---------------------------------------------------------------- layer-1: fused logits+softmax+gather+LN+ELU
// 128 thr = 2 waves, ONE NODE PER WAVE, zero barriers. Lane owns 8 channels (uint4 16B loads).
__global__ __launch_bounds__(128) void k_agg1(const int* __restrict__ offsets, const int2* __restrict__ csr_se,
                                              const float* __restrict__ eattr, const float* __restrict__ loopattr,
                                              const float* __restrict__ als, const float* __restrict__ aldv,
                                              const float* __restrict__ M1, const ushort* __restrict__ xhh,
                                              const float* __restrict__ b1, const float* __restrict__ g1,
                                              const float* __restrict__ be1, ushort* __restrict__ h1h) {
    int wv = threadIdx.x >> 6, lane = threadIdx.x & 63;
    int n = blockIdx.x * 2 + wv;
    __shared__ float Lc[2][CAP][4];
    __shared__ int   sSrc[2][CAP];
    __shared__ float mhs[2][4], shs[2][4];

    int start = offsets[n];
    int cnt = offsets[n + 1] - start;

    // ---- phase A: inline logits + online softmax stats (4 lanes per edge, 16 edges in parallel)
    int hh = lane & 3;
    float aldn = aldv[n * 4 + hh];
    float c0 = M1[hh], c1 = M1[4 + hh], c2 = M1[8 + hh], c3 = M1[12 + hh];
    float m = -1e30f, s = 0.f;
    for (int j = lane >> 2; j < cnt; j += 16) {
        int2 se = csr_se[start + j];
        const float* eap = (se.y < N_EDGES) ? &eattr[(size_t)se.y * 4] : &loopattr[(size_t)(se.y - N_EDGES) * 4];
        float4 e4 = *(const float4*)eap;
        float l = als[se.x * 4 + hh] + aldn + e4.x * c0 + e4.y * c1 + e4.z * c2 + e4.w * c3;
        l = (l >= 0.f) ? l : 0.2f * l;
        Lc[wv][j][hh] = l;
        if (hh == 0) sSrc[wv][j] = se.x;
        float mn = fmaxf(m, l);
        s = s * __expf(m - mn) + __expf(l - mn);
        m = mn;
    }
#pragma unroll
    for (int off = 4; off < 64; off <<= 1) {
        float mo = __shfl_xor(m, off), so = __shfl_xor(s, off);
        float mn = fmaxf(m, mo);
        s = s * __expf(m - mn) + so * __expf(mo - mn);
        m = mn;
    }
    if (lane < 4) { mhs[wv][lane] = m; shs[wv][lane] = 1.0f / s; }
    // wave-internal LDS ordering: no barrier needed (per-wave slices)

    // ---- phase A2: logits -> alpha in place
    int tot = cnt * 4;
    for (int idx = lane; idx < tot; idx += 64) {
        int j = idx >> 2, h = idx & 3;
        Lc[wv][j][h] = __expf(Lc[wv][j][h] - mhs[wv][h]) * shs[wv][h];
    }

    // ---- gather: lane owns channels 8*lane..8*lane+7; 4 edges in flight
    float acc[8];
#pragma unroll
    for (int i = 0; i < 8; i++) acc[i] = 0.f;
    int hg = lane >> 4;
    uint ch = (uint)lane * 8u;
    auto accum = [&](float a, uint4 v) {
        acc[0] += a * h2f((ushort)(v.x & 0xffffu));
        acc[1] += a * h2f((ushort)(v.x >> 16));
        acc[2] += a * h2f((ushort)(v.y & 0xffffu));
        acc[3] += a * h2f((ushort)(v.y >> 16));
        acc[4] += a * h2f((ushort)(v.z & 0xffffu));
        acc[5] += a * h2f((ushort)(v.z >> 16));
        acc[6] += a * h2f((ushort)(v.w & 0xffffu));
        acc[7] += a * h2f((ushort)(v.w >> 16));
    };
    int j = 0;
    for (; j + 4 <= cnt; j += 4) {
        float a0 = Lc[wv][j][hg], a1 = Lc[wv][j + 1][hg];
        float a2 = Lc[wv][j + 2][hg], a3 = Lc[wv][j + 3][hg];
        uint4 v0 = *(const uint4*)&xhh[((uint)sSrc[wv][j] << 9) + ch];
        uint4 v1 = *(const uint4*)&xhh[((uint)sSrc[wv][j + 1] << 9) + ch];
        uint4 v2 = *(const uint4*)&xhh[((uint)sSrc[wv][j + 2] << 9) + ch];
        uint4 v3 = *(const uint4*)&xhh[((uint)sSrc[wv][j + 3] << 9) + ch];
        accum(a0, v0); accum(a1, v1); accum(a2, v2); accum(a3, v3);
    }
    for (; j < cnt; j++) {
        float a = Lc[wv][j][hg];
        uint4 v = *(const uint4*)&xhh[((uint)sSrc[wv][j] << 9) + ch];
        accum(a, v);
    }

    // ---- + bias, LayerNorm(512), ELU — all wave-local shuffles
    float4 ba = *(const float4*)&b1[ch];
    float4 bb = *(const float4*)&b1[ch + 4];
    float v0 = acc[0] + ba.x, v1 = acc[1] + ba.y, v2 = acc[2] + ba.z, v3 = acc[3] + ba.w;
    float v4 = acc[4] + bb.x, v5 = acc[5] + bb.y, v6 = acc[6] + bb.z, v7 = acc[7] + bb.w;
    float s8 = v0 + v1 + v2 + v3 + v4 + v5 + v6 + v7;
#pragma unroll
    for (int off = 1; off < 64; off <<= 1) s8 += __shfl_xor(s8, off);
    float mu = s8 * (1.0f / 512.0f);
    float d0 = v0 - mu, d1 = v1 - mu, d2 = v2 - mu, d3 = v3 - mu;
    float d4 = v4 - mu, d5 = v5 - mu, d6 = v6 - mu, d7 = v7 - mu;
    float sq = d0 * d0 + d1 * d1 + d2 * d2 + d3 * d3 + d4 * d4 + d5 * d5 + d6 * d6 + d7 * d7;
#pragma unroll
    for (int off = 1; off < 64; off <<= 1) sq += __shfl_xor(sq, off);
    float rstd = rsqrtf(sq * (1.0f / 512.0f) + 1e-5f);
    float4 ga = *(const float4*)&g1[ch];
    float4 gb = *(const float4*)&g1[ch + 4];
    float4 ea = *(const float4*)&be1[ch];
    float4 eb = *(const float4*)&be1[ch + 4];
    float y0 = d0 * rstd * ga.x + ea.x, y1 = d1 * rstd * ga.y + ea.y;
    float y2 = d2 * rstd * ga.z + ea.z, y3 = d3 * rstd * ga.w + ea.w;
    float y4 = d4 * rstd * gb.x + eb.x, y5 = d5 * rstd * gb.y + eb.y;
    float y6 = d6 * rstd * gb.z + eb.z, y7 = d7 * rstd * gb.w + eb.w;
    y0 = (y0 > 0.f) ? y0 : (__expf(y0) - 1.0f);
    y1 = (y1 > 0.f) ? y1 : (__expf(y1) - 1.0f);
    y2 = (y2 > 0.f) ? y2 : (__expf(y2) - 1.0f);
    y3 = (y3 > 0.f) ? y3 : (__expf(y3) - 1.0f);
    y4 = (y4 > 0.f) ? y4 : (__expf(y4) - 1.0f);
    y5 = (y5 > 0.f) ? y5 : (__expf(y5) - 1.0f);
    y6 = (y6 > 0.f) ? y6 : (__expf(y6) - 1.0f);
    y7 = (y7 > 0.f) ? y7 : (__expf(y7) - 1.0f);
    uint4 o;
    o.x = (uint)f2h(y0) | ((uint)f2h(y1) << 16);
    o.y = (uint)f2h(y2) | ((uint)f2h(y3) << 16);
    o.z = (uint)f2h(y4) | ((uint)f2h(y5) << 16);
    o.w = (uint)f2h(y6) | ((uint)f2h(y7) << 16);
    *(uint4*)&h1h[(size_t)n * 512 + ch] = o;
}

// ---------------------------------------------------------------- layer-2: fused logits+softmax+alpha-out+gather+LN
// 128 thr = 2 waves, ONE NODE PER WAVE, zero barriers. Lane owns 2 channels.
__global__ __launch_bounds__(128) void k_agg2(const int* __restrict__ offsets, const int2* __restrict__ csr_se,
                                              const float* __restrict__ eattr, const float* __restrict__ loopattr,
                                              const float* __restrict__ als, const float* __restrict__ aldv,
                                              const float* __restrict__ m2v, const ushort* __restrict__ xh2h,
                                              const float* __restrict__ b2, const float* __restrict__ g2,
                                              const float* __restrict__ be2, float* __restrict__ eaout,
                                              ushort* __restrict__ h2h) {
    int wv = threadIdx.x >> 6, lane = threadIdx.x & 63;
    int n = blockIdx.x * 2 + wv;
    __shared__ float Lc[2][CAP];
    __shared__ int   sS[2][CAP];
    __shared__ int   sE[2][CAP];

    int start = offsets[n];
    int cnt = offsets[n + 1] - start;
    float aldn = aldv[n];
    float c0 = m2v[0], c1 = m2v[1], c2 = m2v[2], c3 = m2v[3];
    float m = -1e30f, s = 0.f;
    for (int j = lane; j < cnt; j += 64) {
        int2 se = csr_se[start + j];
        const float* eap = (se.y < N_EDGES) ? &eattr[(size_t)se.y * 4] : &loopattr[(size_t)(se.y - N_EDGES) * 4];
        float4 e4 = *(const float4*)eap;
        float l = als[se.x] + aldn + e4.x * c0 + e4.y * c1 + e4.z * c2 + e4.w * c3;
        l = (l >= 0.f) ? l : 0.2f * l;
        Lc[wv][j] = l; sS[wv][j] = se.x; sE[wv][j] = se.y;
        float mn = fmaxf(m, l);
        s = s * __expf(m - mn) + __expf(l - mn);
        m = mn;
    }
#pragma unroll
    for (int off = 1; off < 64; off <<= 1) {
        float mo = __shfl_xor(m, off), so = __shfl_xor(s, off);
        float mn = fmaxf(m, mo);
        s = s * __expf(m - mn) + so * __expf(mo - mn);
        m = mn;
    }
    float inv = 1.0f / s;
    for (int j = lane; j < cnt; j += 64) {
        float a = __expf(Lc[wv][j] - m) * inv;
        Lc[wv][j] = a;
        eaout[sE[wv][j]] = a;
    }
    // gather: lane owns channels 2*lane, 2*lane+1; 8 edges in flight
    float acc0 = 0.f, acc1 = 0.f;
    uint ch = (uint)lane * 2u;
    int j = 0;
    for (; j + 8 <= cnt; j += 8) {
        float a0 = Lc[wv][j], a1 = Lc[wv][j + 1], a2 = Lc[wv][j + 2], a3 = Lc[wv][j + 3];
        float a4 = Lc[wv][j + 4], a5 = Lc[wv][j + 5], a6 = Lc[wv][j + 6], a7 = Lc[wv][j + 7];
        uint v0 = *(const uint*)&xh2h[((uint)sS[wv][j] << 7) + ch];
        uint v1 = *(const uint*)&xh2h[((uint)sS[wv][j + 1] << 7) + ch];
        uint v2 = *(const uint*)&xh2h[((uint)sS[wv][j + 2] << 7) + ch];
        uint v3 = *(const uint*)&xh2h[((uint)sS[wv][j + 3] << 7) + ch];
        uint v4 = *(const uint*)&xh2h[((uint)sS[wv][j + 4] << 7) + ch];
        uint v5 = *(const uint*)&xh2h[((uint)sS[wv][j + 5] << 7) + ch];
        uint v6 = *(const uint*)&xh2h[((uint)sS[wv][j + 6] << 7) + ch];
        uint v7 = *(const uint*)&xh2h[((uint)sS[wv][j + 7] << 7) + ch];
        acc0 += a0 * h2f((ushort)(v0 & 0xffffu)) + a1 * h2f((ushort)(v1 & 0xffffu))
              + a2 * h2f((ushort)(v2 & 0xffffu)) + a3 * h2f((ushort)(v3 & 0xffffu))
              + a4 * h2f((ushort)(v4 & 0xffffu)) + a5 * h2f((ushort)(v5 & 0xffffu))
              + a6 * h2f((ushort)(v6 & 0xffffu)) + a7 * h2f((ushort)(v7 & 0xffffu));
        acc1 += a0 * h2f((ushort)(v0 >> 16)) + a1 * h2f((ushort)(v1 >> 16))
              + a2 * h2f((ushort)(v2 >> 16)) + a3 * h2f((ushort)(v3 >> 16))
              + a4 * h2f((ushort)(v4 >> 16)) + a5 * h2f((ushort)(v5 >> 16))
              + a6 * h2f((ushort)(v6 >> 16)) + a7 * h2f((ushort)(v7 >> 16));
    }
    for (; j < cnt; j++) {
        float a = Lc[wv][j];
        uint v = *(const uint*)&xh2h[((uint)sS[wv][j] << 7) + ch];
        acc0 += a * h2f((ushort)(v & 0xffffu));
        acc1 += a * h2f((ushort)(v >> 16));
    }
    // bias + LN(128) within the wave
    float2 bb = *(const float2*)&b2[ch];
    float v0 = acc0 + bb.x, v1 = acc1 + bb.y;
    float s2 = v0 + v1;
#pragma unroll
    for (int off = 1; off < 64; off <<= 1) s2 += __shfl_xor(s2, off);
    float mu = s2 * (1.0f / 128.0f);
    float d0 = v0 - mu, d1 = v1 - mu;
    float q = d0 * d0 + d1 * d1;
#pragma unroll
    for (int off = 1; off < 64; off <<= 1) q += __shfl_xor(q, off);
    float rstd = rsqrtf(q * (1.0f / 128.0f) + 1e-5f);
    float2 gg = *(const float2*)&g2[ch];
    float2 ee = *(const float2*)&be2[ch];
    float y0 = d0 * rstd * gg.x + ee.x;
    float y1 = d1 * rstd * gg.y + ee.y;
    uint o = (uint)f2h(y0) | ((uint)f2h(y1) << 16);
    *(uint*)&h2h[(size_t)n * 128 + ch] = o;
}

// ---------------------------------------------------------------- importance = sigmoid(emb @ Wi + bi)
__global__ __launch_bounds__(256) void k_imp(const float* __restrict__ emb, const float* __restrict__ Wi,
                                             const float* __restrict__ bi, float* __restrict__ impout) {
    int w = threadIdx.x >> 6, l = threadIdx.x & 63;
    int n = blockIdx.x * 4 + w;
    if (n >= N_NODES) return;
    const float* ep = &emb[(size_t)n * 128];
    float p = ep[l] * Wi[l] + ep[l + 64] * Wi[l + 64];
    for (int off = 32; off; off >>= 1) p += __shfl_down(p, off);
    if (l == 0) impout[n] = 1.0f / (1.0f + expf(-(p + bi[0])));
}

// ================================================================ launch
extern "C" void kernel_launch(void* const* d_in, const int* in_sizes, int n_in,
                              void* d_out, int out_size, void* d_ws, size_t ws_size,
                              hipStream_t stream) {
    const float* x    = (const float*)d_in[0];
    const int*   eidx = (const int*)d_in[1];
    const float* eattr= (const float*)d_in[2];
    const float* Wp   = (const float*)d_in[3];
    const float* bp   = (const float*)d_in[4];
    const float* W1   = (const float*)d_in[5];
    const float* We1  = (const float*)d_in[6];
    const float* as1  = (const float*)d_in[7];
    const float* ad1  = (const float*)d_in[8];
    const float* ae1  = (const float*)d_in[9];
    const float* b1   = (const float*)d_in[10];
    const float* g1   = (const float*)d_in[11];
    const float* be1  = (const float*)d_in[12];
    const float* W2   = (const float*)d_in[13];
    const float* We2  = (const float*)d_in[14];
    const float* as2  = (const float*)d_in[15];
    const float* ad2  = (const float*)d_in[16];
    const float* ae2  = (const float*)d_in[17];
    const float* b2   = (const float*)d_in[18];
    const float* g2   = (const float*)d_in[19];
    const float* be2  = (const float*)d_in[20];
    const float* Wo   = (const float*)d_in[21];
    const float* bo   = (const float*)d_in[22];
    const float* Wi   = (const float*)d_in[23];
    const float* bi   = (const float*)d_in[24];

    const int* src = eidx;
    const int* dst = eidx + N_EDGES;

    float* emb_out = (float*)d_out;                       // [N,128]
    float* ea_out  = emb_out + (size_t)N_NODES * 128;     // [E+N]
    float* imp_out = ea_out + EN_TOT;                     // [N]

    // ---- workspace carve (256B aligned) ----
    char* w = (char*)d_ws;
    auto alloc = [&](size_t bytes) -> void* { void* p = (void*)w; w += (bytes + 255) & ~(size_t)255; return p; };
    ushort* xhh    = (ushort*)alloc((size_t)N_NODES * 512 * 2);  // [N,512] fp16
    ushort* h1h    = (ushort*)alloc((size_t)N_NODES * 512 * 2);  // [N,512] fp16
    ushort* h0h    = (ushort*)alloc((size_t)N_NODES * 128 * 2);  // [N,128] fp16
    ushort* xh2h   = (ushort*)alloc((size_t)N_NODES * 128 * 2);  // [N,128] fp16
    ushort* h2h    = (ushort*)alloc((size_t)N_NODES * 128 * 2);  // [N,128] fp16
    ushort* W1T    = (ushort*)alloc((size_t)512 * 128 * 2);
    ushort* W2T    = (ushort*)alloc((size_t)128 * 512 * 2);
    ushort* WoT    = (ushort*)alloc((size_t)128 * 128 * 2);
    int2*  csr_se  = (int2*)alloc((size_t)EN_TOT * 8);
    int*   offsets = (int*)alloc((size_t)(N_NODES + 1) * 4);
    int*   cursor  = (int*)alloc((size_t)N_NODES * 4);
    int*   degi    = (int*)alloc((size_t)N_NODES * 4);
    float* loopat  = (float*)alloc((size_t)N_NODES * 4 * 4);
    float* als1v   = (float*)alloc((size_t)N_NODES * 4 * 4);
    float* ald1v   = (float*)alloc((size_t)N_NODES * 4 * 4);
    float* als2v   = (float*)alloc((size_t)N_NODES * 4);
    float* ald2v   = (float*)alloc((size_t)N_NODES * 4);
    float* M1      = (float*)alloc(32 * 4);
    float* m2      = M1 + 16;

    hipMemsetAsync(degi,   0, (size_t)N_NODES * 4, stream);
    hipMemsetAsync(cursor, 0, (size_t)N_NODES * 4, stream);

    k_deg<<<(N_EDGES + 255) / 256, 256, 0, stream>>>(dst, degi);
    k_scan<<<1, 1024, 0, stream>>>(degi, offsets, We1, ae1, We2, ae2, M1, m2);
    k_fill<<<(EN_TOT + 255) / 256, 256, 0, stream>>>(src, dst, offsets, cursor, csr_se);
    k_misc<<<15576, 256, 0, stream>>>(offsets, csr_se, eattr, loopat, W1, W2, Wo,
                                      W1T, W2T, WoT, x, Wp, bp, h0h);

    // xh = h0 @ W1   [20000,128] x [128,512] -> fp16
    k_gemm_hf<<<dim3((N_NODES + 63) / 64, 4), 256, 0, stream>>>(h0h, W1T, nullptr, xhh,
                                                                N_NODES, 512, 128, nullptr);
    k_ald1<<<N_NODES, 256, 0, stream>>>(xhh, as1, ad1, als1v, ald1v);
    k_agg1<<<N_NODES / 2, 128, 0, stream>>>(offsets, csr_se, eattr, loopat, als1v, ald1v, M1,
                                            xhh, b1, g1, be1, h1h);

    // xh2 = h1 @ W2  [20000,512] x [512,128] -> fp16
    k_gemm_hf<<<dim3((N_NODES + 63) / 64, 1), 256, 0, stream>>>(h1h, W2T, nullptr, xh2h,
                                                                N_NODES, 128, 512, nullptr);
    k_ald2<<<(N_NODES + 3) / 4, 256, 0, stream>>>(xh2h, as2, ad2, als2v, ald2v);
    k_agg2<<<N_NODES / 2, 128, 0, stream>>>(offsets, csr_se, eattr, loopat, als2v, ald2v, m2,
                                            xh2h, b2, g2, be2, ea_out, h2h);

    // emb = h2 @ Wo + bo -> d_out (fp32)
    k_gemm_hf<<<dim3((N_NODES + 63) / 64, 1), 256, 0, stream>>>(h2h, WoT, emb_out, nullptr,
                                                                N_NODES, 128, 128, bo);
    k_imp<<<(N_NODES + 3) / 4, 256, 0, stream>>>(emb_out, Wi, bi, imp_out);
}

// Round 8
// 207.109 us; speedup vs baseline: 2.3306x; 1.0646x over previous
//
#include <hip/hip_runtime.h>
#include <math.h>
#include <stdint.h>

#define N_NODES 20000
#define N_EDGES 320000
#define EN_TOT  340000   // E + N (with self loops)
#define CAP     160      // max per-node CSR segment (deg ~ Poisson(16); 160 is >30 sigma)

typedef __attribute__((ext_vector_type(8))) _Float16 half8v;  // 8 fp16 (4 VGPRs)
typedef __attribute__((ext_vector_type(2))) _Float16 half2v;  // packed fp16 pair
typedef __attribute__((ext_vector_type(4))) float float4v;    // MFMA accumulator

__device__ __forceinline__ ushort f2h(float f) {              // fp32 -> fp16 RNE
    _Float16 h = (_Float16)f;
    return __builtin_bit_cast(ushort, h);
}
__device__ __forceinline__ float h2f(ushort s) {
    return (float)__builtin_bit_cast(_Float16, s);
}

// ---------------------------------------------------------------- degree count (1 int atomic / edge)
__global__ void k_deg(const int* __restrict__ dst, int* __restrict__ degi) {
    int e = blockIdx.x * 256 + threadIdx.x;
    if (e >= N_EDGES) return;
    atomicAdd(&degi[dst[e]], 1);
}

// ---------------------------------------------------------------- scan (offsets) + M1/m2 fold
__global__ __launch_bounds__(1024) void k_scan(const int* __restrict__ degi, int* __restrict__ offsets,
                                               const float* __restrict__ We1, const float* __restrict__ ae1,
                                               const float* __restrict__ We2, const float* __restrict__ ae2,
                                               float* __restrict__ M1, float* __restrict__ m2) {
    __shared__ int s[1024];
    int t = threadIdx.x;
    int n0 = t * 20;
    int tot = 0;
    for (int i = 0; i < 20; i++) {
        int n = n0 + i;
        if (n < N_NODES) tot += degi[n] + 1;
    }
    s[t] = tot;
    __syncthreads();
    for (int off = 1; off < 1024; off <<= 1) {
        int v = (t >= off) ? s[t - off] : 0;
        __syncthreads();
        s[t] += v;
        __syncthreads();
    }
    int run = s[t] - tot;
    for (int i = 0; i < 20; i++) {
        int n = n0 + i;
        if (n < N_NODES) {
            offsets[n] = run;
            run += degi[n] + 1;
        }
    }
    if (t == 1023) offsets[N_NODES] = s[1023];
    if (t < 16) {
        int f = t >> 2, h = t & 3;
        float acc = 0.f;
        for (int c = 0; c < 128; c++) acc += We1[f * 512 + h * 128 + c] * ae1[h * 128 + c];
        M1[f * 4 + h] = acc;
    } else if (t < 20) {
        int f = t - 16;
        float acc = 0.f;
        for (int c = 0; c < 128; c++) acc += We2[f * 128 + c] * ae2[c];
        m2[f] = acc;
    }
}

// ---------------------------------------------------------------- CSR fill: packed (src, eid) int2
__global__ void k_fill(const int* __restrict__ src, const int* __restrict__ dst,
                       const int* __restrict__ offsets, int* __restrict__ cursor,
                       int2* __restrict__ csr_se) {
    int i = blockIdx.x * 256 + threadIdx.x;
    if (i >= EN_TOT) return;
    int d, sidx, eid;
    if (i < N_EDGES) { d = dst[i]; sidx = src[i]; eid = i; }
    else { int n = i - N_EDGES; d = n; sidx = n; eid = N_EDGES + n; }
    int pos = offsets[d] + atomicAdd(&cursor[d], 1);
    csr_se[pos] = make_int2(sidx, eid);
}

// ---------------------------------------------------------------- merged: loop_attr | weight prep | input proj
__global__ __launch_bounds__(256) void k_misc(const int* __restrict__ offsets, const int2* __restrict__ csr_se,
                                              const float* __restrict__ eattr, float* __restrict__ loopattr,
                                              const float* __restrict__ W1, const float* __restrict__ W2,
                                              const float* __restrict__ Wo, ushort* __restrict__ W1T,
                                              ushort* __restrict__ W2T, ushort* __restrict__ WoT,
                                              const float* __restrict__ x, const float* __restrict__ Wp,
                                              const float* __restrict__ bp, ushort* __restrict__ h0h) {
    int b = blockIdx.x;
    int tid = threadIdx.x;
    if (b < 5000) {
        int wv = tid >> 6, l = tid & 63;
        int n = b * 4 + wv;
        if (n >= N_NODES) return;
        int start = offsets[n], end = offsets[n + 1];
        float sx = 0.f, sy = 0.f, sz = 0.f, sw = 0.f;
        for (int p = start + l; p < end; p += 64) {
            int eid = csr_se[p].y;
            if (eid < N_EDGES) {
                float4 e = *(const float4*)&eattr[(size_t)eid * 4];
                sx += e.x; sy += e.y; sz += e.z; sw += e.w;
            }
        }
        for (int off = 32; off; off >>= 1) {
            sx += __shfl_down(sx, off);
            sy += __shfl_down(sy, off);
            sz += __shfl_down(sz, off);
            sw += __shfl_down(sw, off);
        }
        if (l == 0) {
            float inv = 1.0f / fmaxf((float)(end - start - 1), 1.0f);
            float4 o;
            o.x = sx * inv; o.y = sy * inv; o.z = sz * inv; o.w = sw * inv;
            *(float4*)&loopattr[(size_t)n * 4] = o;
        }
    } else if (b < 5576) {
        int i = (b - 5000) * 256 + tid;
        if (i < 512 * 128) {
            int nn = i >> 7, kk = i & 127;
            W1T[i] = f2h(W1[kk * 512 + nn]);
        } else if (i < 2 * 512 * 128) {
            int j = i - 512 * 128;
            int nn = j >> 9, kk = j & 511;
            W2T[j] = f2h(W2[kk * 128 + nn]);
        } else if (i < 2 * 512 * 128 + 128 * 128) {
            int j = i - 2 * 512 * 128;
            int nn = j >> 7, kk = j & 127;
            WoT[j] = f2h(Wo[kk * 128 + nn]);
        }
    } else {
        int n = (b - 5576) * 2 + (tid >> 7);
        int c = tid & 127;
        float acc = bp[c];
#pragma unroll
        for (int f = 0; f < 4; f++) acc += x[n * 4 + f] * Wp[f * 128 + c];
        h0h[(size_t)n * 128 + c] = f2h(acc);
    }
}

// ---------------------------------------------------------------- MFMA fp16 GEMM + fused row-dot epilogue
// C[M,Nn] = A[M,K] @ BT[Nn,K]^T ; optional outS/outD[row] = sum_col C*asv/adv (per block-col tile),
// or sigmoid importance when sbias != null.
__global__ __launch_bounds__(256) void k_gemm_hf(const ushort* __restrict__ A, const ushort* __restrict__ BT,
                                                 float* __restrict__ Cf, ushort* __restrict__ Ch,
                                                 int M, int Nn, int K, const float* __restrict__ bias,
                                                 const float* __restrict__ asv, const float* __restrict__ adv,
                                                 float* __restrict__ outS, float* __restrict__ outD,
                                                 int hstride, const float* __restrict__ sbias) {
    __shared__ ushort As[64 * 64];    // 8 KB
    __shared__ ushort Bs[128 * 64];   // 16 KB
    __shared__ float redS[4][64];
    __shared__ float redD[4][64];
    const int tid = threadIdx.x;
    const int lane = tid & 63, wid = tid >> 6;
    const int m0 = blockIdx.x * 64, n0 = blockIdx.y * 128;
    float4v acc[4][2];
#pragma unroll
    for (int i = 0; i < 4; i++)
#pragma unroll
        for (int j = 0; j < 2; j++) acc[i][j] = (float4v){0.f, 0.f, 0.f, 0.f};

    for (int k0 = 0; k0 < K; k0 += 64) {
        __syncthreads();
#pragma unroll
        for (int i = 0; i < 2; i++) {           // A: 64 rows x 8 chunks
            int c = tid + i * 256;
            int row = c >> 3, sl = c & 7;
            int off = row * 128 + ((sl ^ (row & 7)) << 4);
            uint4 va = make_uint4(0u, 0u, 0u, 0u);
            if (m0 + row < M) va = *(const uint4*)&A[(size_t)(m0 + row) * K + k0 + sl * 8];
            *(uint4*)((char*)As + off) = va;
        }
#pragma unroll
        for (int i = 0; i < 4; i++) {           // B: 128 rows x 8 chunks
            int c = tid + i * 256;
            int row = c >> 3, sl = c & 7;
            int off = row * 128 + ((sl ^ (row & 7)) << 4);
            uint4 vb = *(const uint4*)&BT[(size_t)(n0 + row) * K + k0 + sl * 8];
            *(uint4*)((char*)Bs + off) = vb;
        }
        __syncthreads();
#pragma unroll
        for (int kk = 0; kk < 2; kk++) {
            half8v af[4], bq[2];
            int sl = kk * 4 + (lane >> 4);
#pragma unroll
            for (int mi = 0; mi < 4; mi++) {
                int row = (lane & 15) + mi * 16;
                af[mi] = *(const half8v*)((const char*)As + row * 128 + ((sl ^ (row & 7)) << 4));
            }
#pragma unroll
            for (int ni = 0; ni < 2; ni++) {
                int row = wid * 32 + ni * 16 + (lane & 15);
                bq[ni] = *(const half8v*)((const char*)Bs + row * 128 + ((sl ^ (row & 7)) << 4));
            }
#pragma unroll
            for (int mi = 0; mi < 4; mi++)
#pragma unroll
                for (int ni = 0; ni < 2; ni++)
                    acc[mi][ni] = __builtin_amdgcn_mfma_f32_16x16x32_f16(af[mi], bq[ni], acc[mi][ni], 0, 0, 0);
        }
    }
    // ---- C write
    float bcol[2];
#pragma unroll
    for (int ni = 0; ni < 2; ni++)
        bcol[ni] = bias ? bias[n0 + wid * 32 + ni * 16 + (lane & 15)] : 0.f;
#pragma unroll
    for (int mi = 0; mi < 4; mi++) {
#pragma unroll
        for (int j = 0; j < 4; j++) {
            int row = m0 + mi * 16 + ((lane >> 4) << 2) + j;
            if (row < M) {
#pragma unroll
                for (int ni = 0; ni < 2; ni++) {
                    int col = n0 + wid * 32 + ni * 16 + (lane & 15);
                    float v = acc[mi][ni][j] + bcol[ni];
                    if (Cf) Cf[(size_t)row * Nn + col] = v;
                    if (Ch) Ch[(size_t)row * Nn + col] = f2h(v);
                }
            }
        }
    }
    // ---- fused row-dot epilogue (als/ald or sigmoid importance)
    if (asv) {
        float asl[2], adl[2];
#pragma unroll
        for (int ni = 0; ni < 2; ni++) {
            int col = n0 + wid * 32 + ni * 16 + (lane & 15);
            asl[ni] = asv[col];
            adl[ni] = adv ? adv[col] : 0.f;
        }
        float psv[4][4], pdv[4][4];
#pragma unroll
        for (int mi = 0; mi < 4; mi++)
#pragma unroll
            for (int j = 0; j < 4; j++) {
                float v0 = acc[mi][0][j] + bcol[0];
                float v1 = acc[mi][1][j] + bcol[1];
                psv[mi][j] = v0 * asl[0] + v1 * asl[1];
                pdv[mi][j] = v0 * adl[0] + v1 * adl[1];
            }
#pragma unroll
        for (int off = 1; off < 16; off <<= 1) {
#pragma unroll
            for (int mi = 0; mi < 4; mi++)
#pragma unroll
                for (int j = 0; j < 4; j++) {
                    psv[mi][j] += __shfl_xor(psv[mi][j], off);
                    pdv[mi][j] += __shfl_xor(pdv[mi][j], off);
                }
        }
        if ((lane & 15) == 0) {
#pragma unroll
            for (int mi = 0; mi < 4; mi++)
#pragma unroll
                for (int j = 0; j < 4; j++) {
                    int r = mi * 16 + ((lane >> 4) << 2) + j;
                    redS[wid][r] = psv[mi][j];
                    redD[wid][r] = pdv[mi][j];
                }
        }
        __syncthreads();
        if (tid < 64) {
            int row = m0 + tid;
            if (row < M) {
                float ss = redS[0][tid] + redS[1][tid] + redS[2][tid] + redS[3][tid];
                float dd = redD[0][tid] + redD[1][tid] + redD[2][tid] + redD[3][tid];
                if (sbias) {
                    outS[row] = 1.0f / (1.0f + __expf(-(ss + sbias[0])));
                } else {
                    outS[row * hstride + blockIdx.y] = ss;
                    if (outD) outD[row * hstride + blockIdx.y] = dd;
                }
            }
        }
    }
}

// ---------------------------------------------------------------- layer-1: fused logits+softmax+gather+LN+ELU
// 128 thr = 2 waves, ONE NODE PER WAVE, zero barriers. Lane owns 8 channels; 8 edges in flight; pk_fma fp16 acc.
__global__ __launch_bounds__(128) void k_agg1(const int* __restrict__ offsets, const int2* __restrict__ csr_se,
                                              const float* __restrict__ eattr, const float* __restrict__ loopattr,
                                              const float* __restrict__ als, const float* __restrict__ aldv,
                                              const float* __restrict__ M1, const ushort* __restrict__ xhh,
                                              const float* __restrict__ b1, const float* __restrict__ g1,
                                              const float* __restrict__ be1, ushort* __restrict__ h1h) {
    int wv = threadIdx.x >> 6, lane = threadIdx.x & 63;
    int n = blockIdx.x * 2 + wv;
    __shared__ float Lc[2][CAP][4];
    __shared__ int   sSrc[2][CAP];
    __shared__ float mhs[2][4], shs[2][4];

    int start = offsets[n];
    int cnt = offsets[n + 1] - start;

    // ---- phase A: inline logits + online softmax stats (4 lanes per edge)
    int hh = lane & 3;
    float aldn = aldv[n * 4 + hh];
    float c0 = M1[hh], c1 = M1[4 + hh], c2 = M1[8 + hh], c3 = M1[12 + hh];
    float m = -1e30f, s = 0.f;
    for (int j = lane >> 2; j < cnt; j += 16) {
        int2 se = csr_se[start + j];
        const float* eap = (se.y < N_EDGES) ? &eattr[(size_t)se.y * 4] : &loopattr[(size_t)(se.y - N_EDGES) * 4];
        float4 e4 = *(const float4*)eap;
        float l = als[se.x * 4 + hh] + aldn + e4.x * c0 + e4.y * c1 + e4.z * c2 + e4.w * c3;
        l = (l >= 0.f) ? l : 0.2f * l;
        Lc[wv][j][hh] = l;
        if (hh == 0) sSrc[wv][j] = se.x;
        float mn = fmaxf(m, l);
        s = s * __expf(m - mn) + __expf(l - mn);
        m = mn;
    }
#pragma unroll
    for (int off = 4; off < 64; off <<= 1) {
        float mo = __shfl_xor(m, off), so = __shfl_xor(s, off);
        float mn = fmaxf(m, mo);
        s = s * __expf(m - mn) + so * __expf(mo - mn);
        m = mn;
    }
    if (lane < 4) { mhs[wv][lane] = m; shs[wv][lane] = 1.0f / s; }

    // ---- phase A2: logits -> alpha in place
    int tot = cnt * 4;
    for (int idx = lane; idx < tot; idx += 64) {
        int j = idx >> 2, h = idx & 3;
        Lc[wv][j][h] = __expf(Lc[wv][j][h] - mhs[wv][h]) * shs[wv][h];
    }

    // ---- gather: lane owns channels 8*lane..8*lane+7; 8 edges in flight; fp16 packed accumulate
    half2v hac0 = (half2v)0, hac1 = (half2v)0, hac2 = (half2v)0, hac3 = (half2v)0;
    int hg = lane >> 4;
    uint ch = (uint)lane * 8u;
    int j = 0;
    for (; j + 8 <= cnt; j += 8) {
        _Float16 av[8];
        uint4 vv[8];
#pragma unroll
        for (int t = 0; t < 8; t++) av[t] = (_Float16)Lc[wv][j + t][hg];
#pragma unroll
        for (int t = 0; t < 8; t++) vv[t] = *(const uint4*)&xhh[((uint)sSrc[wv][j + t] << 9) + ch];
#pragma unroll
        for (int t = 0; t < 8; t++) {
            half2v a2 = (half2v){av[t], av[t]};
            const half2v* pv = (const half2v*)&vv[t];
            hac0 = pv[0] * a2 + hac0;
            hac1 = pv[1] * a2 + hac1;
            hac2 = pv[2] * a2 + hac2;
            hac3 = pv[3] * a2 + hac3;
        }
    }
    for (; j < cnt; j++) {
        _Float16 a = (_Float16)Lc[wv][j][hg];
        half2v a2 = (half2v){a, a};
        uint4 v = *(const uint4*)&xhh[((uint)sSrc[wv][j] << 9) + ch];
        const half2v* pv = (const half2v*)&v;
        hac0 = pv[0] * a2 + hac0;
        hac1 = pv[1] * a2 + hac1;
        hac2 = pv[2] * a2 + hac2;
        hac3 = pv[3] * a2 + hac3;
    }

    // ---- + bias, LayerNorm(512), ELU — wave-local shuffles
    float4 ba = *(const float4*)&b1[ch];
    float4 bb = *(const float4*)&b1[ch + 4];
    float v0 = (float)hac0[0] + ba.x, v1 = (float)hac0[1] + ba.y;
    float v2 = (float)hac1[0] + ba.z, v3 = (float)hac1[1] + ba.w;
    float v4 = (float)hac2[0] + bb.x, v5 = (float)hac2[1] + bb.y;
    float v6 = (float)hac3[0] + bb.z, v7 = (float)hac3[1] + bb.w;
    float s8 = v0 + v1 + v2 + v3 + v4 + v5 + v6 + v7;
#pragma unroll
    for (int off = 1; off < 64; off <<= 1) s8 += __shfl_xor(s8, off);
    float mu = s8 * (1.0f / 512.0f);
    float d0 = v0 - mu, d1 = v1 - mu, d2 = v2 - mu, d3 = v3 - mu;
    float d4 = v4 - mu, d5 = v5 - mu, d6 = v6 - mu, d7 = v7 - mu;
    float sq = d0 * d0 + d1 * d1 + d2 * d2 + d3 * d3 + d4 * d4 + d5 * d5 + d6 * d6 + d7 * d7;
#pragma unroll
    for (int off = 1; off < 64; off <<= 1) sq += __shfl_xor(sq, off);
    float rstd = rsqrtf(sq * (1.0f / 512.0f) + 1e-5f);
    float4 ga = *(const float4*)&g1[ch];
    float4 gb = *(const float4*)&g1[ch + 4];
    float4 ea = *(const float4*)&be1[ch];
    float4 eb = *(const float4*)&be1[ch + 4];
    float y0 = d0 * rstd * ga.x + ea.x, y1 = d1 * rstd * ga.y + ea.y;
    float y2 = d2 * rstd * ga.z + ea.z, y3 = d3 * rstd * ga.w + ea.w;
    float y4 = d4 * rstd * gb.x + eb.x, y5 = d5 * rstd * gb.y + eb.y;
    float y6 = d6 * rstd * gb.z + eb.z, y7 = d7 * rstd * gb.w + eb.w;
    y0 = (y0 > 0.f) ? y0 : (__expf(y0) - 1.0f);
    y1 = (y1 > 0.f) ? y1 : (__expf(y1) - 1.0f);
    y2 = (y2 > 0.f) ? y2 : (__expf(y2) - 1.0f);
    y3 = (y3 > 0.f) ? y3 : (__expf(y3) - 1.0f);
    y4 = (y4 > 0.f) ? y4 : (__expf(y4) - 1.0f);
    y5 = (y5 > 0.f) ? y5 : (__expf(y5) - 1.0f);
    y6 = (y6 > 0.f) ? y6 : (__expf(y6) - 1.0f);
    y7 = (y7 > 0.f) ? y7 : (__expf(y7) - 1.0f);
    uint4 o;
    o.x = (uint)f2h(y0) | ((uint)f2h(y1) << 16);
    o.y = (uint)f2h(y2) | ((uint)f2h(y3) << 16);
    o.z = (uint)f2h(y4) | ((uint)f2h(y5) << 16);
    o.w = (uint)f2h(y6) | ((uint)f2h(y7) << 16);
    *(uint4*)&h1h[(size_t)n * 512 + ch] = o;
}

// ---------------------------------------------------------------- layer-2: fused logits+softmax+alpha-out+gather+LN
// 128 thr = 2 waves, ONE NODE PER WAVE, zero barriers. Lane owns 2 channels; pk_fma fp16 acc.
__global__ __launch_bounds__(128) void k_agg2(const int* __restrict__ offsets, const int2* __restrict__ csr_se,
                                              const float* __restrict__ eattr, const float* __restrict__ loopattr,
                                              const float* __restrict__ als, const float* __restrict__ aldv,
                                              const float* __restrict__ m2v, const ushort* __restrict__ xh2h,
                                              const float* __restrict__ b2, const float* __restrict__ g2,
                                              const float* __restrict__ be2, float* __restrict__ eaout,
                                              ushort* __restrict__ h2h) {
    int wv = threadIdx.x >> 6, lane = threadIdx.x & 63;
    int n = blockIdx.x * 2 + wv;
    __shared__ float Lc[2][CAP];
    __shared__ int   sS[2][CAP];
    __shared__ int   sE[2][CAP];

    int start = offsets[n];
    int cnt = offsets[n + 1] - start;
    float aldn = aldv[n];
    float c0 = m2v[0], c1 = m2v[1], c2 = m2v[2], c3 = m2v[3];
    float m = -1e30f, s = 0.f;
    for (int j = lane; j < cnt; j += 64) {
        int2 se = csr_se[start + j];
        const float* eap = (se.y < N_EDGES) ? &eattr[(size_t)se.y * 4] : &loopattr[(size_t)(se.y - N_EDGES) * 4];
        float4 e4 = *(const float4*)eap;
        float l = als[se.x] + aldn + e4.x * c0 + e4.y * c1 + e4.z * c2 + e4.w * c3;
        l = (l >= 0.f) ? l : 0.2f * l;
        Lc[wv][j] = l; sS[wv][j] = se.x; sE[wv][j] = se.y;
        float mn = fmaxf(m, l);
        s = s * __expf(m - mn) + __expf(l - mn);
        m = mn;
    }
#pragma unroll
    for (int off = 1; off < 64; off <<= 1) {
        float mo = __shfl_xor(m, off), so = __shfl_xor(s, off);
        float mn = fmaxf(m, mo);
        s = s * __expf(m - mn) + so * __expf(mo - mn);
        m = mn;
    }
    float inv = 1.0f / s;
    for (int j = lane; j < cnt; j += 64) {
        float a = __expf(Lc[wv][j] - m) * inv;
        Lc[wv][j] = a;
        eaout[sE[wv][j]] = a;
    }
    // gather: lane owns channels 2*lane, 2*lane+1; 8 edges in flight; fp16 packed accumulate
    half2v hac = (half2v)0;
    uint ch = (uint)lane * 2u;
    int j = 0;
    for (; j + 8 <= cnt; j += 8) {
        _Float16 av[8];
        uint vv[8];
#pragma unroll
        for (int t = 0; t < 8; t++) av[t] = (_Float16)Lc[wv][j + t];
#pragma unroll
        for (int t = 0; t < 8; t++) vv[t] = *(const uint*)&xh2h[((uint)sS[wv][j + t] << 7) + ch];
#pragma unroll
        for (int t = 0; t < 8; t++) {
            half2v a2 = (half2v){av[t], av[t]};
            half2v pv = __builtin_bit_cast(half2v, vv[t]);
            hac = pv * a2 + hac;
        }
    }
    for (; j < cnt; j++) {
        _Float16 a = (_Float16)Lc[wv][j];
        half2v a2 = (half2v){a, a};
        half2v pv = __builtin_bit_cast(half2v, *(const uint*)&xh2h[((uint)sS[wv][j] << 7) + ch]);
        hac = pv * a2 + hac;
    }
    // bias + LN(128) within the wave
    float2 bb = *(const float2*)&b2[ch];
    float v0 = (float)hac[0] + bb.x, v1 = (float)hac[1] + bb.y;
    float s2 = v0 + v1;
#pragma unroll
    for (int off = 1; off < 64; off <<= 1) s2 += __shfl_xor(s2, off);
    float mu = s2 * (1.0f / 128.0f);
    float d0 = v0 - mu, d1 = v1 - mu;
    float q = d0 * d0 + d1 * d1;
#pragma unroll
    for (int off = 1; off < 64; off <<= 1) q += __shfl_xor(q, off);
    float rstd = rsqrtf(q * (1.0f / 128.0f) + 1e-5f);
    float2 gg = *(const float2*)&g2[ch];
    float2 ee = *(const float2*)&be2[ch];
    float y0 = d0 * rstd * gg.x + ee.x;
    float y1 = d1 * rstd * gg.y + ee.y;
    uint o = (uint)f2h(y0) | ((uint)f2h(y1) << 16);
    *(uint*)&h2h[(size_t)n * 128 + ch] = o;
}

// ================================================================ launch
extern "C" void kernel_launch(void* const* d_in, const int* in_sizes, int n_in,
                              void* d_out, int out_size, void* d_ws, size_t ws_size,
                              hipStream_t stream) {
    const float* x    = (const float*)d_in[0];
    const int*   eidx = (const int*)d_in[1];
    const float* eattr= (const float*)d_in[2];
    const float* Wp   = (const float*)d_in[3];
    const float* bp   = (const float*)d_in[4];
    const float* W1   = (const float*)d_in[5];
    const float* We1  = (const float*)d_in[6];
    const float* as1  = (const float*)d_in[7];
    const float* ad1  = (const float*)d_in[8];
    const float* ae1  = (const float*)d_in[9];
    const float* b1   = (const float*)d_in[10];
    const float* g1   = (const float*)d_in[11];
    const float* be1  = (const float*)d_in[12];
    const float* W2   = (const float*)d_in[13];
    const float* We2  = (const float*)d_in[14];
    const float* as2  = (const float*)d_in[15];
    const float* ad2  = (const float*)d_in[16];
    const float* ae2  = (const float*)d_in[17];
    const float* b2   = (const float*)d_in[18];
    const float* g2   = (const float*)d_in[19];
    const float* be2  = (const float*)d_in[20];
    const float* Wo   = (const float*)d_in[21];
    const float* bo   = (const float*)d_in[22];
    const float* Wi   = (const float*)d_in[23];
    const float* bi   = (const float*)d_in[24];

    const int* src = eidx;
    const int* dst = eidx + N_EDGES;

    float* emb_out = (float*)d_out;                       // [N,128]
    float* ea_out  = emb_out + (size_t)N_NODES * 128;     // [E+N]
    float* imp_out = ea_out + EN_TOT;                     // [N]

    // ---- workspace carve (256B aligned) ----
    char* w = (char*)d_ws;
    auto alloc = [&](size_t bytes) -> void* { void* p = (void*)w; w += (bytes + 255) & ~(size_t)255; return p; };
    ushort* xhh    = (ushort*)alloc((size_t)N_NODES * 512 * 2);  // [N,512] fp16
    ushort* h1h    = (ushort*)alloc((size_t)N_NODES * 512 * 2);  // [N,512] fp16
    ushort* h0h    = (ushort*)alloc((size_t)N_NODES * 128 * 2);  // [N,128] fp16
    ushort* xh2h   = (ushort*)alloc((size_t)N_NODES * 128 * 2);  // [N,128] fp16
    ushort* h2h    = (ushort*)alloc((size_t)N_NODES * 128 * 2);  // [N,128] fp16
    ushort* W1T    = (ushort*)alloc((size_t)512 * 128 * 2);
    ushort* W2T    = (ushort*)alloc((size_t)128 * 512 * 2);
    ushort* WoT    = (ushort*)alloc((size_t)128 * 128 * 2);
    int2*  csr_se  = (int2*)alloc((size_t)EN_TOT * 8);
    int*   offsets = (int*)alloc((size_t)(N_NODES + 1) * 4);
    int*   cursor  = (int*)alloc((size_t)N_NODES * 4);
    int*   degi    = (int*)alloc((size_t)N_NODES * 4);
    float* loopat  = (float*)alloc((size_t)N_NODES * 4 * 4);
    float* als1v   = (float*)alloc((size_t)N_NODES * 4 * 4);
    float* ald1v   = (float*)alloc((size_t)N_NODES * 4 * 4);
    float* als2v   = (float*)alloc((size_t)N_NODES * 4);
    float* ald2v   = (float*)alloc((size_t)N_NODES * 4);
    float* M1      = (float*)alloc(32 * 4);
    float* m2      = M1 + 16;

    hipMemsetAsync(degi,   0, (size_t)N_NODES * 4, stream);
    hipMemsetAsync(cursor, 0, (size_t)N_NODES * 4, stream);

    k_deg<<<(N_EDGES + 255) / 256, 256, 0, stream>>>(dst, degi);
    k_scan<<<1, 1024, 0, stream>>>(degi, offsets, We1, ae1, We2, ae2, M1, m2);
    k_fill<<<(EN_TOT + 255) / 256, 256, 0, stream>>>(src, dst, offsets, cursor, csr_se);
    k_misc<<<15576, 256, 0, stream>>>(offsets, csr_se, eattr, loopat, W1, W2, Wo,
                                      W1T, W2T, WoT, x, Wp, bp, h0h);

    // xh = h0 @ W1  + fused als1/ald1 (blockIdx.y == head)
    k_gemm_hf<<<dim3((N_NODES + 63) / 64, 4), 256, 0, stream>>>(h0h, W1T, nullptr, xhh,
                                                                N_NODES, 512, 128, nullptr,
                                                                as1, ad1, als1v, ald1v, 4, nullptr);
    k_agg1<<<N_NODES / 2, 128, 0, stream>>>(offsets, csr_se, eattr, loopat, als1v, ald1v, M1,
                                            xhh, b1, g1, be1, h1h);

    // xh2 = h1 @ W2  + fused als2/ald2
    k_gemm_hf<<<dim3((N_NODES + 63) / 64, 1), 256, 0, stream>>>(h1h, W2T, nullptr, xh2h,
                                                                N_NODES, 128, 512, nullptr,
                                                                as2, ad2, als2v, ald2v, 1, nullptr);
    k_agg2<<<N_NODES / 2, 128, 0, stream>>>(offsets, csr_se, eattr, loopat, als2v, ald2v, m2,
                                            xh2h, b2, g2, be2, ea_out, h2h);

    // emb = h2 @ Wo + bo -> d_out (fp32) + fused importance (sigmoid(emb@Wi+bi))
    k_gemm_hf<<<dim3((N_NODES + 63) / 64, 1), 256, 0, stream>>>(h2h, WoT, emb_out, nullptr,
                                                                N_NODES, 128, 128, bo,
                                                                Wi, nullptr, imp_out, nullptr, 1, bi);
}